// Round 5
// baseline (1496.572 us; speedup 1.0000x reference)
//
#include <hip/hip_runtime.h>

#define D 128
#define NLAYERS 3
#define BN_EPS 1e-5f

__device__ __forceinline__ unsigned short f2bf(float f) {
    unsigned int u = __float_as_uint(f);
    u += 0x7FFFu + ((u >> 16) & 1u);   // round-to-nearest-even
    return (unsigned short)(u >> 16);
}
__device__ __forceinline__ float bf2f(unsigned short b) {
    return __uint_as_float(((unsigned int)b) << 16);
}

// ---------------- setup kernels ----------------

__global__ void k_hist_edges(const int* __restrict__ dst, int* __restrict__ cnt, int E) {
    int i = blockIdx.x * blockDim.x + threadIdx.x;
    if (i < E) atomicAdd(&cnt[dst[i]], 1);
}

__global__ void k_hist_batch(const int* __restrict__ batch, int* __restrict__ gcnt, int N) {
    int i = blockIdx.x * blockDim.x + threadIdx.x;
    if (i < N) atomicAdd(&gcnt[batch[i]], 1);
}

__global__ void k_dinv(const int* __restrict__ cnt, float* __restrict__ dinv, int N) {
    int i = blockIdx.x * blockDim.x + threadIdx.x;
    if (i < N) dinv[i] = rsqrtf((float)(cnt[i] + 1));   // +1 self loop
}

// partial sums of blocks of 1024 counts
__global__ void k_scan_partial(const int* __restrict__ cnt, int* __restrict__ bsum, int N) {
    __shared__ int sh[256];
    int b = blockIdx.x, t = threadIdx.x;
    int base = b * 1024 + t * 4;
    int s = 0;
#pragma unroll
    for (int i = 0; i < 4; ++i) { int idx = base + i; s += (idx < N) ? cnt[idx] : 0; }
    sh[t] = s;
    for (int ofs = 128; ofs > 0; ofs >>= 1) {
        __syncthreads();
        if (t < ofs) sh[t] += sh[t + ofs];
    }
    __syncthreads();
    if (t == 0) bsum[b] = sh[0];
}

// exclusive scan of up to 256 block sums (single block, 256 threads)
__global__ void k_scan_small(const int* __restrict__ bsum, int* __restrict__ bbase, int nb) {
    __shared__ int sh[256];
    int t = threadIdx.x;
    int v = (t < nb) ? bsum[t] : 0;
    sh[t] = v;
    __syncthreads();
    for (int ofs = 1; ofs < 256; ofs <<= 1) {
        int vv = (t >= ofs) ? sh[t - ofs] : 0;
        __syncthreads();
        sh[t] += vv;
        __syncthreads();
    }
    bbase[t] = sh[t] - v;   // exclusive
}

__global__ void k_scan_apply(const int* __restrict__ cnt, const int* __restrict__ bbase,
                             int* __restrict__ roff, int* __restrict__ cur, int N) {
    __shared__ int sh[256];
    int b = blockIdx.x, t = threadIdx.x;
    int base = b * 1024 + t * 4;
    int v[4]; int s = 0;
#pragma unroll
    for (int i = 0; i < 4; ++i) { v[i] = (base + i < N) ? cnt[base + i] : 0; s += v[i]; }
    sh[t] = s;
    __syncthreads();
    for (int ofs = 1; ofs < 256; ofs <<= 1) {
        int vv = (t >= ofs) ? sh[t - ofs] : 0;
        __syncthreads();
        sh[t] += vv;
        __syncthreads();
    }
    int o = bbase[b] + sh[t] - s;
#pragma unroll
    for (int i = 0; i < 4; ++i) {
        int idx = base + i;
        if (idx < N) {
            roff[idx] = o; cur[idx] = o;
            o += v[i];
            if (idx == N - 1) roff[N] = o;
        }
    }
}

// scan of graph counts (G <= 1024), single block of 256 threads
__global__ void k_gscan(const int* __restrict__ gcnt, int* __restrict__ goff, int G, int N) {
    __shared__ int sh[256];
    int t = threadIdx.x;
    int base = t * 4;
    int v[4]; int s = 0;
#pragma unroll
    for (int i = 0; i < 4; ++i) { v[i] = (base + i < G) ? gcnt[base + i] : 0; s += v[i]; }
    sh[t] = s;
    __syncthreads();
    for (int ofs = 1; ofs < 256; ofs <<= 1) {
        int vv = (t >= ofs) ? sh[t - ofs] : 0;
        __syncthreads();
        sh[t] += vv;
        __syncthreads();
    }
    int o = sh[t] - s;
#pragma unroll
    for (int i = 0; i < 4; ++i) {
        int idx = base + i;
        if (idx < G) { goff[idx] = o; o += v[i]; }
    }
    if (t == 255) goff[G] = N;
}

__global__ void k_fill(const int* __restrict__ src, const int* __restrict__ dst,
                       int* __restrict__ cur, int* __restrict__ csr, int E) {
    int i = blockIdx.x * blockDim.x + threadIdx.x;
    if (i < E) {
        int p = atomicAdd(&cur[dst[i]], 1);
        csr[p] = src[i];
    }
}

__global__ void k_init_ac(float* __restrict__ a, float* __restrict__ c) {
    int t = threadIdx.x;
    a[t] = 1.0f; c[t] = 0.0f;
}

// Wf[k][j] = a[k]*W[k][j], same for rW
__global__ void k_fold_scale(const float* __restrict__ W, const float* __restrict__ rW,
                             const float* __restrict__ a,
                             float* __restrict__ Wf, float* __restrict__ rWf) {
    int idx = blockIdx.x * 256 + threadIdx.x;  // grid 128 -> 32768 threads
    if (idx < D * D) {
        int k = idx >> 7;
        Wf[idx] = a[k] * W[idx];
    } else {
        int li = idx - D * D;
        int k = li >> 7;
        rWf[li] = a[k] * rW[li];
    }
}

// cwA[j] = sum_k c[k]*W[k][j];  crb[j] = rb[j] + sum_k c[k]*rW[k][j]
__global__ void k_fold_vec(const float* __restrict__ W, const float* __restrict__ rW,
                           const float* __restrict__ c, const float* __restrict__ rb,
                           float* __restrict__ cwA, float* __restrict__ crb) {
    int t = threadIdx.x;  // 256
    if (t < D) {
        float s = 0.f;
        for (int k = 0; k < D; ++k) s += c[k] * W[k * D + t];
        cwA[t] = s;
    } else {
        int j = t - D;
        float s = rb[j];
        for (int k = 0; k < D; ++k) s += c[k] * rW[k * D + j];
        crb[j] = s;
    }
}

// ---------------- fused dual GEMM ----------------
// Ob (bf16) = (F @ W0 + add0) * dinv[row]   -- pre-scaled message matrix
// O1 (f32)  = relu(F @ W1 + add1)
__global__ __launch_bounds__(256) void k_gemm_dual(
    const float* __restrict__ F,
    const float* __restrict__ W0, const float* __restrict__ W1,
    const float* __restrict__ add0, const float* __restrict__ add1,
    const float* __restrict__ dinv,
    unsigned short* __restrict__ Ob, float* __restrict__ O1, int N) {
    __shared__ float fs[128 * 128];
    const int t = threadIdx.x;
    const int rowbase = blockIdx.x * 128;

    // stage 128x128 f tile, XOR-swizzled on 16B units: su = unit ^ ((row>>3)&7)
#pragma unroll
    for (int i = 0; i < 16; ++i) {
        int l = t + i * 256;          // float4 index 0..4095
        int row = l >> 5;
        int unit = l & 31;
        float4 v = make_float4(0.f, 0.f, 0.f, 0.f);
        int gr = rowbase + row;
        if (gr < N) v = *(const float4*)(F + (size_t)gr * D + unit * 4);
        int su = unit ^ ((row >> 3) & 7);
        *(float4*)&fs[row * 128 + su * 4] = v;
    }
    __syncthreads();

    const int tx = t & 15, ty = t >> 4;
    const int c0 = tx * 8;
    const int r0 = ty * 8;

#pragma unroll 1
    for (int m = 0; m < 2; ++m) {
        const float* __restrict__ W = m ? W1 : W0;
        const float* __restrict__ addv = m ? add1 : add0;

        float acc[8][8];
#pragma unroll
        for (int i = 0; i < 8; ++i)
#pragma unroll
            for (int j = 0; j < 8; ++j) acc[i][j] = 0.f;

        for (int kc = 0; kc < 128; kc += 4) {
            float fr[8][4];
#pragma unroll
            for (int i = 0; i < 8; ++i) {
                int rr = r0 + i;
                int su = (kc >> 2) ^ ((rr >> 3) & 7);
                float4 t4 = *(const float4*)&fs[rr * 128 + su * 4];
                fr[i][0] = t4.x; fr[i][1] = t4.y; fr[i][2] = t4.z; fr[i][3] = t4.w;
            }
#pragma unroll
            for (int kk = 0; kk < 4; ++kk) {
                float4 wa = *(const float4*)(W + (size_t)(kc + kk) * D + c0);
                float4 wb = *(const float4*)(W + (size_t)(kc + kk) * D + c0 + 4);
                float wv[8] = {wa.x, wa.y, wa.z, wa.w, wb.x, wb.y, wb.z, wb.w};
#pragma unroll
                for (int i = 0; i < 8; ++i) {
                    float fv = fr[i][kk];
#pragma unroll
                    for (int j = 0; j < 8; ++j) acc[i][j] += fv * wv[j];
                }
            }
        }

        float va[8];
#pragma unroll
        for (int j = 0; j < 8; ++j) va[j] = addv[c0 + j];

#pragma unroll
        for (int i = 0; i < 8; ++i) {
            int gr = rowbase + r0 + i;
            if (gr < N) {
                float o[8];
#pragma unroll
                for (int j = 0; j < 8; ++j) o[j] = acc[i][j] + va[j];
                if (m == 0) {
                    float dv = dinv[gr];
                    unsigned int p[4];
#pragma unroll
                    for (int j = 0; j < 4; ++j) {
                        unsigned int lo = f2bf(o[2 * j] * dv);
                        unsigned int hi = f2bf(o[2 * j + 1] * dv);
                        p[j] = lo | (hi << 16);
                    }
                    *(uint4*)(Ob + (size_t)gr * D + c0) =
                        make_uint4(p[0], p[1], p[2], p[3]);
                } else {
#pragma unroll
                    for (int j = 0; j < 8; ++j) o[j] = fmaxf(o[j], 0.f);
                    *(float4*)(O1 + (size_t)gr * D + c0) =
                        make_float4(o[0], o[1], o[2], o[3]);
                    *(float4*)(O1 + (size_t)gr * D + c0 + 4) =
                        make_float4(o[4], o[5], o[6], o[7]);
                }
            }
        }
    }
}

// ---------------- aggregation + residual + BN stats ----------------
// 1 node per wave; h is bf16 pre-scaled by dinv[src] -> row = 256B,
// lane loads ushort2 (4B). Inner loop: csr[e] (scalar) -> gather. No weights.
// agg[v] = (sum_u h'[u] + h'[v]) * dinv[v] + bias ; out = agg + res (in-place).
__global__ __launch_bounds__(256) void k_agg(
    const unsigned short* __restrict__ hb, float* __restrict__ resf,
    const int* __restrict__ roff, const int* __restrict__ csr,
    const float* __restrict__ dinv, const float* __restrict__ bias,
    float* __restrict__ stats, int N) {
    const int tid = threadIdx.x;
    const int lane = tid & 63;
    const int c = lane * 2;
    const int wid = (blockIdx.x * blockDim.x + tid) >> 6;
    const int nw = (gridDim.x * blockDim.x) >> 6;
    const float b0 = bias[c], b1 = bias[c + 1];
    float sx = 0.f, sy = 0.f, qx = 0.f, qy = 0.f;

    for (int v = wid; v < N; v += nw) {
        int e = roff[v];
        const int end = roff[v + 1];
        float ax = 0.f, ay = 0.f;
        for (; e < end; ++e) {
            int u = csr[e];
            const ushort2 hv = *(const ushort2*)(hb + (size_t)u * D + c);
            ax += bf2f(hv.x);
            ay += bf2f(hv.y);
        }
        float dv = dinv[v];
        const ushort2 hs = *(const ushort2*)(hb + (size_t)v * D + c);
        ax = (ax + bf2f(hs.x)) * dv + b0;
        ay = (ay + bf2f(hs.y)) * dv + b1;
        const float2 r = *(const float2*)(resf + (size_t)v * D + c);
        float ox = ax + r.x, oy = ay + r.y;
        *(float2*)(resf + (size_t)v * D + c) = make_float2(ox, oy);
        sx += ox; sy += oy; qx += ox * ox; qy += oy * oy;
    }

    __shared__ float4 red[256];
    red[tid] = make_float4(sx, sy, qx, qy);
    __syncthreads();
    if (tid < 64) {
        float4 a = red[tid];
        float4 b = red[tid + 64];
        float4 cc = red[tid + 128];
        float4 d = red[tid + 192];
        float tsx = a.x + b.x + cc.x + d.x;
        float tsy = a.y + b.y + cc.y + d.y;
        float tqx = a.z + b.z + cc.z + d.z;
        float tqy = a.w + b.w + cc.w + d.w;
        atomicAdd(&stats[c], tsx);
        atomicAdd(&stats[c + 1], tsy);
        atomicAdd(&stats[D + c], tqx);
        atomicAdd(&stats[D + c + 1], tqy);
    }
}

__global__ void k_bnfin(const float* __restrict__ stats, const float* __restrict__ gamma,
                        const float* __restrict__ beta,
                        float* __restrict__ a_next, float* __restrict__ c_next, float invN) {
    int t = threadIdx.x;  // 128
    float mean = stats[t] * invN;
    float var = stats[D + t] * invN - mean * mean;
    float rs = rsqrtf(var + BN_EPS);
    float a = gamma[t] * rs;
    a_next[t] = a;
    c_next[t] = beta[t] - mean * a;
}

// out[g] = (sum_{v in g} f[v]) * a + cnt_g * c
__global__ void k_pool(const float* __restrict__ f, const int* __restrict__ goff,
                       const float* __restrict__ a, const float* __restrict__ c,
                       float* __restrict__ out) {
    int g = blockIdx.x, t = threadIdx.x;  // 128 threads
    int beg = goff[g], end = goff[g + 1];
    float acc = 0.f;
    for (int v = beg; v < end; ++v) acc += f[(size_t)v * D + t];
    out[(size_t)g * D + t] = acc * a[t] + (float)(end - beg) * c[t];
}

// ---------------- launcher ----------------

extern "C" void kernel_launch(void* const* d_in, const int* in_sizes, int n_in,
                              void* d_out, int out_size, void* d_ws, size_t ws_size,
                              hipStream_t stream) {
    const float* x      = (const float*)d_in[0];
    const int*   ei     = (const int*)d_in[1];
    const int*   batch  = (const int*)d_in[2];
    const float* Ws     = (const float*)d_in[3];
    const float* bs     = (const float*)d_in[4];
    const float* rWs    = (const float*)d_in[5];
    const float* rbs    = (const float*)d_in[6];
    const float* gammas = (const float*)d_in[7];
    const float* betas  = (const float*)d_in[8];
    float* out = (float*)d_out;

    const int N = in_sizes[2];
    const int E = in_sizes[1] / 2;
    const int G = out_size / D;
    const int* src = ei;
    const int* dst = ei + E;

    char* ws = (char*)d_ws;
    size_t off = 0;
    auto alloc = [&](size_t bytes) -> char* {
        char* p = ws + off;
        off += (bytes + 255) & ~(size_t)255;
        return p;
    };
    unsigned short* hb = (unsigned short*)alloc((size_t)N * D * 2);
    float* R0   = (float*)alloc((size_t)N * D * 4);
    float* R1   = (float*)alloc((size_t)N * D * 4);
    int*   csr  = (int*)alloc((size_t)E * 4);
    int*   roff = (int*)alloc((size_t)(N + 1) * 4);
    int*   cur  = (int*)alloc((size_t)N * 4);
    int*   cnt  = (int*)alloc((size_t)N * 4);
    float* dinv = (float*)alloc((size_t)N * 4);
    int*   gcnt = (int*)alloc((size_t)G * 4);
    int*   goff = (int*)alloc((size_t)(G + 1) * 4);
    int*   bsum = (int*)alloc(256 * 4);
    int*   bbase= (int*)alloc(256 * 4);
    float* stats= (float*)alloc((size_t)NLAYERS * 2 * D * 4);
    float* aarr = (float*)alloc((size_t)(NLAYERS + 1) * D * 4);
    float* carr = (float*)alloc((size_t)(NLAYERS + 1) * D * 4);
    float* Wf   = (float*)alloc((size_t)D * D * 4);
    float* rWf  = (float*)alloc((size_t)D * D * 4);
    float* cwA  = (float*)alloc(D * 4);
    float* crb  = (float*)alloc(D * 4);
    (void)ws_size;

    hipMemsetAsync(cnt, 0, (size_t)N * 4, stream);
    hipMemsetAsync(gcnt, 0, (size_t)G * 4, stream);
    hipMemsetAsync(stats, 0, (size_t)NLAYERS * 2 * D * 4, stream);

    k_hist_edges<<<(E + 255) / 256, 256, 0, stream>>>(dst, cnt, E);
    k_hist_batch<<<(N + 255) / 256, 256, 0, stream>>>(batch, gcnt, N);
    k_dinv<<<(N + 255) / 256, 256, 0, stream>>>(cnt, dinv, N);

    int nb = (N + 1023) / 1024;
    k_scan_partial<<<nb, 256, 0, stream>>>(cnt, bsum, N);
    k_scan_small<<<1, 256, 0, stream>>>(bsum, bbase, nb);
    k_scan_apply<<<nb, 256, 0, stream>>>(cnt, bbase, roff, cur, N);
    k_gscan<<<1, 256, 0, stream>>>(gcnt, goff, G, N);
    k_fill<<<(E + 255) / 256, 256, 0, stream>>>(src, dst, cur, csr, E);
    k_init_ac<<<1, D, 0, stream>>>(aarr, carr);

    const float* fin = x;
    float* fouts[NLAYERS] = {R0, R1, R0};
    for (int l = 0; l < NLAYERS; ++l) {
        const float* W  = Ws + (size_t)l * D * D;
        const float* rW = rWs + (size_t)l * D * D;
        const float* aP = aarr + (size_t)l * D;
        const float* cP = carr + (size_t)l * D;

        k_fold_scale<<<128, 256, 0, stream>>>(W, rW, aP, Wf, rWf);
        k_fold_vec<<<1, 256, 0, stream>>>(W, rW, cP, rbs + (size_t)l * D, cwA, crb);

        float* fo = fouts[l];
        k_gemm_dual<<<(N + 127) / 128, 256, 0, stream>>>(fin, Wf, rWf, cwA, crb, dinv,
                                                         hb, fo, N);
        k_agg<<<4096, 256, 0, stream>>>(hb, fo, roff, csr, dinv, bs + (size_t)l * D,
                                        stats + (size_t)l * 2 * D, N);
        k_bnfin<<<1, D, 0, stream>>>(stats + (size_t)l * 2 * D, gammas + (size_t)l * D,
                                     betas + (size_t)l * D,
                                     aarr + (size_t)(l + 1) * D, carr + (size_t)(l + 1) * D,
                                     1.0f / (float)N);
        fin = fo;
    }

    k_pool<<<G, D, 0, stream>>>(fin, goff, aarr + (size_t)NLAYERS * D,
                                carr + (size_t)NLAYERS * D, out);
}

// Round 6
// 1140.544 us; speedup vs baseline: 1.3122x; 1.3122x over previous
//
#include <hip/hip_runtime.h>

#define D 128
#define NLAYERS 3
#define BN_EPS 1e-5f

__device__ __forceinline__ unsigned short f2bf(float f) {
    unsigned int u = __float_as_uint(f);
    u += 0x7FFFu + ((u >> 16) & 1u);   // round-to-nearest-even
    return (unsigned short)(u >> 16);
}
__device__ __forceinline__ float bf_lo(unsigned int u) {
    return __uint_as_float(u << 16);
}
__device__ __forceinline__ float bf_hi(unsigned int u) {
    return __uint_as_float(u & 0xFFFF0000u);
}

// ---------------- setup kernels ----------------

__global__ void k_hist_edges(const int* __restrict__ dst, int* __restrict__ cnt, int E) {
    int i = blockIdx.x * blockDim.x + threadIdx.x;
    if (i < E) atomicAdd(&cnt[dst[i]], 1);
}

__global__ void k_hist_batch(const int* __restrict__ batch, int* __restrict__ gcnt, int N) {
    int i = blockIdx.x * blockDim.x + threadIdx.x;
    if (i < N) atomicAdd(&gcnt[batch[i]], 1);
}

__global__ void k_dinv(const int* __restrict__ cnt, float* __restrict__ dinv, int N) {
    int i = blockIdx.x * blockDim.x + threadIdx.x;
    if (i < N) dinv[i] = rsqrtf((float)(cnt[i] + 1));   // +1 self loop
}

// fill csr with the dummy index N (pad slots resolve to the zero row)
__global__ void k_csr_init(int* __restrict__ csr, int n, int N) {
    int i = blockIdx.x * blockDim.x + threadIdx.x;
    if (i < n) csr[i] = N;
}

// zero the dummy message row N
__global__ void k_zrow(unsigned short* __restrict__ hb, int N) {
    hb[(size_t)N * D + threadIdx.x] = 0;
}

// partial sums of blocks of 1024 PADDED counts (padded to multiple of 4)
__global__ void k_scan_partial(const int* __restrict__ cnt, int* __restrict__ bsum, int N) {
    __shared__ int sh[256];
    int b = blockIdx.x, t = threadIdx.x;
    int base = b * 1024 + t * 4;
    int s = 0;
#pragma unroll
    for (int i = 0; i < 4; ++i) {
        int idx = base + i;
        int cv = (idx < N) ? cnt[idx] : 0;
        s += (cv + 3) & ~3;
    }
    sh[t] = s;
    for (int ofs = 128; ofs > 0; ofs >>= 1) {
        __syncthreads();
        if (t < ofs) sh[t] += sh[t + ofs];
    }
    __syncthreads();
    if (t == 0) bsum[b] = sh[0];
}

// exclusive scan of up to 256 block sums (single block, 256 threads)
__global__ void k_scan_small(const int* __restrict__ bsum, int* __restrict__ bbase, int nb) {
    __shared__ int sh[256];
    int t = threadIdx.x;
    int v = (t < nb) ? bsum[t] : 0;
    sh[t] = v;
    __syncthreads();
    for (int ofs = 1; ofs < 256; ofs <<= 1) {
        int vv = (t >= ofs) ? sh[t - ofs] : 0;
        __syncthreads();
        sh[t] += vv;
        __syncthreads();
    }
    bbase[t] = sh[t] - v;   // exclusive
}

__global__ void k_scan_apply(const int* __restrict__ cnt, const int* __restrict__ bbase,
                             int* __restrict__ roff, int* __restrict__ cur, int N) {
    __shared__ int sh[256];
    int b = blockIdx.x, t = threadIdx.x;
    int base = b * 1024 + t * 4;
    int v[4]; int s = 0;
#pragma unroll
    for (int i = 0; i < 4; ++i) {
        int cv = (base + i < N) ? cnt[base + i] : 0;
        v[i] = (cv + 3) & ~3;
        s += v[i];
    }
    sh[t] = s;
    __syncthreads();
    for (int ofs = 1; ofs < 256; ofs <<= 1) {
        int vv = (t >= ofs) ? sh[t - ofs] : 0;
        __syncthreads();
        sh[t] += vv;
        __syncthreads();
    }
    int o = bbase[b] + sh[t] - s;
#pragma unroll
    for (int i = 0; i < 4; ++i) {
        int idx = base + i;
        if (idx < N) {
            roff[idx] = o; cur[idx] = o;
            o += v[i];
            if (idx == N - 1) roff[N] = o;
        }
    }
}

// scan of graph counts (G <= 1024), single block of 256 threads
__global__ void k_gscan(const int* __restrict__ gcnt, int* __restrict__ goff, int G, int N) {
    __shared__ int sh[256];
    int t = threadIdx.x;
    int base = t * 4;
    int v[4]; int s = 0;
#pragma unroll
    for (int i = 0; i < 4; ++i) { v[i] = (base + i < G) ? gcnt[base + i] : 0; s += v[i]; }
    sh[t] = s;
    __syncthreads();
    for (int ofs = 1; ofs < 256; ofs <<= 1) {
        int vv = (t >= ofs) ? sh[t - ofs] : 0;
        __syncthreads();
        sh[t] += vv;
        __syncthreads();
    }
    int o = sh[t] - s;
#pragma unroll
    for (int i = 0; i < 4; ++i) {
        int idx = base + i;
        if (idx < G) { goff[idx] = o; o += v[i]; }
    }
    if (t == 255) goff[G] = N;
}

__global__ void k_fill(const int* __restrict__ src, const int* __restrict__ dst,
                       int* __restrict__ cur, int* __restrict__ csr, int E) {
    int i = blockIdx.x * blockDim.x + threadIdx.x;
    if (i < E) {
        int p = atomicAdd(&cur[dst[i]], 1);
        csr[p] = src[i];
    }
}

__global__ void k_init_ac(float* __restrict__ a, float* __restrict__ c) {
    int t = threadIdx.x;
    a[t] = 1.0f; c[t] = 0.0f;
}

// Wf[k][j] = a[k]*W[k][j], same for rW
__global__ void k_fold_scale(const float* __restrict__ W, const float* __restrict__ rW,
                             const float* __restrict__ a,
                             float* __restrict__ Wf, float* __restrict__ rWf) {
    int idx = blockIdx.x * 256 + threadIdx.x;  // grid 128 -> 32768 threads
    if (idx < D * D) {
        int k = idx >> 7;
        Wf[idx] = a[k] * W[idx];
    } else {
        int li = idx - D * D;
        int k = li >> 7;
        rWf[li] = a[k] * rW[li];
    }
}

// cwA[j] = sum_k c[k]*W[k][j];  crb[j] = rb[j] + sum_k c[k]*rW[k][j]
__global__ void k_fold_vec(const float* __restrict__ W, const float* __restrict__ rW,
                           const float* __restrict__ c, const float* __restrict__ rb,
                           float* __restrict__ cwA, float* __restrict__ crb) {
    int t = threadIdx.x;  // 256
    if (t < D) {
        float s = 0.f;
        for (int k = 0; k < D; ++k) s += c[k] * W[k * D + t];
        cwA[t] = s;
    } else {
        int j = t - D;
        float s = rb[j];
        for (int k = 0; k < D; ++k) s += c[k] * rW[k * D + j];
        crb[j] = s;
    }
}

// ---------------- fused dual GEMM ----------------
// Ob (bf16) = (F @ W0 + add0) * dinv[row]   -- pre-scaled message matrix
// O1 (f32)  = relu(F @ W1 + add1)
__global__ __launch_bounds__(256) void k_gemm_dual(
    const float* __restrict__ F,
    const float* __restrict__ W0, const float* __restrict__ W1,
    const float* __restrict__ add0, const float* __restrict__ add1,
    const float* __restrict__ dinv,
    unsigned short* __restrict__ Ob, float* __restrict__ O1, int N) {
    __shared__ float fs[128 * 128];
    const int t = threadIdx.x;
    const int rowbase = blockIdx.x * 128;

    // stage 128x128 f tile, XOR-swizzled on 16B units: su = unit ^ ((row>>3)&7)
#pragma unroll
    for (int i = 0; i < 16; ++i) {
        int l = t + i * 256;          // float4 index 0..4095
        int row = l >> 5;
        int unit = l & 31;
        float4 v = make_float4(0.f, 0.f, 0.f, 0.f);
        int gr = rowbase + row;
        if (gr < N) v = *(const float4*)(F + (size_t)gr * D + unit * 4);
        int su = unit ^ ((row >> 3) & 7);
        *(float4*)&fs[row * 128 + su * 4] = v;
    }
    __syncthreads();

    const int tx = t & 15, ty = t >> 4;
    const int c0 = tx * 8;
    const int r0 = ty * 8;

#pragma unroll 1
    for (int m = 0; m < 2; ++m) {
        const float* __restrict__ W = m ? W1 : W0;
        const float* __restrict__ addv = m ? add1 : add0;

        float acc[8][8];
#pragma unroll
        for (int i = 0; i < 8; ++i)
#pragma unroll
            for (int j = 0; j < 8; ++j) acc[i][j] = 0.f;

        for (int kc = 0; kc < 128; kc += 4) {
            float fr[8][4];
#pragma unroll
            for (int i = 0; i < 8; ++i) {
                int rr = r0 + i;
                int su = (kc >> 2) ^ ((rr >> 3) & 7);
                float4 t4 = *(const float4*)&fs[rr * 128 + su * 4];
                fr[i][0] = t4.x; fr[i][1] = t4.y; fr[i][2] = t4.z; fr[i][3] = t4.w;
            }
#pragma unroll
            for (int kk = 0; kk < 4; ++kk) {
                float4 wa = *(const float4*)(W + (size_t)(kc + kk) * D + c0);
                float4 wb = *(const float4*)(W + (size_t)(kc + kk) * D + c0 + 4);
                float wv[8] = {wa.x, wa.y, wa.z, wa.w, wb.x, wb.y, wb.z, wb.w};
#pragma unroll
                for (int i = 0; i < 8; ++i) {
                    float fv = fr[i][kk];
#pragma unroll
                    for (int j = 0; j < 8; ++j) acc[i][j] += fv * wv[j];
                }
            }
        }

        float va[8];
#pragma unroll
        for (int j = 0; j < 8; ++j) va[j] = addv[c0 + j];

#pragma unroll
        for (int i = 0; i < 8; ++i) {
            int gr = rowbase + r0 + i;
            if (gr < N) {
                float o[8];
#pragma unroll
                for (int j = 0; j < 8; ++j) o[j] = acc[i][j] + va[j];
                if (m == 0) {
                    float dv = dinv[gr];
                    unsigned int p[4];
#pragma unroll
                    for (int j = 0; j < 4; ++j) {
                        unsigned int lo = f2bf(o[2 * j] * dv);
                        unsigned int hi = f2bf(o[2 * j + 1] * dv);
                        p[j] = lo | (hi << 16);
                    }
                    *(uint4*)(Ob + (size_t)gr * D + c0) =
                        make_uint4(p[0], p[1], p[2], p[3]);
                } else {
#pragma unroll
                    for (int j = 0; j < 8; ++j) o[j] = fmaxf(o[j], 0.f);
                    *(float4*)(O1 + (size_t)gr * D + c0) =
                        make_float4(o[0], o[1], o[2], o[3]);
                    *(float4*)(O1 + (size_t)gr * D + c0 + 4) =
                        make_float4(o[4], o[5], o[6], o[7]);
                }
            }
        }
    }
}

// ---------------- aggregation + residual + BN stats ----------------
// 1 node per wave, 4 EDGES PER GATHER INSTRUCTION: lane group g=lane>>4 reads
// edge e+g's bf16 row slice (16 lanes x 16B = 256B row). CSR padded per node
// to a multiple of 4 with dummy index N -> zero row, so the loop is branch-
// free and int4 index loads are aligned. Epilogue folds the 4 group partials
// with shfl_xor(16/32).
__global__ __launch_bounds__(256) void k_agg(
    const unsigned short* __restrict__ hb, float* __restrict__ resf,
    const int* __restrict__ roff, const int* __restrict__ csr,
    const float* __restrict__ dinv, const float* __restrict__ bias,
    float* __restrict__ stats, int N) {
    const int tid = threadIdx.x;
    const int lane = tid & 63;
    const int g = lane >> 4;           // edge slot within quad
    const int li = lane & 15;          // 16-lane column group
    const int cs = li * 8;             // 8 bf16 columns per lane
    const int wid = (blockIdx.x * blockDim.x + tid) >> 6;
    const int nw = (gridDim.x * blockDim.x) >> 6;

    float bv[8];
#pragma unroll
    for (int k = 0; k < 8; ++k) bv[k] = bias[cs + k];

    float s8[8], q8[8];
#pragma unroll
    for (int k = 0; k < 8; ++k) { s8[k] = 0.f; q8[k] = 0.f; }

    for (int v = wid; v < N; v += nw) {
        const int beg = roff[v], end = roff[v + 1];   // multiples of 4
        float acc[8];
#pragma unroll
        for (int k = 0; k < 8; ++k) acc[k] = 0.f;

        for (int e = beg; e < end; e += 4) {
            const int4 u4 = *(const int4*)(csr + e);
            int uu = (g == 0) ? u4.x : (g == 1) ? u4.y : (g == 2) ? u4.z : u4.w;
            const uint4 hv = *(const uint4*)(hb + (size_t)uu * D + cs);
            acc[0] += bf_lo(hv.x); acc[1] += bf_hi(hv.x);
            acc[2] += bf_lo(hv.y); acc[3] += bf_hi(hv.y);
            acc[4] += bf_lo(hv.z); acc[5] += bf_hi(hv.z);
            acc[6] += bf_lo(hv.w); acc[7] += bf_hi(hv.w);
        }

        // fold the 4 edge-group partials
#pragma unroll
        for (int k = 0; k < 8; ++k) {
            acc[k] += __shfl_xor(acc[k], 16);
            acc[k] += __shfl_xor(acc[k], 32);
        }

        const float dv = dinv[v];
        const uint4 hs = *(const uint4*)(hb + (size_t)v * D + cs);
        float hsv[8];
        hsv[0] = bf_lo(hs.x); hsv[1] = bf_hi(hs.x);
        hsv[2] = bf_lo(hs.y); hsv[3] = bf_hi(hs.y);
        hsv[4] = bf_lo(hs.z); hsv[5] = bf_hi(hs.z);
        hsv[6] = bf_lo(hs.w); hsv[7] = bf_hi(hs.w);

        const float4 r0 = *(const float4*)(resf + (size_t)v * D + cs);
        const float4 r1 = *(const float4*)(resf + (size_t)v * D + cs + 4);
        float ox[8];
        ox[0] = (acc[0] + hsv[0]) * dv + bv[0] + r0.x;
        ox[1] = (acc[1] + hsv[1]) * dv + bv[1] + r0.y;
        ox[2] = (acc[2] + hsv[2]) * dv + bv[2] + r0.z;
        ox[3] = (acc[3] + hsv[3]) * dv + bv[3] + r0.w;
        ox[4] = (acc[4] + hsv[4]) * dv + bv[4] + r1.x;
        ox[5] = (acc[5] + hsv[5]) * dv + bv[5] + r1.y;
        ox[6] = (acc[6] + hsv[6]) * dv + bv[6] + r1.z;
        ox[7] = (acc[7] + hsv[7]) * dv + bv[7] + r1.w;

        if (g == 0) {
            *(float4*)(resf + (size_t)v * D + cs) =
                make_float4(ox[0], ox[1], ox[2], ox[3]);
            *(float4*)(resf + (size_t)v * D + cs + 4) =
                make_float4(ox[4], ox[5], ox[6], ox[7]);
#pragma unroll
            for (int k = 0; k < 8; ++k) { s8[k] += ox[k]; q8[k] += ox[k] * ox[k]; }
        }
    }

    // block-level BN-stats reduction: lanes g==0 hold valid partials
    __shared__ float sred[4][16][8];
    __shared__ float qred[4][16][8];
    const int w = tid >> 6;
    if (g == 0) {
#pragma unroll
        for (int k = 0; k < 8; ++k) { sred[w][li][k] = s8[k]; qred[w][li][k] = q8[k]; }
    }
    __syncthreads();
    if (tid < D) {
        const int col = tid;
        float ts = 0.f, tq = 0.f;
#pragma unroll
        for (int ww = 0; ww < 4; ++ww) {
            ts += sred[ww][col >> 3][col & 7];
            tq += qred[ww][col >> 3][col & 7];
        }
        atomicAdd(&stats[col], ts);
        atomicAdd(&stats[D + col], tq);
    }
}

__global__ void k_bnfin(const float* __restrict__ stats, const float* __restrict__ gamma,
                        const float* __restrict__ beta,
                        float* __restrict__ a_next, float* __restrict__ c_next, float invN) {
    int t = threadIdx.x;  // 128
    float mean = stats[t] * invN;
    float var = stats[D + t] * invN - mean * mean;
    float rs = rsqrtf(var + BN_EPS);
    float a = gamma[t] * rs;
    a_next[t] = a;
    c_next[t] = beta[t] - mean * a;
}

// out[g] = (sum_{v in g} f[v]) * a + cnt_g * c
__global__ void k_pool(const float* __restrict__ f, const int* __restrict__ goff,
                       const float* __restrict__ a, const float* __restrict__ c,
                       float* __restrict__ out) {
    int g = blockIdx.x, t = threadIdx.x;  // 128 threads
    int beg = goff[g], end = goff[g + 1];
    float acc = 0.f;
    for (int v = beg; v < end; ++v) acc += f[(size_t)v * D + t];
    out[(size_t)g * D + t] = acc * a[t] + (float)(end - beg) * c[t];
}

// ---------------- launcher ----------------

extern "C" void kernel_launch(void* const* d_in, const int* in_sizes, int n_in,
                              void* d_out, int out_size, void* d_ws, size_t ws_size,
                              hipStream_t stream) {
    const float* x      = (const float*)d_in[0];
    const int*   ei     = (const int*)d_in[1];
    const int*   batch  = (const int*)d_in[2];
    const float* Ws     = (const float*)d_in[3];
    const float* bs     = (const float*)d_in[4];
    const float* rWs    = (const float*)d_in[5];
    const float* rbs    = (const float*)d_in[6];
    const float* gammas = (const float*)d_in[7];
    const float* betas  = (const float*)d_in[8];
    float* out = (float*)d_out;

    const int N = in_sizes[2];
    const int E = in_sizes[1] / 2;
    const int G = out_size / D;
    const int* src = ei;
    const int* dst = ei + E;
    const int EP = E + 4 * N;   // padded-CSR upper bound

    char* ws = (char*)d_ws;
    size_t off = 0;
    auto alloc = [&](size_t bytes) -> char* {
        char* p = ws + off;
        off += (bytes + 255) & ~(size_t)255;
        return p;
    };
    unsigned short* hb = (unsigned short*)alloc((size_t)(N + 1) * D * 2);
    float* R0   = (float*)alloc((size_t)N * D * 4);
    float* R1   = (float*)alloc((size_t)N * D * 4);
    int*   csr  = (int*)alloc((size_t)EP * 4);
    int*   roff = (int*)alloc((size_t)(N + 1) * 4);
    int*   cur  = (int*)alloc((size_t)N * 4);
    int*   cnt  = (int*)alloc((size_t)N * 4);
    float* dinv = (float*)alloc((size_t)N * 4);
    int*   gcnt = (int*)alloc((size_t)G * 4);
    int*   goff = (int*)alloc((size_t)(G + 1) * 4);
    int*   bsum = (int*)alloc(256 * 4);
    int*   bbase= (int*)alloc(256 * 4);
    float* stats= (float*)alloc((size_t)NLAYERS * 2 * D * 4);
    float* aarr = (float*)alloc((size_t)(NLAYERS + 1) * D * 4);
    float* carr = (float*)alloc((size_t)(NLAYERS + 1) * D * 4);
    float* Wf   = (float*)alloc((size_t)D * D * 4);
    float* rWf  = (float*)alloc((size_t)D * D * 4);
    float* cwA  = (float*)alloc(D * 4);
    float* crb  = (float*)alloc(D * 4);
    (void)ws_size;

    hipMemsetAsync(cnt, 0, (size_t)N * 4, stream);
    hipMemsetAsync(gcnt, 0, (size_t)G * 4, stream);
    hipMemsetAsync(stats, 0, (size_t)NLAYERS * 2 * D * 4, stream);

    k_hist_edges<<<(E + 255) / 256, 256, 0, stream>>>(dst, cnt, E);
    k_hist_batch<<<(N + 255) / 256, 256, 0, stream>>>(batch, gcnt, N);
    k_dinv<<<(N + 255) / 256, 256, 0, stream>>>(cnt, dinv, N);
    k_csr_init<<<(EP + 255) / 256, 256, 0, stream>>>(csr, EP, N);
    k_zrow<<<1, D, 0, stream>>>(hb, N);

    int nb = (N + 1023) / 1024;
    k_scan_partial<<<nb, 256, 0, stream>>>(cnt, bsum, N);
    k_scan_small<<<1, 256, 0, stream>>>(bsum, bbase, nb);
    k_scan_apply<<<nb, 256, 0, stream>>>(cnt, bbase, roff, cur, N);
    k_gscan<<<1, 256, 0, stream>>>(gcnt, goff, G, N);
    k_fill<<<(E + 255) / 256, 256, 0, stream>>>(src, dst, cur, csr, E);
    k_init_ac<<<1, D, 0, stream>>>(aarr, carr);

    const float* fin = x;
    float* fouts[NLAYERS] = {R0, R1, R0};
    for (int l = 0; l < NLAYERS; ++l) {
        const float* W  = Ws + (size_t)l * D * D;
        const float* rW = rWs + (size_t)l * D * D;
        const float* aP = aarr + (size_t)l * D;
        const float* cP = carr + (size_t)l * D;

        k_fold_scale<<<128, 256, 0, stream>>>(W, rW, aP, Wf, rWf);
        k_fold_vec<<<1, 256, 0, stream>>>(W, rW, cP, rbs + (size_t)l * D, cwA, crb);

        float* fo = fouts[l];
        k_gemm_dual<<<(N + 127) / 128, 256, 0, stream>>>(fin, Wf, rWf, cwA, crb, dinv,
                                                         hb, fo, N);
        k_agg<<<4096, 256, 0, stream>>>(hb, fo, roff, csr, dinv, bs + (size_t)l * D,
                                        stats + (size_t)l * 2 * D, N);
        k_bnfin<<<1, D, 0, stream>>>(stats + (size_t)l * 2 * D, gammas + (size_t)l * D,
                                     betas + (size_t)l * D,
                                     aarr + (size_t)(l + 1) * D, carr + (size_t)(l + 1) * D,
                                     1.0f / (float)N);
        fin = fo;
    }

    k_pool<<<G, D, 0, stream>>>(fin, goff, aarr + (size_t)NLAYERS * D,
                                carr + (size_t)NLAYERS * D, out);
}

// Round 7
// 965.319 us; speedup vs baseline: 1.5503x; 1.1815x over previous
//
#include <hip/hip_runtime.h>

#define D 128
#define NLAYERS 3
#define BN_EPS 1e-5f

typedef short bf16x8 __attribute__((ext_vector_type(8)));
typedef float f32x4 __attribute__((ext_vector_type(4)));

__device__ __forceinline__ unsigned short f2bf(float f) {
    unsigned int u = __float_as_uint(f);
    u += 0x7FFFu + ((u >> 16) & 1u);   // round-to-nearest-even
    return (unsigned short)(u >> 16);
}
__device__ __forceinline__ float bf_lo(unsigned int u) {
    return __uint_as_float(u << 16);
}
__device__ __forceinline__ float bf_hi(unsigned int u) {
    return __uint_as_float(u & 0xFFFF0000u);
}

// ---------------- setup kernels ----------------

__global__ void k_hist_edges(const int* __restrict__ dst, int* __restrict__ cnt, int E) {
    int i = blockIdx.x * blockDim.x + threadIdx.x;
    if (i < E) atomicAdd(&cnt[dst[i]], 1);
}

__global__ void k_hist_batch(const int* __restrict__ batch, int* __restrict__ gcnt, int N) {
    int i = blockIdx.x * blockDim.x + threadIdx.x;
    if (i < N) atomicAdd(&gcnt[batch[i]], 1);
}

__global__ void k_dinv(const int* __restrict__ cnt, float* __restrict__ dinv, int N) {
    int i = blockIdx.x * blockDim.x + threadIdx.x;
    if (i < N) dinv[i] = rsqrtf((float)(cnt[i] + 1));   // +1 self loop
}

// fill csr with the dummy index N (pad slots resolve to the zero row)
__global__ void k_csr_init(int* __restrict__ csr, int n, int N) {
    int i = blockIdx.x * blockDim.x + threadIdx.x;
    if (i < n) csr[i] = N;
}

// zero the dummy message row N
__global__ void k_zrow(unsigned short* __restrict__ hb, int N) {
    hb[(size_t)N * D + threadIdx.x] = 0;
}

// x (f32) -> fb (bf16), 8 elems/thread
__global__ void k_xb(const float* __restrict__ x, unsigned short* __restrict__ fb, int n8) {
    int i = blockIdx.x * blockDim.x + threadIdx.x;
    if (i < n8) {
        const float4 a = ((const float4*)x)[i * 2];
        const float4 b = ((const float4*)x)[i * 2 + 1];
        uint4 p;
        p.x = (unsigned int)f2bf(a.x) | ((unsigned int)f2bf(a.y) << 16);
        p.y = (unsigned int)f2bf(a.z) | ((unsigned int)f2bf(a.w) << 16);
        p.z = (unsigned int)f2bf(b.x) | ((unsigned int)f2bf(b.y) << 16);
        p.w = (unsigned int)f2bf(b.z) | ((unsigned int)f2bf(b.w) << 16);
        ((uint4*)fb)[i] = p;
    }
}

// partial sums of blocks of 1024 PADDED counts (padded to multiple of 4)
__global__ void k_scan_partial(const int* __restrict__ cnt, int* __restrict__ bsum, int N) {
    __shared__ int sh[256];
    int b = blockIdx.x, t = threadIdx.x;
    int base = b * 1024 + t * 4;
    int s = 0;
#pragma unroll
    for (int i = 0; i < 4; ++i) {
        int idx = base + i;
        int cv = (idx < N) ? cnt[idx] : 0;
        s += (cv + 3) & ~3;
    }
    sh[t] = s;
    for (int ofs = 128; ofs > 0; ofs >>= 1) {
        __syncthreads();
        if (t < ofs) sh[t] += sh[t + ofs];
    }
    __syncthreads();
    if (t == 0) bsum[b] = sh[0];
}

// exclusive scan of up to 256 block sums (single block, 256 threads)
__global__ void k_scan_small(const int* __restrict__ bsum, int* __restrict__ bbase, int nb) {
    __shared__ int sh[256];
    int t = threadIdx.x;
    int v = (t < nb) ? bsum[t] : 0;
    sh[t] = v;
    __syncthreads();
    for (int ofs = 1; ofs < 256; ofs <<= 1) {
        int vv = (t >= ofs) ? sh[t - ofs] : 0;
        __syncthreads();
        sh[t] += vv;
        __syncthreads();
    }
    bbase[t] = sh[t] - v;   // exclusive
}

__global__ void k_scan_apply(const int* __restrict__ cnt, const int* __restrict__ bbase,
                             int* __restrict__ roff, int* __restrict__ cur, int N) {
    __shared__ int sh[256];
    int b = blockIdx.x, t = threadIdx.x;
    int base = b * 1024 + t * 4;
    int v[4]; int s = 0;
#pragma unroll
    for (int i = 0; i < 4; ++i) {
        int cv = (base + i < N) ? cnt[base + i] : 0;
        v[i] = (cv + 3) & ~3;
        s += v[i];
    }
    sh[t] = s;
    __syncthreads();
    for (int ofs = 1; ofs < 256; ofs <<= 1) {
        int vv = (t >= ofs) ? sh[t - ofs] : 0;
        __syncthreads();
        sh[t] += vv;
        __syncthreads();
    }
    int o = bbase[b] + sh[t] - s;
#pragma unroll
    for (int i = 0; i < 4; ++i) {
        int idx = base + i;
        if (idx < N) {
            roff[idx] = o; cur[idx] = o;
            o += v[i];
            if (idx == N - 1) roff[N] = o;
        }
    }
}

// scan of graph counts (G <= 1024), single block of 256 threads
__global__ void k_gscan(const int* __restrict__ gcnt, int* __restrict__ goff, int G, int N) {
    __shared__ int sh[256];
    int t = threadIdx.x;
    int base = t * 4;
    int v[4]; int s = 0;
#pragma unroll
    for (int i = 0; i < 4; ++i) { v[i] = (base + i < G) ? gcnt[base + i] : 0; s += v[i]; }
    sh[t] = s;
    __syncthreads();
    for (int ofs = 1; ofs < 256; ofs <<= 1) {
        int vv = (t >= ofs) ? sh[t - ofs] : 0;
        __syncthreads();
        sh[t] += vv;
        __syncthreads();
    }
    int o = sh[t] - s;
#pragma unroll
    for (int i = 0; i < 4; ++i) {
        int idx = base + i;
        if (idx < G) { goff[idx] = o; o += v[i]; }
    }
    if (t == 255) goff[G] = N;
}

__global__ void k_fill(const int* __restrict__ src, const int* __restrict__ dst,
                       int* __restrict__ cur, int* __restrict__ csr, int E) {
    int i = blockIdx.x * blockDim.x + threadIdx.x;
    if (i < E) {
        int p = atomicAdd(&cur[dst[i]], 1);
        csr[p] = src[i];
    }
}

__global__ void k_init_ac(float* __restrict__ a, float* __restrict__ c) {
    int t = threadIdx.x;
    a[t] = 1.0f; c[t] = 0.0f;
}

// Pack a[k]*W[k][c] (and a[k]*rW) into the MFMA B-fragment layout, bf16.
// B frag for 16x16x32: lane l holds col=l&15, k=(l>>4)*8+j (j=0..7).
// Wp elem index = frag*512 + lane*8 + j, frag = (k>>5)*8 + (c>>4).
__global__ void k_pack_w(const float* __restrict__ W, const float* __restrict__ rW,
                         const float* __restrict__ a, unsigned short* __restrict__ Wp) {
    int idx = blockIdx.x * 256 + threadIdx.x;       // 0..32767
    int m = idx >> 14;
    int i = idx & 16383;
    int k = i >> 7, c = i & 127;
    const float* src = m ? rW : W;
    float v = a[k] * src[i];
    int frag = ((k >> 5) << 3) + (c >> 4);
    int lane = (((k & 31) >> 3) << 4) + (c & 15);
    int j = k & 7;
    Wp[(m << 14) + frag * 512 + lane * 8 + j] = f2bf(v);
}

// cwA[j] = sum_k c[k]*W[k][t];  crb[j] = rb[j] + sum_k c[k]*rW[k][j]
__global__ void k_fold_vec(const float* __restrict__ W, const float* __restrict__ rW,
                           const float* __restrict__ c, const float* __restrict__ rb,
                           float* __restrict__ cwA, float* __restrict__ crb) {
    int t = threadIdx.x;  // 256
    if (t < D) {
        float s = 0.f;
        for (int k = 0; k < D; ++k) s += c[k] * W[k * D + t];
        cwA[t] = s;
    } else {
        int j = t - D;
        float s = rb[j];
        for (int k = 0; k < D; ++k) s += c[k] * rW[k * D + j];
        crb[j] = s;
    }
}

// ---------------- MFMA dual GEMM ----------------
// hb (bf16) = (fb @ W0p + add0) * dinv[row]   -- pre-scaled message matrix
// fo (f32)  = relu(fb @ W1p + add1)
// Block 256 thr = 4 waves; tile 128 rows x 128 cols; wave owns 32 rows.
// A staged in LDS (XOR-swizzled 16B units); B frags read straight from
// packed Wp (L2-resident, coalesced 16B/lane).
__global__ __launch_bounds__(256) void k_gemm_mfma(
    const unsigned short* __restrict__ fb,
    const unsigned short* __restrict__ Wp,    // [2][16384] packed frags
    const float* __restrict__ add0, const float* __restrict__ add1,
    const float* __restrict__ dinv,
    unsigned short* __restrict__ hb, float* __restrict__ fo, int N) {
    __shared__ unsigned short As[128 * 128];
    const int t = threadIdx.x;
    const int rowbase = blockIdx.x * 128;

#pragma unroll
    for (int i = 0; i < 8; ++i) {
        int ch = t + i * 256;            // 16B chunk id, 0..2047
        int row = ch >> 4, slot = ch & 15;
        uint4 v = make_uint4(0, 0, 0, 0);
        int gr = rowbase + row;
        if (gr < N) v = *(const uint4*)(fb + (size_t)gr * D + slot * 8);
        *(uint4*)((char*)As + row * 256 + ((slot ^ (row & 7)) << 4)) = v;
    }
    __syncthreads();

    const int wave = t >> 6, l = t & 63;
    const int wrow = wave * 32;
    const int lg = l >> 4, lc = l & 15;

    int rows[2][4];
#pragma unroll
    for (int rf = 0; rf < 2; ++rf)
#pragma unroll
        for (int r = 0; r < 4; ++r)
            rows[rf][r] = rowbase + wrow + rf * 16 + lg * 4 + r;

#pragma unroll 1
    for (int m = 0; m < 2; ++m) {
        const unsigned short* wp = Wp + (m << 14);
        f32x4 acc[2][8];
#pragma unroll
        for (int rf = 0; rf < 2; ++rf)
#pragma unroll
            for (int cf = 0; cf < 8; ++cf) acc[rf][cf] = (f32x4){0.f, 0.f, 0.f, 0.f};

#pragma unroll
        for (int ks = 0; ks < 4; ++ks) {
            const int r0 = wrow + lc;
            const int r1 = wrow + 16 + lc;
            const int s = ks * 4 + lg;
            bf16x8 a0 = *(const bf16x8*)((const char*)As + r0 * 256 + ((s ^ (r0 & 7)) << 4));
            bf16x8 a1 = *(const bf16x8*)((const char*)As + r1 * 256 + ((s ^ (r1 & 7)) << 4));
#pragma unroll
            for (int cf = 0; cf < 8; ++cf) {
                bf16x8 b = *(const bf16x8*)(wp + ((ks * 8 + cf) * 64 + l) * 8);
                acc[0][cf] = __builtin_amdgcn_mfma_f32_16x16x32_bf16(a0, b, acc[0][cf], 0, 0, 0);
                acc[1][cf] = __builtin_amdgcn_mfma_f32_16x16x32_bf16(a1, b, acc[1][cf], 0, 0, 0);
            }
        }

        if (m == 0) {
            float dvv[2][4];
#pragma unroll
            for (int rf = 0; rf < 2; ++rf)
#pragma unroll
                for (int r = 0; r < 4; ++r)
                    dvv[rf][r] = (rows[rf][r] < N) ? dinv[rows[rf][r]] : 0.f;
#pragma unroll
            for (int cf = 0; cf < 8; ++cf) {
                float va = add0[cf * 16 + lc];
#pragma unroll
                for (int rf = 0; rf < 2; ++rf)
#pragma unroll
                    for (int r = 0; r < 4; ++r) {
                        int g = rows[rf][r];
                        if (g < N)
                            hb[(size_t)g * D + cf * 16 + lc] =
                                f2bf((acc[rf][cf][r] + va) * dvv[rf][r]);
                    }
            }
        } else {
#pragma unroll
            for (int cf = 0; cf < 8; ++cf) {
                float va = add1[cf * 16 + lc];
#pragma unroll
                for (int rf = 0; rf < 2; ++rf)
#pragma unroll
                    for (int r = 0; r < 4; ++r) {
                        int g = rows[rf][r];
                        if (g < N)
                            fo[(size_t)g * D + cf * 16 + lc] =
                                fmaxf(acc[rf][cf][r] + va, 0.f);
                    }
            }
        }
    }
}

// ---------------- aggregation + residual + BN stats ----------------
// 1 node per wave, 4 edges per gather instruction (lane group g=lane>>4).
// CSR padded per node to a multiple of 4 with dummy index N -> zero row.
// Also emits the bf16 activation row (fbout) for the next layer's GEMM.
__global__ __launch_bounds__(256) void k_agg(
    const unsigned short* __restrict__ hb, float* __restrict__ resf,
    unsigned short* __restrict__ fbout,
    const int* __restrict__ roff, const int* __restrict__ csr,
    const float* __restrict__ dinv, const float* __restrict__ bias,
    float* __restrict__ stats, int N) {
    const int tid = threadIdx.x;
    const int lane = tid & 63;
    const int g = lane >> 4;           // edge slot within quad
    const int li = lane & 15;          // 16-lane column group
    const int cs = li * 8;             // 8 bf16 columns per lane
    const int wid = (blockIdx.x * blockDim.x + tid) >> 6;
    const int nw = (gridDim.x * blockDim.x) >> 6;

    float bv[8];
#pragma unroll
    for (int k = 0; k < 8; ++k) bv[k] = bias[cs + k];

    float s8[8], q8[8];
#pragma unroll
    for (int k = 0; k < 8; ++k) { s8[k] = 0.f; q8[k] = 0.f; }

    for (int v = wid; v < N; v += nw) {
        const int beg = roff[v], end = roff[v + 1];   // multiples of 4
        float acc[8];
#pragma unroll
        for (int k = 0; k < 8; ++k) acc[k] = 0.f;

        for (int e = beg; e < end; e += 4) {
            const int4 u4 = *(const int4*)(csr + e);
            int uu = (g == 0) ? u4.x : (g == 1) ? u4.y : (g == 2) ? u4.z : u4.w;
            const uint4 hv = *(const uint4*)(hb + (size_t)uu * D + cs);
            acc[0] += bf_lo(hv.x); acc[1] += bf_hi(hv.x);
            acc[2] += bf_lo(hv.y); acc[3] += bf_hi(hv.y);
            acc[4] += bf_lo(hv.z); acc[5] += bf_hi(hv.z);
            acc[6] += bf_lo(hv.w); acc[7] += bf_hi(hv.w);
        }

        // fold the 4 edge-group partials
#pragma unroll
        for (int k = 0; k < 8; ++k) {
            acc[k] += __shfl_xor(acc[k], 16);
            acc[k] += __shfl_xor(acc[k], 32);
        }

        const float dv = dinv[v];
        const uint4 hs = *(const uint4*)(hb + (size_t)v * D + cs);
        float hsv[8];
        hsv[0] = bf_lo(hs.x); hsv[1] = bf_hi(hs.x);
        hsv[2] = bf_lo(hs.y); hsv[3] = bf_hi(hs.y);
        hsv[4] = bf_lo(hs.z); hsv[5] = bf_hi(hs.z);
        hsv[6] = bf_lo(hs.w); hsv[7] = bf_hi(hs.w);

        const float4 r0 = *(const float4*)(resf + (size_t)v * D + cs);
        const float4 r1 = *(const float4*)(resf + (size_t)v * D + cs + 4);
        float ox[8];
        ox[0] = (acc[0] + hsv[0]) * dv + bv[0] + r0.x;
        ox[1] = (acc[1] + hsv[1]) * dv + bv[1] + r0.y;
        ox[2] = (acc[2] + hsv[2]) * dv + bv[2] + r0.z;
        ox[3] = (acc[3] + hsv[3]) * dv + bv[3] + r0.w;
        ox[4] = (acc[4] + hsv[4]) * dv + bv[4] + r1.x;
        ox[5] = (acc[5] + hsv[5]) * dv + bv[5] + r1.y;
        ox[6] = (acc[6] + hsv[6]) * dv + bv[6] + r1.z;
        ox[7] = (acc[7] + hsv[7]) * dv + bv[7] + r1.w;

        if (g == 0) {
            *(float4*)(resf + (size_t)v * D + cs) =
                make_float4(ox[0], ox[1], ox[2], ox[3]);
            *(float4*)(resf + (size_t)v * D + cs + 4) =
                make_float4(ox[4], ox[5], ox[6], ox[7]);
            uint4 p;
            p.x = (unsigned int)f2bf(ox[0]) | ((unsigned int)f2bf(ox[1]) << 16);
            p.y = (unsigned int)f2bf(ox[2]) | ((unsigned int)f2bf(ox[3]) << 16);
            p.z = (unsigned int)f2bf(ox[4]) | ((unsigned int)f2bf(ox[5]) << 16);
            p.w = (unsigned int)f2bf(ox[6]) | ((unsigned int)f2bf(ox[7]) << 16);
            *(uint4*)(fbout + (size_t)v * D + cs) = p;
#pragma unroll
            for (int k = 0; k < 8; ++k) { s8[k] += ox[k]; q8[k] += ox[k] * ox[k]; }
        }
    }

    // block-level BN-stats reduction: lanes g==0 hold valid partials
    __shared__ float sred[4][16][8];
    __shared__ float qred[4][16][8];
    const int w = tid >> 6;
    if (g == 0) {
#pragma unroll
        for (int k = 0; k < 8; ++k) { sred[w][li][k] = s8[k]; qred[w][li][k] = q8[k]; }
    }
    __syncthreads();
    if (tid < D) {
        const int col = tid;
        float ts = 0.f, tq = 0.f;
#pragma unroll
        for (int ww = 0; ww < 4; ++ww) {
            ts += sred[ww][col >> 3][col & 7];
            tq += qred[ww][col >> 3][col & 7];
        }
        atomicAdd(&stats[col], ts);
        atomicAdd(&stats[D + col], tq);
    }
}

__global__ void k_bnfin(const float* __restrict__ stats, const float* __restrict__ gamma,
                        const float* __restrict__ beta,
                        float* __restrict__ a_next, float* __restrict__ c_next, float invN) {
    int t = threadIdx.x;  // 128
    float mean = stats[t] * invN;
    float var = stats[D + t] * invN - mean * mean;
    float rs = rsqrtf(var + BN_EPS);
    float a = gamma[t] * rs;
    a_next[t] = a;
    c_next[t] = beta[t] - mean * a;
}

// out[g] = (sum_{v in g} f[v]) * a + cnt_g * c
__global__ void k_pool(const float* __restrict__ f, const int* __restrict__ goff,
                       const float* __restrict__ a, const float* __restrict__ c,
                       float* __restrict__ out) {
    int g = blockIdx.x, t = threadIdx.x;  // 128 threads
    int beg = goff[g], end = goff[g + 1];
    float acc = 0.f;
    for (int v = beg; v < end; ++v) acc += f[(size_t)v * D + t];
    out[(size_t)g * D + t] = acc * a[t] + (float)(end - beg) * c[t];
}

// ---------------- launcher ----------------

extern "C" void kernel_launch(void* const* d_in, const int* in_sizes, int n_in,
                              void* d_out, int out_size, void* d_ws, size_t ws_size,
                              hipStream_t stream) {
    const float* x      = (const float*)d_in[0];
    const int*   ei     = (const int*)d_in[1];
    const int*   batch  = (const int*)d_in[2];
    const float* Ws     = (const float*)d_in[3];
    const float* bs     = (const float*)d_in[4];
    const float* rWs    = (const float*)d_in[5];
    const float* rbs    = (const float*)d_in[6];
    const float* gammas = (const float*)d_in[7];
    const float* betas  = (const float*)d_in[8];
    float* out = (float*)d_out;

    const int N = in_sizes[2];
    const int E = in_sizes[1] / 2;
    const int G = out_size / D;
    const int* src = ei;
    const int* dst = ei + E;
    const int EP = E + 4 * N;   // padded-CSR upper bound

    char* ws = (char*)d_ws;
    size_t off = 0;
    auto alloc = [&](size_t bytes) -> char* {
        char* p = ws + off;
        off += (bytes + 255) & ~(size_t)255;
        return p;
    };
    unsigned short* hb = (unsigned short*)alloc((size_t)(N + 1) * D * 2);
    unsigned short* fb = (unsigned short*)alloc((size_t)N * D * 2);
    float* R0   = (float*)alloc((size_t)N * D * 4);
    int*   csr  = (int*)alloc((size_t)EP * 4);
    int*   roff = (int*)alloc((size_t)(N + 1) * 4);
    int*   cur  = (int*)alloc((size_t)N * 4);
    int*   cnt  = (int*)alloc((size_t)N * 4);
    float* dinv = (float*)alloc((size_t)N * 4);
    int*   gcnt = (int*)alloc((size_t)G * 4);
    int*   goff = (int*)alloc((size_t)(G + 1) * 4);
    int*   bsum = (int*)alloc(256 * 4);
    int*   bbase= (int*)alloc(256 * 4);
    float* stats= (float*)alloc((size_t)NLAYERS * 2 * D * 4);
    float* aarr = (float*)alloc((size_t)(NLAYERS + 1) * D * 4);
    float* carr = (float*)alloc((size_t)(NLAYERS + 1) * D * 4);
    unsigned short* Wp = (unsigned short*)alloc((size_t)2 * D * D * 2);
    float* cwA  = (float*)alloc(D * 4);
    float* crb  = (float*)alloc(D * 4);
    (void)ws_size;

    hipMemsetAsync(cnt, 0, (size_t)N * 4, stream);
    hipMemsetAsync(gcnt, 0, (size_t)G * 4, stream);
    hipMemsetAsync(stats, 0, (size_t)NLAYERS * 2 * D * 4, stream);

    k_hist_edges<<<(E + 255) / 256, 256, 0, stream>>>(dst, cnt, E);
    k_hist_batch<<<(N + 255) / 256, 256, 0, stream>>>(batch, gcnt, N);
    k_dinv<<<(N + 255) / 256, 256, 0, stream>>>(cnt, dinv, N);
    k_csr_init<<<(EP + 255) / 256, 256, 0, stream>>>(csr, EP, N);
    k_zrow<<<1, D, 0, stream>>>(hb, N);
    k_xb<<<(N * (D / 8) + 255) / 256, 256, 0, stream>>>(x, fb, N * (D / 8));

    int nb = (N + 1023) / 1024;
    k_scan_partial<<<nb, 256, 0, stream>>>(cnt, bsum, N);
    k_scan_small<<<1, 256, 0, stream>>>(bsum, bbase, nb);
    k_scan_apply<<<nb, 256, 0, stream>>>(cnt, bbase, roff, cur, N);
    k_gscan<<<1, 256, 0, stream>>>(gcnt, goff, G, N);
    k_fill<<<(E + 255) / 256, 256, 0, stream>>>(src, dst, cur, csr, E);
    k_init_ac<<<1, D, 0, stream>>>(aarr, carr);

    for (int l = 0; l < NLAYERS; ++l) {
        const float* W  = Ws + (size_t)l * D * D;
        const float* rW = rWs + (size_t)l * D * D;
        const float* aP = aarr + (size_t)l * D;
        const float* cP = carr + (size_t)l * D;

        k_pack_w<<<128, 256, 0, stream>>>(W, rW, aP, Wp);
        k_fold_vec<<<1, 256, 0, stream>>>(W, rW, cP, rbs + (size_t)l * D, cwA, crb);

        k_gemm_mfma<<<(N + 127) / 128, 256, 0, stream>>>(fb, Wp, cwA, crb, dinv,
                                                         hb, R0, N);
        k_agg<<<4096, 256, 0, stream>>>(hb, R0, fb, roff, csr, dinv, bs + (size_t)l * D,
                                        stats + (size_t)l * 2 * D, N);
        k_bnfin<<<1, D, 0, stream>>>(stats + (size_t)l * 2 * D, gammas + (size_t)l * D,
                                     betas + (size_t)l * D,
                                     aarr + (size_t)(l + 1) * D, carr + (size_t)(l + 1) * D,
                                     1.0f / (float)N);
    }

    k_pool<<<G, D, 0, stream>>>(R0, goff, aarr + (size_t)NLAYERS * D,
                                carr + (size_t)NLAYERS * D, out);
}

// Round 8
// 943.543 us; speedup vs baseline: 1.5861x; 1.0231x over previous
//
#include <hip/hip_runtime.h>

#define D 128
#define NLAYERS 3
#define BN_EPS 1e-5f

typedef short bf16x8 __attribute__((ext_vector_type(8)));
typedef float f32x4 __attribute__((ext_vector_type(4)));

__device__ __forceinline__ unsigned short f2bf(float f) {
    unsigned int u = __float_as_uint(f);
    u += 0x7FFFu + ((u >> 16) & 1u);   // round-to-nearest-even
    return (unsigned short)(u >> 16);
}
__device__ __forceinline__ float bf_lo(unsigned int u) {
    return __uint_as_float(u << 16);
}
__device__ __forceinline__ float bf_hi(unsigned int u) {
    return __uint_as_float(u & 0xFFFF0000u);
}

// ---------------- setup kernels ----------------

__global__ void k_hist_edges(const int* __restrict__ dst, int* __restrict__ cnt, int E) {
    int i = blockIdx.x * blockDim.x + threadIdx.x;
    if (i < E) atomicAdd(&cnt[dst[i]], 1);
}

__global__ void k_hist_batch(const int* __restrict__ batch, int* __restrict__ gcnt, int N) {
    int i = blockIdx.x * blockDim.x + threadIdx.x;
    if (i < N) atomicAdd(&gcnt[batch[i]], 1);
}

__global__ void k_dinv(const int* __restrict__ cnt, float* __restrict__ dinv, int N) {
    int i = blockIdx.x * blockDim.x + threadIdx.x;
    if (i < N) dinv[i] = rsqrtf((float)(cnt[i] + 1));   // +1 self loop
}

// fill csr with the dummy index N (pad slots resolve to the zero row)
__global__ void k_csr_init(int* __restrict__ csr, int n, int N) {
    int i = blockIdx.x * blockDim.x + threadIdx.x;
    if (i < n) csr[i] = N;
}

// zero the dummy message row N
__global__ void k_zrow(unsigned short* __restrict__ hb, int N) {
    hb[(size_t)N * D + threadIdx.x] = 0;
}

// x (f32) -> fb (bf16), 8 elems/thread
__global__ void k_xb(const float* __restrict__ x, unsigned short* __restrict__ fb, int n8) {
    int i = blockIdx.x * blockDim.x + threadIdx.x;
    if (i < n8) {
        const float4 a = ((const float4*)x)[i * 2];
        const float4 b = ((const float4*)x)[i * 2 + 1];
        uint4 p;
        p.x = (unsigned int)f2bf(a.x) | ((unsigned int)f2bf(a.y) << 16);
        p.y = (unsigned int)f2bf(a.z) | ((unsigned int)f2bf(a.w) << 16);
        p.z = (unsigned int)f2bf(b.x) | ((unsigned int)f2bf(b.y) << 16);
        p.w = (unsigned int)f2bf(b.z) | ((unsigned int)f2bf(b.w) << 16);
        ((uint4*)fb)[i] = p;
    }
}

// partial sums of blocks of 1024 PADDED counts (padded to multiple of 4)
__global__ void k_scan_partial(const int* __restrict__ cnt, int* __restrict__ bsum, int N) {
    __shared__ int sh[256];
    int b = blockIdx.x, t = threadIdx.x;
    int base = b * 1024 + t * 4;
    int s = 0;
#pragma unroll
    for (int i = 0; i < 4; ++i) {
        int idx = base + i;
        int cv = (idx < N) ? cnt[idx] : 0;
        s += (cv + 3) & ~3;
    }
    sh[t] = s;
    for (int ofs = 128; ofs > 0; ofs >>= 1) {
        __syncthreads();
        if (t < ofs) sh[t] += sh[t + ofs];
    }
    __syncthreads();
    if (t == 0) bsum[b] = sh[0];
}

// exclusive scan of up to 256 block sums (single block, 256 threads)
__global__ void k_scan_small(const int* __restrict__ bsum, int* __restrict__ bbase, int nb) {
    __shared__ int sh[256];
    int t = threadIdx.x;
    int v = (t < nb) ? bsum[t] : 0;
    sh[t] = v;
    __syncthreads();
    for (int ofs = 1; ofs < 256; ofs <<= 1) {
        int vv = (t >= ofs) ? sh[t - ofs] : 0;
        __syncthreads();
        sh[t] += vv;
        __syncthreads();
    }
    bbase[t] = sh[t] - v;   // exclusive
}

__global__ void k_scan_apply(const int* __restrict__ cnt, const int* __restrict__ bbase,
                             int* __restrict__ roff, int* __restrict__ cur, int N) {
    __shared__ int sh[256];
    int b = blockIdx.x, t = threadIdx.x;
    int base = b * 1024 + t * 4;
    int v[4]; int s = 0;
#pragma unroll
    for (int i = 0; i < 4; ++i) {
        int cv = (base + i < N) ? cnt[base + i] : 0;
        v[i] = (cv + 3) & ~3;
        s += v[i];
    }
    sh[t] = s;
    __syncthreads();
    for (int ofs = 1; ofs < 256; ofs <<= 1) {
        int vv = (t >= ofs) ? sh[t - ofs] : 0;
        __syncthreads();
        sh[t] += vv;
        __syncthreads();
    }
    int o = bbase[b] + sh[t] - s;
#pragma unroll
    for (int i = 0; i < 4; ++i) {
        int idx = base + i;
        if (idx < N) {
            roff[idx] = o; cur[idx] = o;
            o += v[i];
            if (idx == N - 1) roff[N] = o;
        }
    }
}

// scan of graph counts (G <= 1024), single block of 256 threads
__global__ void k_gscan(const int* __restrict__ gcnt, int* __restrict__ goff, int G, int N) {
    __shared__ int sh[256];
    int t = threadIdx.x;
    int base = t * 4;
    int v[4]; int s = 0;
#pragma unroll
    for (int i = 0; i < 4; ++i) { v[i] = (base + i < G) ? gcnt[base + i] : 0; s += v[i]; }
    sh[t] = s;
    __syncthreads();
    for (int ofs = 1; ofs < 256; ofs <<= 1) {
        int vv = (t >= ofs) ? sh[t - ofs] : 0;
        __syncthreads();
        sh[t] += vv;
        __syncthreads();
    }
    int o = sh[t] - s;
#pragma unroll
    for (int i = 0; i < 4; ++i) {
        int idx = base + i;
        if (idx < G) { goff[idx] = o; o += v[i]; }
    }
    if (t == 255) goff[G] = N;
}

__global__ void k_fill(const int* __restrict__ src, const int* __restrict__ dst,
                       int* __restrict__ cur, int* __restrict__ csr, int E) {
    int i = blockIdx.x * blockDim.x + threadIdx.x;
    if (i < E) {
        int p = atomicAdd(&cur[dst[i]], 1);
        csr[p] = src[i];
    }
}

__global__ void k_init_ac(float* __restrict__ a, float* __restrict__ c) {
    int t = threadIdx.x;
    a[t] = 1.0f; c[t] = 0.0f;
}

// Pack a[k]*W[k][c] (and a[k]*rW) into the MFMA fragment layout, bf16.
// Fragment (used as the A operand = W^T): lane l holds feat=l&15,
// k=(l>>4)*8+j (j=0..7). Wp elem index = frag*512 + lane*8 + j,
// frag = (k>>5)*8 + (c>>4).
__global__ void k_pack_w(const float* __restrict__ W, const float* __restrict__ rW,
                         const float* __restrict__ a, unsigned short* __restrict__ Wp) {
    int idx = blockIdx.x * 256 + threadIdx.x;       // 0..32767
    int m = idx >> 14;
    int i = idx & 16383;
    int k = i >> 7, c = i & 127;
    const float* src = m ? rW : W;
    float v = a[k] * src[i];
    int frag = ((k >> 5) << 3) + (c >> 4);
    int lane = (((k & 31) >> 3) << 4) + (c & 15);
    int j = k & 7;
    Wp[(m << 14) + frag * 512 + lane * 8 + j] = f2bf(v);
}

// cwA[j] = sum_k c[k]*W[k][t];  crb[j] = rb[j] + sum_k c[k]*rW[k][j]
__global__ void k_fold_vec(const float* __restrict__ W, const float* __restrict__ rW,
                           const float* __restrict__ c, const float* __restrict__ rb,
                           float* __restrict__ cwA, float* __restrict__ crb) {
    int t = threadIdx.x;  // 256
    if (t < D) {
        float s = 0.f;
        for (int k = 0; k < D; ++k) s += c[k] * W[k * D + t];
        cwA[t] = s;
    } else {
        int j = t - D;
        float s = rb[j];
        for (int k = 0; k < D; ++k) s += c[k] * rW[k * D + j];
        crb[j] = s;
    }
}

// ---------------- MFMA dual GEMM (transposed-C epilogue) ----------------
// hb (bf16) = (fb @ W0 + add0) * dinv[row] ; fo (f32) = relu(fb @ W1 + add1)
// Compute D^T = W^T(A) x f^T(B): out tile row=feature, col=node. Each lane
// then owns 4 CONSECUTIVE FEATURES of one node per acc reg -> vector stores
// (16x8B + 16x16B per thread instead of 128 scalar stores).
__global__ __launch_bounds__(256) void k_gemm_mfma(
    const unsigned short* __restrict__ fb,
    const unsigned short* __restrict__ Wp,    // [2][16384] packed frags
    const float* __restrict__ add0, const float* __restrict__ add1,
    const float* __restrict__ dinv,
    unsigned short* __restrict__ hb, float* __restrict__ fo, int N) {
    __shared__ unsigned short As[128 * 128];
    const int t = threadIdx.x;
    const int rowbase = blockIdx.x * 128;

#pragma unroll
    for (int i = 0; i < 8; ++i) {
        int ch = t + i * 256;            // 16B chunk id, 0..2047
        int row = ch >> 4, slot = ch & 15;
        uint4 v = make_uint4(0, 0, 0, 0);
        int gr = rowbase + row;
        if (gr < N) v = *(const uint4*)(fb + (size_t)gr * D + slot * 8);
        *(uint4*)((char*)As + row * 256 + ((slot ^ (row & 7)) << 4)) = v;
    }
    __syncthreads();

    const int wave = t >> 6, l = t & 63;
    const int wrow = wave * 32;
    const int lg = l >> 4, lc = l & 15;

    const int g0 = rowbase + wrow + lc;        // node for nf=0
    const int g1 = g0 + 16;                    // node for nf=1
    const int f0 = lg * 4;                     // feature base within col-frag

#pragma unroll 1
    for (int m = 0; m < 2; ++m) {
        const unsigned short* wp = Wp + (m << 14);
        f32x4 acc[2][8];
#pragma unroll
        for (int nf = 0; nf < 2; ++nf)
#pragma unroll
            for (int cf = 0; cf < 8; ++cf) acc[nf][cf] = (f32x4){0.f, 0.f, 0.f, 0.f};

#pragma unroll
        for (int ks = 0; ks < 4; ++ks) {
            const int r0 = wrow + lc;
            const int r1 = wrow + 16 + lc;
            const int s = ks * 4 + lg;
            bf16x8 a0 = *(const bf16x8*)((const char*)As + r0 * 256 + ((s ^ (r0 & 7)) << 4));
            bf16x8 a1 = *(const bf16x8*)((const char*)As + r1 * 256 + ((s ^ (r1 & 7)) << 4));
#pragma unroll
            for (int cf = 0; cf < 8; ++cf) {
                bf16x8 b = *(const bf16x8*)(wp + ((ks * 8 + cf) * 64 + l) * 8);
                // W frag as A (row=feature), activation frag as B (col=node)
                acc[0][cf] = __builtin_amdgcn_mfma_f32_16x16x32_bf16(b, a0, acc[0][cf], 0, 0, 0);
                acc[1][cf] = __builtin_amdgcn_mfma_f32_16x16x32_bf16(b, a1, acc[1][cf], 0, 0, 0);
            }
        }

        if (m == 0) {
            const float dv0 = (g0 < N) ? dinv[g0] : 0.f;
            const float dv1 = (g1 < N) ? dinv[g1] : 0.f;
#pragma unroll
            for (int cf = 0; cf < 8; ++cf) {
                const int fx = cf * 16 + f0;
                const float4 va = *(const float4*)(add0 + fx);
                if (g0 < N) {
                    uint2 p;
                    p.x = (unsigned int)f2bf((acc[0][cf][0] + va.x) * dv0) |
                          ((unsigned int)f2bf((acc[0][cf][1] + va.y) * dv0) << 16);
                    p.y = (unsigned int)f2bf((acc[0][cf][2] + va.z) * dv0) |
                          ((unsigned int)f2bf((acc[0][cf][3] + va.w) * dv0) << 16);
                    *(uint2*)(hb + (size_t)g0 * D + fx) = p;
                }
                if (g1 < N) {
                    uint2 p;
                    p.x = (unsigned int)f2bf((acc[1][cf][0] + va.x) * dv1) |
                          ((unsigned int)f2bf((acc[1][cf][1] + va.y) * dv1) << 16);
                    p.y = (unsigned int)f2bf((acc[1][cf][2] + va.z) * dv1) |
                          ((unsigned int)f2bf((acc[1][cf][3] + va.w) * dv1) << 16);
                    *(uint2*)(hb + (size_t)g1 * D + fx) = p;
                }
            }
        } else {
#pragma unroll
            for (int cf = 0; cf < 8; ++cf) {
                const int fx = cf * 16 + f0;
                const float4 va = *(const float4*)(add1 + fx);
                if (g0 < N)
                    *(float4*)(fo + (size_t)g0 * D + fx) = make_float4(
                        fmaxf(acc[0][cf][0] + va.x, 0.f), fmaxf(acc[0][cf][1] + va.y, 0.f),
                        fmaxf(acc[0][cf][2] + va.z, 0.f), fmaxf(acc[0][cf][3] + va.w, 0.f));
                if (g1 < N)
                    *(float4*)(fo + (size_t)g1 * D + fx) = make_float4(
                        fmaxf(acc[1][cf][0] + va.x, 0.f), fmaxf(acc[1][cf][1] + va.y, 0.f),
                        fmaxf(acc[1][cf][2] + va.z, 0.f), fmaxf(acc[1][cf][3] + va.w, 0.f));
            }
        }
    }
}

// ---------------- aggregation + residual + BN stats ----------------
// 1 node per wave, 4 edges per gather instruction (lane group g=lane>>4).
// CSR padded per node to a multiple of 4 with dummy index N -> zero row.
// Also emits the bf16 activation row (fbout) for the next layer's GEMM.
__global__ __launch_bounds__(256) void k_agg(
    const unsigned short* __restrict__ hb, float* __restrict__ resf,
    unsigned short* __restrict__ fbout,
    const int* __restrict__ roff, const int* __restrict__ csr,
    const float* __restrict__ dinv, const float* __restrict__ bias,
    float* __restrict__ stats, int N) {
    const int tid = threadIdx.x;
    const int lane = tid & 63;
    const int g = lane >> 4;           // edge slot within quad
    const int li = lane & 15;          // 16-lane column group
    const int cs = li * 8;             // 8 bf16 columns per lane
    const int wid = (blockIdx.x * blockDim.x + tid) >> 6;
    const int nw = (gridDim.x * blockDim.x) >> 6;

    float bv[8];
#pragma unroll
    for (int k = 0; k < 8; ++k) bv[k] = bias[cs + k];

    float s8[8], q8[8];
#pragma unroll
    for (int k = 0; k < 8; ++k) { s8[k] = 0.f; q8[k] = 0.f; }

    for (int v = wid; v < N; v += nw) {
        const int beg = roff[v], end = roff[v + 1];   // multiples of 4
        float acc[8];
#pragma unroll
        for (int k = 0; k < 8; ++k) acc[k] = 0.f;

        for (int e = beg; e < end; e += 4) {
            const int4 u4 = *(const int4*)(csr + e);
            int uu = (g == 0) ? u4.x : (g == 1) ? u4.y : (g == 2) ? u4.z : u4.w;
            const uint4 hv = *(const uint4*)(hb + (size_t)uu * D + cs);
            acc[0] += bf_lo(hv.x); acc[1] += bf_hi(hv.x);
            acc[2] += bf_lo(hv.y); acc[3] += bf_hi(hv.y);
            acc[4] += bf_lo(hv.z); acc[5] += bf_hi(hv.z);
            acc[6] += bf_lo(hv.w); acc[7] += bf_hi(hv.w);
        }

        // fold the 4 edge-group partials
#pragma unroll
        for (int k = 0; k < 8; ++k) {
            acc[k] += __shfl_xor(acc[k], 16);
            acc[k] += __shfl_xor(acc[k], 32);
        }

        const float dv = dinv[v];
        const uint4 hs = *(const uint4*)(hb + (size_t)v * D + cs);
        float hsv[8];
        hsv[0] = bf_lo(hs.x); hsv[1] = bf_hi(hs.x);
        hsv[2] = bf_lo(hs.y); hsv[3] = bf_hi(hs.y);
        hsv[4] = bf_lo(hs.z); hsv[5] = bf_hi(hs.z);
        hsv[6] = bf_lo(hs.w); hsv[7] = bf_hi(hs.w);

        const float4 r0 = *(const float4*)(resf + (size_t)v * D + cs);
        const float4 r1 = *(const float4*)(resf + (size_t)v * D + cs + 4);
        float ox[8];
        ox[0] = (acc[0] + hsv[0]) * dv + bv[0] + r0.x;
        ox[1] = (acc[1] + hsv[1]) * dv + bv[1] + r0.y;
        ox[2] = (acc[2] + hsv[2]) * dv + bv[2] + r0.z;
        ox[3] = (acc[3] + hsv[3]) * dv + bv[3] + r0.w;
        ox[4] = (acc[4] + hsv[4]) * dv + bv[4] + r1.x;
        ox[5] = (acc[5] + hsv[5]) * dv + bv[5] + r1.y;
        ox[6] = (acc[6] + hsv[6]) * dv + bv[6] + r1.z;
        ox[7] = (acc[7] + hsv[7]) * dv + bv[7] + r1.w;

        if (g == 0) {
            *(float4*)(resf + (size_t)v * D + cs) =
                make_float4(ox[0], ox[1], ox[2], ox[3]);
            *(float4*)(resf + (size_t)v * D + cs + 4) =
                make_float4(ox[4], ox[5], ox[6], ox[7]);
            uint4 p;
            p.x = (unsigned int)f2bf(ox[0]) | ((unsigned int)f2bf(ox[1]) << 16);
            p.y = (unsigned int)f2bf(ox[2]) | ((unsigned int)f2bf(ox[3]) << 16);
            p.z = (unsigned int)f2bf(ox[4]) | ((unsigned int)f2bf(ox[5]) << 16);
            p.w = (unsigned int)f2bf(ox[6]) | ((unsigned int)f2bf(ox[7]) << 16);
            *(uint4*)(fbout + (size_t)v * D + cs) = p;
#pragma unroll
            for (int k = 0; k < 8; ++k) { s8[k] += ox[k]; q8[k] += ox[k] * ox[k]; }
        }
    }

    // block-level BN-stats reduction: lanes g==0 hold valid partials
    __shared__ float sred[4][16][8];
    __shared__ float qred[4][16][8];
    const int w = tid >> 6;
    if (g == 0) {
#pragma unroll
        for (int k = 0; k < 8; ++k) { sred[w][li][k] = s8[k]; qred[w][li][k] = q8[k]; }
    }
    __syncthreads();
    if (tid < D) {
        const int col = tid;
        float ts = 0.f, tq = 0.f;
#pragma unroll
        for (int ww = 0; ww < 4; ++ww) {
            ts += sred[ww][col >> 3][col & 7];
            tq += qred[ww][col >> 3][col & 7];
        }
        atomicAdd(&stats[col], ts);
        atomicAdd(&stats[D + col], tq);
    }
}

__global__ void k_bnfin(const float* __restrict__ stats, const float* __restrict__ gamma,
                        const float* __restrict__ beta,
                        float* __restrict__ a_next, float* __restrict__ c_next, float invN) {
    int t = threadIdx.x;  // 128
    float mean = stats[t] * invN;
    float var = stats[D + t] * invN - mean * mean;
    float rs = rsqrtf(var + BN_EPS);
    float a = gamma[t] * rs;
    a_next[t] = a;
    c_next[t] = beta[t] - mean * a;
}

// out[g] = (sum_{v in g} f[v]) * a + cnt_g * c
__global__ void k_pool(const float* __restrict__ f, const int* __restrict__ goff,
                       const float* __restrict__ a, const float* __restrict__ c,
                       float* __restrict__ out) {
    int g = blockIdx.x, t = threadIdx.x;  // 128 threads
    int beg = goff[g], end = goff[g + 1];
    float acc = 0.f;
    for (int v = beg; v < end; ++v) acc += f[(size_t)v * D + t];
    out[(size_t)g * D + t] = acc * a[t] + (float)(end - beg) * c[t];
}

// ---------------- launcher ----------------

extern "C" void kernel_launch(void* const* d_in, const int* in_sizes, int n_in,
                              void* d_out, int out_size, void* d_ws, size_t ws_size,
                              hipStream_t stream) {
    const float* x      = (const float*)d_in[0];
    const int*   ei     = (const int*)d_in[1];
    const int*   batch  = (const int*)d_in[2];
    const float* Ws     = (const float*)d_in[3];
    const float* bs     = (const float*)d_in[4];
    const float* rWs    = (const float*)d_in[5];
    const float* rbs    = (const float*)d_in[6];
    const float* gammas = (const float*)d_in[7];
    const float* betas  = (const float*)d_in[8];
    float* out = (float*)d_out;

    const int N = in_sizes[2];
    const int E = in_sizes[1] / 2;
    const int G = out_size / D;
    const int* src = ei;
    const int* dst = ei + E;
    const int EP = E + 4 * N;   // padded-CSR upper bound

    char* ws = (char*)d_ws;
    size_t off = 0;
    auto alloc = [&](size_t bytes) -> char* {
        char* p = ws + off;
        off += (bytes + 255) & ~(size_t)255;
        return p;
    };
    unsigned short* hb = (unsigned short*)alloc((size_t)(N + 1) * D * 2);
    unsigned short* fb = (unsigned short*)alloc((size_t)N * D * 2);
    float* R0   = (float*)alloc((size_t)N * D * 4);
    int*   csr  = (int*)alloc((size_t)EP * 4);
    int*   roff = (int*)alloc((size_t)(N + 1) * 4);
    int*   cur  = (int*)alloc((size_t)N * 4);
    int*   cnt  = (int*)alloc((size_t)N * 4);
    float* dinv = (float*)alloc((size_t)N * 4);
    int*   gcnt = (int*)alloc((size_t)G * 4);
    int*   goff = (int*)alloc((size_t)(G + 1) * 4);
    int*   bsum = (int*)alloc(256 * 4);
    int*   bbase= (int*)alloc(256 * 4);
    float* stats= (float*)alloc((size_t)NLAYERS * 2 * D * 4);
    float* aarr = (float*)alloc((size_t)(NLAYERS + 1) * D * 4);
    float* carr = (float*)alloc((size_t)(NLAYERS + 1) * D * 4);
    unsigned short* Wp = (unsigned short*)alloc((size_t)2 * D * D * 2);
    float* cwA  = (float*)alloc(D * 4);
    float* crb  = (float*)alloc(D * 4);
    (void)ws_size;

    hipMemsetAsync(cnt, 0, (size_t)N * 4, stream);
    hipMemsetAsync(gcnt, 0, (size_t)G * 4, stream);
    hipMemsetAsync(stats, 0, (size_t)NLAYERS * 2 * D * 4, stream);

    k_hist_edges<<<(E + 255) / 256, 256, 0, stream>>>(dst, cnt, E);
    k_hist_batch<<<(N + 255) / 256, 256, 0, stream>>>(batch, gcnt, N);
    k_dinv<<<(N + 255) / 256, 256, 0, stream>>>(cnt, dinv, N);
    k_csr_init<<<(EP + 255) / 256, 256, 0, stream>>>(csr, EP, N);
    k_zrow<<<1, D, 0, stream>>>(hb, N);
    k_xb<<<(N * (D / 8) + 255) / 256, 256, 0, stream>>>(x, fb, N * (D / 8));

    int nb = (N + 1023) / 1024;
    k_scan_partial<<<nb, 256, 0, stream>>>(cnt, bsum, N);
    k_scan_small<<<1, 256, 0, stream>>>(bsum, bbase, nb);
    k_scan_apply<<<nb, 256, 0, stream>>>(cnt, bbase, roff, cur, N);
    k_gscan<<<1, 256, 0, stream>>>(gcnt, goff, G, N);
    k_fill<<<(E + 255) / 256, 256, 0, stream>>>(src, dst, cur, csr, E);
    k_init_ac<<<1, D, 0, stream>>>(aarr, carr);

    for (int l = 0; l < NLAYERS; ++l) {
        const float* W  = Ws + (size_t)l * D * D;
        const float* rW = rWs + (size_t)l * D * D;
        const float* aP = aarr + (size_t)l * D;
        const float* cP = carr + (size_t)l * D;

        k_pack_w<<<128, 256, 0, stream>>>(W, rW, aP, Wp);
        k_fold_vec<<<1, 256, 0, stream>>>(W, rW, cP, rbs + (size_t)l * D, cwA, crb);

        k_gemm_mfma<<<(N + 127) / 128, 256, 0, stream>>>(fb, Wp, cwA, crb, dinv,
                                                         hb, R0, N);
        k_agg<<<4096, 256, 0, stream>>>(hb, R0, fb, roff, csr, dinv, bs + (size_t)l * D,
                                        stats + (size_t)l * 2 * D, N);
        k_bnfin<<<1, D, 0, stream>>>(stats + (size_t)l * 2 * D, gammas + (size_t)l * D,
                                     betas + (size_t)l * D,
                                     aarr + (size_t)(l + 1) * D, carr + (size_t)(l + 1) * D,
                                     1.0f / (float)N);
    }

    k_pool<<<G, D, 0, stream>>>(R0, goff, aarr + (size_t)NLAYERS * D,
                                carr + (size_t)NLAYERS * D, out);
}

// Round 9
// 869.510 us; speedup vs baseline: 1.7212x; 1.0851x over previous
//
#include <hip/hip_runtime.h>

#define D 128
#define NLAYERS 3
#define BN_EPS 1e-5f

typedef short bf16x8 __attribute__((ext_vector_type(8)));
typedef float f32x4 __attribute__((ext_vector_type(4)));

__device__ __forceinline__ unsigned short f2bf(float f) {
    unsigned int u = __float_as_uint(f);
    u += 0x7FFFu + ((u >> 16) & 1u);   // round-to-nearest-even
    return (unsigned short)(u >> 16);
}
__device__ __forceinline__ float bf2f(unsigned short b) {
    return __uint_as_float(((unsigned int)b) << 16);
}
__device__ __forceinline__ float bf_lo(unsigned int u) {
    return __uint_as_float(u << 16);
}
__device__ __forceinline__ float bf_hi(unsigned int u) {
    return __uint_as_float(u & 0xFFFF0000u);
}

// ---------------- setup kernels ----------------

__global__ void k_hist_edges(const int* __restrict__ dst, int* __restrict__ cnt, int E) {
    int i = blockIdx.x * blockDim.x + threadIdx.x;
    if (i < E) atomicAdd(&cnt[dst[i]], 1);
}

__global__ void k_hist_batch(const int* __restrict__ batch, int* __restrict__ gcnt, int N) {
    int i = blockIdx.x * blockDim.x + threadIdx.x;
    if (i < N) atomicAdd(&gcnt[batch[i]], 1);
}

__global__ void k_dinv(const int* __restrict__ cnt, float* __restrict__ dinv, int N) {
    int i = blockIdx.x * blockDim.x + threadIdx.x;
    if (i < N) dinv[i] = rsqrtf((float)(cnt[i] + 1));   // +1 self loop
}

// fill csr with the dummy index N (pad slots resolve to the zero row)
__global__ void k_csr_init(int* __restrict__ csr, int n, int N) {
    int i = blockIdx.x * blockDim.x + threadIdx.x;
    if (i < n) csr[i] = N;
}

// zero the dummy message row N
__global__ void k_zrow(unsigned short* __restrict__ hb, int N) {
    hb[(size_t)N * D + threadIdx.x] = 0;
}

// x (f32) -> fb (bf16), 8 elems/thread
__global__ void k_xb(const float* __restrict__ x, unsigned short* __restrict__ fb, int n8) {
    int i = blockIdx.x * blockDim.x + threadIdx.x;
    if (i < n8) {
        const float4 a = ((const float4*)x)[i * 2];
        const float4 b = ((const float4*)x)[i * 2 + 1];
        uint4 p;
        p.x = (unsigned int)f2bf(a.x) | ((unsigned int)f2bf(a.y) << 16);
        p.y = (unsigned int)f2bf(a.z) | ((unsigned int)f2bf(a.w) << 16);
        p.z = (unsigned int)f2bf(b.x) | ((unsigned int)f2bf(b.y) << 16);
        p.w = (unsigned int)f2bf(b.z) | ((unsigned int)f2bf(b.w) << 16);
        ((uint4*)fb)[i] = p;
    }
}

// partial sums of blocks of 1024 PADDED counts (padded to multiple of 4)
__global__ void k_scan_partial(const int* __restrict__ cnt, int* __restrict__ bsum, int N) {
    __shared__ int sh[256];
    int b = blockIdx.x, t = threadIdx.x;
    int base = b * 1024 + t * 4;
    int s = 0;
#pragma unroll
    for (int i = 0; i < 4; ++i) {
        int idx = base + i;
        int cv = (idx < N) ? cnt[idx] : 0;
        s += (cv + 3) & ~3;
    }
    sh[t] = s;
    for (int ofs = 128; ofs > 0; ofs >>= 1) {
        __syncthreads();
        if (t < ofs) sh[t] += sh[t + ofs];
    }
    __syncthreads();
    if (t == 0) bsum[b] = sh[0];
}

// exclusive scan of up to 256 block sums (single block, 256 threads)
__global__ void k_scan_small(const int* __restrict__ bsum, int* __restrict__ bbase, int nb) {
    __shared__ int sh[256];
    int t = threadIdx.x;
    int v = (t < nb) ? bsum[t] : 0;
    sh[t] = v;
    __syncthreads();
    for (int ofs = 1; ofs < 256; ofs <<= 1) {
        int vv = (t >= ofs) ? sh[t - ofs] : 0;
        __syncthreads();
        sh[t] += vv;
        __syncthreads();
    }
    bbase[t] = sh[t] - v;   // exclusive
}

__global__ void k_scan_apply(const int* __restrict__ cnt, const int* __restrict__ bbase,
                             int* __restrict__ roff, int* __restrict__ cur, int N) {
    __shared__ int sh[256];
    int b = blockIdx.x, t = threadIdx.x;
    int base = b * 1024 + t * 4;
    int v[4]; int s = 0;
#pragma unroll
    for (int i = 0; i < 4; ++i) {
        int cv = (base + i < N) ? cnt[base + i] : 0;
        v[i] = (cv + 3) & ~3;
        s += v[i];
    }
    sh[t] = s;
    __syncthreads();
    for (int ofs = 1; ofs < 256; ofs <<= 1) {
        int vv = (t >= ofs) ? sh[t - ofs] : 0;
        __syncthreads();
        sh[t] += vv;
        __syncthreads();
    }
    int o = bbase[b] + sh[t] - s;
#pragma unroll
    for (int i = 0; i < 4; ++i) {
        int idx = base + i;
        if (idx < N) {
            roff[idx] = o; cur[idx] = o;
            o += v[i];
            if (idx == N - 1) roff[N] = o;
        }
    }
}

// scan of graph counts (G <= 1024), single block of 256 threads
__global__ void k_gscan(const int* __restrict__ gcnt, int* __restrict__ goff, int G, int N) {
    __shared__ int sh[256];
    int t = threadIdx.x;
    int base = t * 4;
    int v[4]; int s = 0;
#pragma unroll
    for (int i = 0; i < 4; ++i) { v[i] = (base + i < G) ? gcnt[base + i] : 0; s += v[i]; }
    sh[t] = s;
    __syncthreads();
    for (int ofs = 1; ofs < 256; ofs <<= 1) {
        int vv = (t >= ofs) ? sh[t - ofs] : 0;
        __syncthreads();
        sh[t] += vv;
        __syncthreads();
    }
    int o = sh[t] - s;
#pragma unroll
    for (int i = 0; i < 4; ++i) {
        int idx = base + i;
        if (idx < G) { goff[idx] = o; o += v[i]; }
    }
    if (t == 255) goff[G] = N;
}

__global__ void k_fill(const int* __restrict__ src, const int* __restrict__ dst,
                       int* __restrict__ cur, int* __restrict__ csr, int E) {
    int i = blockIdx.x * blockDim.x + threadIdx.x;
    if (i < E) {
        int p = atomicAdd(&cur[dst[i]], 1);
        csr[p] = src[i];
    }
}

__global__ void k_init_ac(float* __restrict__ a, float* __restrict__ c) {
    int t = threadIdx.x;
    a[t] = 1.0f; c[t] = 0.0f;
}

// Merged: blocks 0..127 pack a[k]*W / a[k]*rW into the MFMA fragment layout;
// block 128 computes cwA/crb (the BN-offset rows).
// Fragment: lane l holds feat=l&15, k=(l>>4)*8+j. Wp idx = frag*512+lane*8+j,
// frag = (k>>5)*8 + (c>>4).
__global__ void k_packfold(const float* __restrict__ W, const float* __restrict__ rW,
                           const float* __restrict__ a, const float* __restrict__ c,
                           const float* __restrict__ rb,
                           unsigned short* __restrict__ Wp,
                           float* __restrict__ cwA, float* __restrict__ crb) {
    if (blockIdx.x < 128) {
        int idx = blockIdx.x * 256 + threadIdx.x;       // 0..32767
        int m = idx >> 14;
        int i = idx & 16383;
        int k = i >> 7, col = i & 127;
        const float* src = m ? rW : W;
        float v = a[k] * src[i];
        int frag = ((k >> 5) << 3) + (col >> 4);
        int lane = (((k & 31) >> 3) << 4) + (col & 15);
        int j = k & 7;
        Wp[(m << 14) + frag * 512 + lane * 8 + j] = f2bf(v);
    } else {
        int t = threadIdx.x;  // 256
        if (t < D) {
            float s = 0.f;
            for (int k = 0; k < D; ++k) s += c[k] * W[k * D + t];
            cwA[t] = s;
        } else {
            int j = t - D;
            float s = rb[j];
            for (int k = 0; k < D; ++k) s += c[k] * rW[k * D + j];
            crb[j] = s;
        }
    }
}

// ---------------- MFMA dual GEMM (transposed-C epilogue) ----------------
// hb (bf16) = (fb @ W0 + add0) * dinv[row] ; rbuf (bf16) = relu(fb @ W1 + add1)
__global__ __launch_bounds__(256) void k_gemm_mfma(
    const unsigned short* __restrict__ fb,
    const unsigned short* __restrict__ Wp,    // [2][16384] packed frags
    const float* __restrict__ add0, const float* __restrict__ add1,
    const float* __restrict__ dinv,
    unsigned short* __restrict__ hb, unsigned short* __restrict__ rbuf, int N) {
    __shared__ unsigned short As[128 * 128];
    const int t = threadIdx.x;
    const int rowbase = blockIdx.x * 128;

#pragma unroll
    for (int i = 0; i < 8; ++i) {
        int ch = t + i * 256;            // 16B chunk id, 0..2047
        int row = ch >> 4, slot = ch & 15;
        uint4 v = make_uint4(0, 0, 0, 0);
        int gr = rowbase + row;
        if (gr < N) v = *(const uint4*)(fb + (size_t)gr * D + slot * 8);
        *(uint4*)((char*)As + row * 256 + ((slot ^ (row & 7)) << 4)) = v;
    }
    __syncthreads();

    const int wave = t >> 6, l = t & 63;
    const int wrow = wave * 32;
    const int lg = l >> 4, lc = l & 15;

    const int g0 = rowbase + wrow + lc;        // node for nf=0
    const int g1 = g0 + 16;                    // node for nf=1
    const int f0 = lg * 4;                     // feature base within col-frag

#pragma unroll 1
    for (int m = 0; m < 2; ++m) {
        const unsigned short* wp = Wp + (m << 14);
        f32x4 acc[2][8];
#pragma unroll
        for (int nf = 0; nf < 2; ++nf)
#pragma unroll
            for (int cf = 0; cf < 8; ++cf) acc[nf][cf] = (f32x4){0.f, 0.f, 0.f, 0.f};

#pragma unroll
        for (int ks = 0; ks < 4; ++ks) {
            const int r0 = wrow + lc;
            const int r1 = wrow + 16 + lc;
            const int s = ks * 4 + lg;
            bf16x8 a0 = *(const bf16x8*)((const char*)As + r0 * 256 + ((s ^ (r0 & 7)) << 4));
            bf16x8 a1 = *(const bf16x8*)((const char*)As + r1 * 256 + ((s ^ (r1 & 7)) << 4));
#pragma unroll
            for (int cf = 0; cf < 8; ++cf) {
                bf16x8 b = *(const bf16x8*)(wp + ((ks * 8 + cf) * 64 + l) * 8);
                // W frag as A (row=feature), activation frag as B (col=node)
                acc[0][cf] = __builtin_amdgcn_mfma_f32_16x16x32_bf16(b, a0, acc[0][cf], 0, 0, 0);
                acc[1][cf] = __builtin_amdgcn_mfma_f32_16x16x32_bf16(b, a1, acc[1][cf], 0, 0, 0);
            }
        }

        if (m == 0) {
            const float dv0 = (g0 < N) ? dinv[g0] : 0.f;
            const float dv1 = (g1 < N) ? dinv[g1] : 0.f;
#pragma unroll
            for (int cf = 0; cf < 8; ++cf) {
                const int fx = cf * 16 + f0;
                const float4 va = *(const float4*)(add0 + fx);
                if (g0 < N) {
                    uint2 p;
                    p.x = (unsigned int)f2bf((acc[0][cf][0] + va.x) * dv0) |
                          ((unsigned int)f2bf((acc[0][cf][1] + va.y) * dv0) << 16);
                    p.y = (unsigned int)f2bf((acc[0][cf][2] + va.z) * dv0) |
                          ((unsigned int)f2bf((acc[0][cf][3] + va.w) * dv0) << 16);
                    *(uint2*)(hb + (size_t)g0 * D + fx) = p;
                }
                if (g1 < N) {
                    uint2 p;
                    p.x = (unsigned int)f2bf((acc[1][cf][0] + va.x) * dv1) |
                          ((unsigned int)f2bf((acc[1][cf][1] + va.y) * dv1) << 16);
                    p.y = (unsigned int)f2bf((acc[1][cf][2] + va.z) * dv1) |
                          ((unsigned int)f2bf((acc[1][cf][3] + va.w) * dv1) << 16);
                    *(uint2*)(hb + (size_t)g1 * D + fx) = p;
                }
            }
        } else {
#pragma unroll
            for (int cf = 0; cf < 8; ++cf) {
                const int fx = cf * 16 + f0;
                const float4 va = *(const float4*)(add1 + fx);
                if (g0 < N) {
                    uint2 p;
                    p.x = (unsigned int)f2bf(fmaxf(acc[0][cf][0] + va.x, 0.f)) |
                          ((unsigned int)f2bf(fmaxf(acc[0][cf][1] + va.y, 0.f)) << 16);
                    p.y = (unsigned int)f2bf(fmaxf(acc[0][cf][2] + va.z, 0.f)) |
                          ((unsigned int)f2bf(fmaxf(acc[0][cf][3] + va.w, 0.f)) << 16);
                    *(uint2*)(rbuf + (size_t)g0 * D + fx) = p;
                }
                if (g1 < N) {
                    uint2 p;
                    p.x = (unsigned int)f2bf(fmaxf(acc[1][cf][0] + va.x, 0.f)) |
                          ((unsigned int)f2bf(fmaxf(acc[1][cf][1] + va.y, 0.f)) << 16);
                    p.y = (unsigned int)f2bf(fmaxf(acc[1][cf][2] + va.z, 0.f)) |
                          ((unsigned int)f2bf(fmaxf(acc[1][cf][3] + va.w, 0.f)) << 16);
                    *(uint2*)(rbuf + (size_t)g1 * D + fx) = p;
                }
            }
        }
    }
}

// ---------------- aggregation + residual + BN stats ----------------
// DUAL-NODE per wave: nodes p and p+half processed in the same uniform loop
// (2 independent gather-quads in flight per iteration; overflow iterations
// gather the L1-hot zero row N). 4 edges per gather instruction as before.
// Reads residual from bf16 rbuf; writes ONLY bf16 fbout + BN stats.
__global__ __launch_bounds__(256) void k_agg(
    const unsigned short* __restrict__ hb, const unsigned short* __restrict__ resb,
    unsigned short* __restrict__ fbout,
    const int* __restrict__ roff, const int* __restrict__ csr,
    const float* __restrict__ dinv, const float* __restrict__ bias,
    float* __restrict__ stats, int N, int half) {
    const int tid = threadIdx.x;
    const int lane = tid & 63;
    const int g = lane >> 4;           // edge slot within quad
    const int li = lane & 15;          // 16-lane column group
    const int cs = li * 8;             // 8 bf16 columns per lane
    const int wid = (blockIdx.x * blockDim.x + tid) >> 6;
    const int nw = (gridDim.x * blockDim.x) >> 6;

    float bv[8];
#pragma unroll
    for (int k = 0; k < 8; ++k) bv[k] = bias[cs + k];

    float s8[8], q8[8];
#pragma unroll
    for (int k = 0; k < 8; ++k) { s8[k] = 0.f; q8[k] = 0.f; }

    for (int p = wid; p < half; p += nw) {
        const int vA = p;
        const int vB = p + half;
        const bool hasB = (vB < N);
        int begA = roff[vA];
        const int qA = (roff[vA + 1] - begA) >> 2;
        int begB = begA, qB = 0;
        if (hasB) { begB = roff[vB]; qB = (roff[vB + 1] - begB) >> 2; }
        int eA = begA, eB = begB;

        float accA[8], accB[8];
#pragma unroll
        for (int k = 0; k < 8; ++k) { accA[k] = 0.f; accB[k] = 0.f; }

        const int mq = (qA > qB) ? qA : qB;
        for (int i = 0; i < mq; ++i) {
            const int4 a4 = *(const int4*)(csr + eA);
            const int4 b4 = *(const int4*)(csr + eB);
            int ua = (g == 0) ? a4.x : (g == 1) ? a4.y : (g == 2) ? a4.z : a4.w;
            int ub = (g == 0) ? b4.x : (g == 1) ? b4.y : (g == 2) ? b4.z : b4.w;
            ua = (i < qA) ? ua : N;
            ub = (i < qB) ? ub : N;
            const uint4 ga = *(const uint4*)(hb + (size_t)ua * D + cs);
            const uint4 gb = *(const uint4*)(hb + (size_t)ub * D + cs);
            accA[0] += bf_lo(ga.x); accA[1] += bf_hi(ga.x);
            accA[2] += bf_lo(ga.y); accA[3] += bf_hi(ga.y);
            accA[4] += bf_lo(ga.z); accA[5] += bf_hi(ga.z);
            accA[6] += bf_lo(ga.w); accA[7] += bf_hi(ga.w);
            accB[0] += bf_lo(gb.x); accB[1] += bf_hi(gb.x);
            accB[2] += bf_lo(gb.y); accB[3] += bf_hi(gb.y);
            accB[4] += bf_lo(gb.z); accB[5] += bf_hi(gb.z);
            accB[6] += bf_lo(gb.w); accB[7] += bf_hi(gb.w);
            if (i + 1 < qA) eA += 4;
            if (i + 1 < qB) eB += 4;
        }

        // fold the 4 edge-group partials
#pragma unroll
        for (int k = 0; k < 8; ++k) {
            accA[k] += __shfl_xor(accA[k], 16);
            accA[k] += __shfl_xor(accA[k], 32);
            accB[k] += __shfl_xor(accB[k], 16);
            accB[k] += __shfl_xor(accB[k], 32);
        }

        // ---- epilogue node A ----
        {
            const float dv = dinv[vA];
            const uint4 hs = *(const uint4*)(hb + (size_t)vA * D + cs);
            const uint4 rr = *(const uint4*)(resb + (size_t)vA * D + cs);
            float ox[8];
            ox[0] = (accA[0] + bf_lo(hs.x)) * dv + bv[0] + bf_lo(rr.x);
            ox[1] = (accA[1] + bf_hi(hs.x)) * dv + bv[1] + bf_hi(rr.x);
            ox[2] = (accA[2] + bf_lo(hs.y)) * dv + bv[2] + bf_lo(rr.y);
            ox[3] = (accA[3] + bf_hi(hs.y)) * dv + bv[3] + bf_hi(rr.y);
            ox[4] = (accA[4] + bf_lo(hs.z)) * dv + bv[4] + bf_lo(rr.z);
            ox[5] = (accA[5] + bf_hi(hs.z)) * dv + bv[5] + bf_hi(rr.z);
            ox[6] = (accA[6] + bf_lo(hs.w)) * dv + bv[6] + bf_lo(rr.w);
            ox[7] = (accA[7] + bf_hi(hs.w)) * dv + bv[7] + bf_hi(rr.w);
            if (g == 0) {
                uint4 pk;
                pk.x = (unsigned int)f2bf(ox[0]) | ((unsigned int)f2bf(ox[1]) << 16);
                pk.y = (unsigned int)f2bf(ox[2]) | ((unsigned int)f2bf(ox[3]) << 16);
                pk.z = (unsigned int)f2bf(ox[4]) | ((unsigned int)f2bf(ox[5]) << 16);
                pk.w = (unsigned int)f2bf(ox[6]) | ((unsigned int)f2bf(ox[7]) << 16);
                *(uint4*)(fbout + (size_t)vA * D + cs) = pk;
#pragma unroll
                for (int k = 0; k < 8; ++k) { s8[k] += ox[k]; q8[k] += ox[k] * ox[k]; }
            }
        }
        // ---- epilogue node B ----
        if (hasB) {
            const float dv = dinv[vB];
            const uint4 hs = *(const uint4*)(hb + (size_t)vB * D + cs);
            const uint4 rr = *(const uint4*)(resb + (size_t)vB * D + cs);
            float ox[8];
            ox[0] = (accB[0] + bf_lo(hs.x)) * dv + bv[0] + bf_lo(rr.x);
            ox[1] = (accB[1] + bf_hi(hs.x)) * dv + bv[1] + bf_hi(rr.x);
            ox[2] = (accB[2] + bf_lo(hs.y)) * dv + bv[2] + bf_lo(rr.y);
            ox[3] = (accB[3] + bf_hi(hs.y)) * dv + bv[3] + bf_hi(rr.y);
            ox[4] = (accB[4] + bf_lo(hs.z)) * dv + bv[4] + bf_lo(rr.z);
            ox[5] = (accB[5] + bf_hi(hs.z)) * dv + bv[5] + bf_hi(rr.z);
            ox[6] = (accB[6] + bf_lo(hs.w)) * dv + bv[6] + bf_lo(rr.w);
            ox[7] = (accB[7] + bf_hi(hs.w)) * dv + bv[7] + bf_hi(rr.w);
            if (g == 0) {
                uint4 pk;
                pk.x = (unsigned int)f2bf(ox[0]) | ((unsigned int)f2bf(ox[1]) << 16);
                pk.y = (unsigned int)f2bf(ox[2]) | ((unsigned int)f2bf(ox[3]) << 16);
                pk.z = (unsigned int)f2bf(ox[4]) | ((unsigned int)f2bf(ox[5]) << 16);
                pk.w = (unsigned int)f2bf(ox[6]) | ((unsigned int)f2bf(ox[7]) << 16);
                *(uint4*)(fbout + (size_t)vB * D + cs) = pk;
#pragma unroll
                for (int k = 0; k < 8; ++k) { s8[k] += ox[k]; q8[k] += ox[k] * ox[k]; }
            }
        }
    }

    // block-level BN-stats reduction: lanes g==0 hold valid partials
    __shared__ float sred[4][16][8];
    __shared__ float qred[4][16][8];
    const int w = tid >> 6;
    if (g == 0) {
#pragma unroll
        for (int k = 0; k < 8; ++k) { sred[w][li][k] = s8[k]; qred[w][li][k] = q8[k]; }
    }
    __syncthreads();
    if (tid < D) {
        const int col = tid;
        float ts = 0.f, tq = 0.f;
#pragma unroll
        for (int ww = 0; ww < 4; ++ww) {
            ts += sred[ww][col >> 3][col & 7];
            tq += qred[ww][col >> 3][col & 7];
        }
        atomicAdd(&stats[col], ts);
        atomicAdd(&stats[D + col], tq);
    }
}

__global__ void k_bnfin(const float* __restrict__ stats, const float* __restrict__ gamma,
                        const float* __restrict__ beta,
                        float* __restrict__ a_next, float* __restrict__ c_next, float invN) {
    int t = threadIdx.x;  // 128
    float mean = stats[t] * invN;
    float var = stats[D + t] * invN - mean * mean;
    float rs = rsqrtf(var + BN_EPS);
    float a = gamma[t] * rs;
    a_next[t] = a;
    c_next[t] = beta[t] - mean * a;
}

// out[g] = (sum_{v in g} fb[v]) * a + cnt_g * c   (fb is bf16)
__global__ void k_pool(const unsigned short* __restrict__ fb, const int* __restrict__ goff,
                       const float* __restrict__ a, const float* __restrict__ c,
                       float* __restrict__ out) {
    int g = blockIdx.x, t = threadIdx.x;  // 128 threads
    int beg = goff[g], end = goff[g + 1];
    float acc = 0.f;
    for (int v = beg; v < end; ++v) acc += bf2f(fb[(size_t)v * D + t]);
    out[(size_t)g * D + t] = acc * a[t] + (float)(end - beg) * c[t];
}

// ---------------- launcher ----------------

extern "C" void kernel_launch(void* const* d_in, const int* in_sizes, int n_in,
                              void* d_out, int out_size, void* d_ws, size_t ws_size,
                              hipStream_t stream) {
    const float* x      = (const float*)d_in[0];
    const int*   ei     = (const int*)d_in[1];
    const int*   batch  = (const int*)d_in[2];
    const float* Ws     = (const float*)d_in[3];
    const float* bs     = (const float*)d_in[4];
    const float* rWs    = (const float*)d_in[5];
    const float* rbs    = (const float*)d_in[6];
    const float* gammas = (const float*)d_in[7];
    const float* betas  = (const float*)d_in[8];
    float* out = (float*)d_out;

    const int N = in_sizes[2];
    const int E = in_sizes[1] / 2;
    const int G = out_size / D;
    const int* src = ei;
    const int* dst = ei + E;
    const int EP = E + 4 * N + 4;   // padded-CSR upper bound (+4 guard)
    const int half = (N + 1) >> 1;

    char* ws = (char*)d_ws;
    size_t off = 0;
    auto alloc = [&](size_t bytes) -> char* {
        char* p = ws + off;
        off += (bytes + 255) & ~(size_t)255;
        return p;
    };
    unsigned short* hb = (unsigned short*)alloc((size_t)(N + 1) * D * 2);
    unsigned short* fb = (unsigned short*)alloc((size_t)N * D * 2);
    unsigned short* rbuf = (unsigned short*)alloc((size_t)N * D * 2);
    int*   csr  = (int*)alloc((size_t)EP * 4);
    int*   roff = (int*)alloc((size_t)(N + 1) * 4);
    int*   cur  = (int*)alloc((size_t)N * 4);
    int*   cnt  = (int*)alloc((size_t)N * 4);
    float* dinv = (float*)alloc((size_t)N * 4);
    int*   gcnt = (int*)alloc((size_t)G * 4);
    int*   goff = (int*)alloc((size_t)(G + 1) * 4);
    int*   bsum = (int*)alloc(256 * 4);
    int*   bbase= (int*)alloc(256 * 4);
    float* stats= (float*)alloc((size_t)NLAYERS * 2 * D * 4);
    float* aarr = (float*)alloc((size_t)(NLAYERS + 1) * D * 4);
    float* carr = (float*)alloc((size_t)(NLAYERS + 1) * D * 4);
    unsigned short* Wp = (unsigned short*)alloc((size_t)2 * D * D * 2);
    float* cwA  = (float*)alloc(D * 4);
    float* crb  = (float*)alloc(D * 4);
    (void)ws_size;

    hipMemsetAsync(cnt, 0, (size_t)N * 4, stream);
    hipMemsetAsync(gcnt, 0, (size_t)G * 4, stream);
    hipMemsetAsync(stats, 0, (size_t)NLAYERS * 2 * D * 4, stream);

    k_hist_edges<<<(E + 255) / 256, 256, 0, stream>>>(dst, cnt, E);
    k_hist_batch<<<(N + 255) / 256, 256, 0, stream>>>(batch, gcnt, N);
    k_dinv<<<(N + 255) / 256, 256, 0, stream>>>(cnt, dinv, N);
    k_csr_init<<<(EP + 255) / 256, 256, 0, stream>>>(csr, EP, N);
    k_zrow<<<1, D, 0, stream>>>(hb, N);
    k_xb<<<(N * (D / 8) + 255) / 256, 256, 0, stream>>>(x, fb, N * (D / 8));

    int nb = (N + 1023) / 1024;
    k_scan_partial<<<nb, 256, 0, stream>>>(cnt, bsum, N);
    k_scan_small<<<1, 256, 0, stream>>>(bsum, bbase, nb);
    k_scan_apply<<<nb, 256, 0, stream>>>(cnt, bbase, roff, cur, N);
    k_gscan<<<1, 256, 0, stream>>>(gcnt, goff, G, N);
    k_fill<<<(E + 255) / 256, 256, 0, stream>>>(src, dst, cur, csr, E);
    k_init_ac<<<1, D, 0, stream>>>(aarr, carr);

    for (int l = 0; l < NLAYERS; ++l) {
        const float* W  = Ws + (size_t)l * D * D;
        const float* rW = rWs + (size_t)l * D * D;
        const float* aP = aarr + (size_t)l * D;
        const float* cP = carr + (size_t)l * D;

        k_packfold<<<129, 256, 0, stream>>>(W, rW, aP, cP, rbs + (size_t)l * D,
                                            Wp, cwA, crb);

        k_gemm_mfma<<<(N + 127) / 128, 256, 0, stream>>>(fb, Wp, cwA, crb, dinv,
                                                         hb, rbuf, N);
        k_agg<<<4096, 256, 0, stream>>>(hb, rbuf, fb, roff, csr, dinv,
                                        bs + (size_t)l * D,
                                        stats + (size_t)l * 2 * D, N, half);
        k_bnfin<<<1, D, 0, stream>>>(stats + (size_t)l * 2 * D, gammas + (size_t)l * D,
                                     betas + (size_t)l * D,
                                     aarr + (size_t)(l + 1) * D, carr + (size_t)(l + 1) * D,
                                     1.0f / (float)N);
    }

    k_pool<<<G, D, 0, stream>>>(fb, goff, aarr + (size_t)NLAYERS * D,
                                carr + (size_t)NLAYERS * D, out);
}

// Round 10
// 828.669 us; speedup vs baseline: 1.8060x; 1.0493x over previous
//
#include <hip/hip_runtime.h>

#define D 128
#define NLAYERS 3
#define BN_EPS 1e-5f

typedef short bf16x8 __attribute__((ext_vector_type(8)));
typedef float f32x4 __attribute__((ext_vector_type(4)));

__device__ __forceinline__ unsigned short f2bf(float f) {
    unsigned int u = __float_as_uint(f);
    u += 0x7FFFu + ((u >> 16) & 1u);   // round-to-nearest-even
    return (unsigned short)(u >> 16);
}
__device__ __forceinline__ float bf2f(unsigned short b) {
    return __uint_as_float(((unsigned int)b) << 16);
}
__device__ __forceinline__ float bf_lo(unsigned int u) {
    return __uint_as_float(u << 16);
}
__device__ __forceinline__ float bf_hi(unsigned int u) {
    return __uint_as_float(u & 0xFFFF0000u);
}

// ---------------- setup kernels ----------------

__global__ void k_hist_edges(const int* __restrict__ dst, int* __restrict__ cnt, int E) {
    int i = blockIdx.x * blockDim.x + threadIdx.x;
    if (i < E) atomicAdd(&cnt[dst[i]], 1);
}

__global__ void k_hist_batch(const int* __restrict__ batch, int* __restrict__ gcnt, int N) {
    int i = blockIdx.x * blockDim.x + threadIdx.x;
    if (i < N) atomicAdd(&gcnt[batch[i]], 1);
}

__global__ void k_dinv(const int* __restrict__ cnt, float* __restrict__ dinv, int N) {
    int i = blockIdx.x * blockDim.x + threadIdx.x;
    if (i < N) dinv[i] = rsqrtf((float)(cnt[i] + 1));   // +1 self loop
}

// fill csr with the dummy index N (pad slots resolve to the zero row)
__global__ void k_csr_init(int* __restrict__ csr, int n, int N) {
    int i = blockIdx.x * blockDim.x + threadIdx.x;
    if (i < n) csr[i] = N;
}

// zero the dummy message row N
__global__ void k_zrow(unsigned short* __restrict__ hb, int N) {
    hb[(size_t)N * D + threadIdx.x] = 0;
}

// x (f32) -> fb (bf16), 8 elems/thread
__global__ void k_xb(const float* __restrict__ x, unsigned short* __restrict__ fb, int n8) {
    int i = blockIdx.x * blockDim.x + threadIdx.x;
    if (i < n8) {
        const float4 a = ((const float4*)x)[i * 2];
        const float4 b = ((const float4*)x)[i * 2 + 1];
        uint4 p;
        p.x = (unsigned int)f2bf(a.x) | ((unsigned int)f2bf(a.y) << 16);
        p.y = (unsigned int)f2bf(a.z) | ((unsigned int)f2bf(a.w) << 16);
        p.z = (unsigned int)f2bf(b.x) | ((unsigned int)f2bf(b.y) << 16);
        p.w = (unsigned int)f2bf(b.z) | ((unsigned int)f2bf(b.w) << 16);
        ((uint4*)fb)[i] = p;
    }
}

// partial sums of blocks of 1024 PADDED counts (padded to multiple of 4)
__global__ void k_scan_partial(const int* __restrict__ cnt, int* __restrict__ bsum, int N) {
    __shared__ int sh[256];
    int b = blockIdx.x, t = threadIdx.x;
    int base = b * 1024 + t * 4;
    int s = 0;
#pragma unroll
    for (int i = 0; i < 4; ++i) {
        int idx = base + i;
        int cv = (idx < N) ? cnt[idx] : 0;
        s += (cv + 3) & ~3;
    }
    sh[t] = s;
    for (int ofs = 128; ofs > 0; ofs >>= 1) {
        __syncthreads();
        if (t < ofs) sh[t] += sh[t + ofs];
    }
    __syncthreads();
    if (t == 0) bsum[b] = sh[0];
}

// exclusive scan of up to 256 block sums (single block, 256 threads)
__global__ void k_scan_small(const int* __restrict__ bsum, int* __restrict__ bbase, int nb) {
    __shared__ int sh[256];
    int t = threadIdx.x;
    int v = (t < nb) ? bsum[t] : 0;
    sh[t] = v;
    __syncthreads();
    for (int ofs = 1; ofs < 256; ofs <<= 1) {
        int vv = (t >= ofs) ? sh[t - ofs] : 0;
        __syncthreads();
        sh[t] += vv;
        __syncthreads();
    }
    bbase[t] = sh[t] - v;   // exclusive
}

__global__ void k_scan_apply(const int* __restrict__ cnt, const int* __restrict__ bbase,
                             int* __restrict__ roff, int* __restrict__ cur, int N) {
    __shared__ int sh[256];
    int b = blockIdx.x, t = threadIdx.x;
    int base = b * 1024 + t * 4;
    int v[4]; int s = 0;
#pragma unroll
    for (int i = 0; i < 4; ++i) {
        int cv = (base + i < N) ? cnt[base + i] : 0;
        v[i] = (cv + 3) & ~3;
        s += v[i];
    }
    sh[t] = s;
    __syncthreads();
    for (int ofs = 1; ofs < 256; ofs <<= 1) {
        int vv = (t >= ofs) ? sh[t - ofs] : 0;
        __syncthreads();
        sh[t] += vv;
        __syncthreads();
    }
    int o = bbase[b] + sh[t] - s;
#pragma unroll
    for (int i = 0; i < 4; ++i) {
        int idx = base + i;
        if (idx < N) {
            roff[idx] = o; cur[idx] = o;
            o += v[i];
            if (idx == N - 1) roff[N] = o;
        }
    }
}

// scan of graph counts (G <= 1024), single block of 256 threads
__global__ void k_gscan(const int* __restrict__ gcnt, int* __restrict__ goff, int G, int N) {
    __shared__ int sh[256];
    int t = threadIdx.x;
    int base = t * 4;
    int v[4]; int s = 0;
#pragma unroll
    for (int i = 0; i < 4; ++i) { v[i] = (base + i < G) ? gcnt[base + i] : 0; s += v[i]; }
    sh[t] = s;
    __syncthreads();
    for (int ofs = 1; ofs < 256; ofs <<= 1) {
        int vv = (t >= ofs) ? sh[t - ofs] : 0;
        __syncthreads();
        sh[t] += vv;
        __syncthreads();
    }
    int o = sh[t] - s;
#pragma unroll
    for (int i = 0; i < 4; ++i) {
        int idx = base + i;
        if (idx < G) { goff[idx] = o; o += v[i]; }
    }
    if (t == 255) goff[G] = N;
}

__global__ void k_fill(const int* __restrict__ src, const int* __restrict__ dst,
                       int* __restrict__ cur, int* __restrict__ csr, int E) {
    int i = blockIdx.x * blockDim.x + threadIdx.x;
    if (i < E) {
        int p = atomicAdd(&cur[dst[i]], 1);
        csr[p] = src[i];
    }
}

__global__ void k_init_ac(float* __restrict__ a, float* __restrict__ c) {
    int t = threadIdx.x;
    a[t] = 1.0f; c[t] = 0.0f;
}

// Merged: blocks 0..127 pack a[k]*W / a[k]*rW into the MFMA fragment layout;
// block 128 computes cwA/crb (the BN-offset rows).
// Fragment: lane l holds feat=l&15, k=(l>>4)*8+j. Wp idx = frag*512+lane*8+j,
// frag = (k>>5)*8 + (c>>4).
__global__ void k_packfold(const float* __restrict__ W, const float* __restrict__ rW,
                           const float* __restrict__ a, const float* __restrict__ c,
                           const float* __restrict__ rb,
                           unsigned short* __restrict__ Wp,
                           float* __restrict__ cwA, float* __restrict__ crb) {
    if (blockIdx.x < 128) {
        int idx = blockIdx.x * 256 + threadIdx.x;       // 0..32767
        int m = idx >> 14;
        int i = idx & 16383;
        int k = i >> 7, col = i & 127;
        const float* src = m ? rW : W;
        float v = a[k] * src[i];
        int frag = ((k >> 5) << 3) + (col >> 4);
        int lane = (((k & 31) >> 3) << 4) + (col & 15);
        int j = k & 7;
        Wp[(m << 14) + frag * 512 + lane * 8 + j] = f2bf(v);
    } else {
        int t = threadIdx.x;  // 256
        if (t < D) {
            float s = 0.f;
            for (int k = 0; k < D; ++k) s += c[k] * W[k * D + t];
            cwA[t] = s;
        } else {
            int j = t - D;
            float s = rb[j];
            for (int k = 0; k < D; ++k) s += c[k] * rW[k * D + j];
            crb[j] = s;
        }
    }
}

// ---------------- MFMA dual GEMM (transposed-C, W frags in LDS) ----------------
// hb (bf16) = (fb @ W0 + add0) * dinv[row] ; rbuf (bf16) = relu(fb @ W1 + add1)
// B-fragment source was global (64 serialized L2-latency steps/wave -> ~115us);
// now staged per-m into LDS: linear conflict-free ds_read_b128, compiler
// schedules with fine-grained lgkmcnt against MFMAs.
__global__ __launch_bounds__(256) void k_gemm_mfma(
    const unsigned short* __restrict__ fb,
    const unsigned short* __restrict__ Wp,    // [2][16384] packed frags
    const float* __restrict__ add0, const float* __restrict__ add1,
    const float* __restrict__ dinv,
    unsigned short* __restrict__ hb, unsigned short* __restrict__ rbuf, int N) {
    __shared__ unsigned short As[128 * 128];   // 32 KB, XOR-swizzled
    __shared__ unsigned short Wb[128 * 128];   // 32 KB, linear frag layout
    const int t = threadIdx.x;
    const int rowbase = blockIdx.x * 128;

#pragma unroll
    for (int i = 0; i < 8; ++i) {
        int ch = t + i * 256;            // 16B chunk id, 0..2047
        int row = ch >> 4, slot = ch & 15;
        uint4 v = make_uint4(0, 0, 0, 0);
        int gr = rowbase + row;
        if (gr < N) v = *(const uint4*)(fb + (size_t)gr * D + slot * 8);
        *(uint4*)((char*)As + row * 256 + ((slot ^ (row & 7)) << 4)) = v;
    }

    const int wave = t >> 6, l = t & 63;
    const int wrow = wave * 32;
    const int lg = l >> 4, lc = l & 15;

    const int g0 = rowbase + wrow + lc;        // node for nf=0
    const int g1 = g0 + 16;                    // node for nf=1
    const int f0 = lg * 4;                     // feature base within col-frag

#pragma unroll 1
    for (int m = 0; m < 2; ++m) {
        // stage this GEMM's packed W frags (32 KB, linear copy)
        const unsigned short* wp = Wp + (m << 14);
        __syncthreads();   // m=0: after As stores; m=1: all waves done reading Wb
#pragma unroll
        for (int i = 0; i < 8; ++i) {
            int ch = t + i * 256;        // 16B chunk id, 0..2047
            *(uint4*)((char*)Wb + ch * 16) = *(const uint4*)((const char*)wp + ch * 16);
        }
        __syncthreads();

        f32x4 acc[2][8];
#pragma unroll
        for (int nf = 0; nf < 2; ++nf)
#pragma unroll
            for (int cf = 0; cf < 8; ++cf) acc[nf][cf] = (f32x4){0.f, 0.f, 0.f, 0.f};

#pragma unroll
        for (int ks = 0; ks < 4; ++ks) {
            const int r0 = wrow + lc;
            const int r1 = wrow + 16 + lc;
            const int s = ks * 4 + lg;
            bf16x8 a0 = *(const bf16x8*)((const char*)As + r0 * 256 + ((s ^ (r0 & 7)) << 4));
            bf16x8 a1 = *(const bf16x8*)((const char*)As + r1 * 256 + ((s ^ (r1 & 7)) << 4));
#pragma unroll
            for (int cf = 0; cf < 8; ++cf) {
                bf16x8 b = *(const bf16x8*)((const char*)Wb + ((ks * 8 + cf) * 64 + l) * 16);
                // W frag as A (row=feature), activation frag as B (col=node)
                acc[0][cf] = __builtin_amdgcn_mfma_f32_16x16x32_bf16(b, a0, acc[0][cf], 0, 0, 0);
                acc[1][cf] = __builtin_amdgcn_mfma_f32_16x16x32_bf16(b, a1, acc[1][cf], 0, 0, 0);
            }
        }

        if (m == 0) {
            const float dv0 = (g0 < N) ? dinv[g0] : 0.f;
            const float dv1 = (g1 < N) ? dinv[g1] : 0.f;
#pragma unroll
            for (int cf = 0; cf < 8; ++cf) {
                const int fx = cf * 16 + f0;
                const float4 va = *(const float4*)(add0 + fx);
                if (g0 < N) {
                    uint2 p;
                    p.x = (unsigned int)f2bf((acc[0][cf][0] + va.x) * dv0) |
                          ((unsigned int)f2bf((acc[0][cf][1] + va.y) * dv0) << 16);
                    p.y = (unsigned int)f2bf((acc[0][cf][2] + va.z) * dv0) |
                          ((unsigned int)f2bf((acc[0][cf][3] + va.w) * dv0) << 16);
                    *(uint2*)(hb + (size_t)g0 * D + fx) = p;
                }
                if (g1 < N) {
                    uint2 p;
                    p.x = (unsigned int)f2bf((acc[1][cf][0] + va.x) * dv1) |
                          ((unsigned int)f2bf((acc[1][cf][1] + va.y) * dv1) << 16);
                    p.y = (unsigned int)f2bf((acc[1][cf][2] + va.z) * dv1) |
                          ((unsigned int)f2bf((acc[1][cf][3] + va.w) * dv1) << 16);
                    *(uint2*)(hb + (size_t)g1 * D + fx) = p;
                }
            }
        } else {
#pragma unroll
            for (int cf = 0; cf < 8; ++cf) {
                const int fx = cf * 16 + f0;
                const float4 va = *(const float4*)(add1 + fx);
                if (g0 < N) {
                    uint2 p;
                    p.x = (unsigned int)f2bf(fmaxf(acc[0][cf][0] + va.x, 0.f)) |
                          ((unsigned int)f2bf(fmaxf(acc[0][cf][1] + va.y, 0.f)) << 16);
                    p.y = (unsigned int)f2bf(fmaxf(acc[0][cf][2] + va.z, 0.f)) |
                          ((unsigned int)f2bf(fmaxf(acc[0][cf][3] + va.w, 0.f)) << 16);
                    *(uint2*)(rbuf + (size_t)g0 * D + fx) = p;
                }
                if (g1 < N) {
                    uint2 p;
                    p.x = (unsigned int)f2bf(fmaxf(acc[1][cf][0] + va.x, 0.f)) |
                          ((unsigned int)f2bf(fmaxf(acc[1][cf][1] + va.y, 0.f)) << 16);
                    p.y = (unsigned int)f2bf(fmaxf(acc[1][cf][2] + va.z, 0.f)) |
                          ((unsigned int)f2bf(fmaxf(acc[1][cf][3] + va.w, 0.f)) << 16);
                    *(uint2*)(rbuf + (size_t)g1 * D + fx) = p;
                }
            }
        }
    }
}

// ---------------- aggregation + residual + BN stats ----------------
// DUAL-NODE per wave: nodes p and p+half processed in the same uniform loop
// (2 independent gather-quads in flight per iteration; overflow iterations
// gather the L1-hot zero row N). 4 edges per gather instruction as before.
// Reads residual from bf16 rbuf; writes ONLY bf16 fbout + BN stats.
__global__ __launch_bounds__(256) void k_agg(
    const unsigned short* __restrict__ hb, const unsigned short* __restrict__ resb,
    unsigned short* __restrict__ fbout,
    const int* __restrict__ roff, const int* __restrict__ csr,
    const float* __restrict__ dinv, const float* __restrict__ bias,
    float* __restrict__ stats, int N, int half) {
    const int tid = threadIdx.x;
    const int lane = tid & 63;
    const int g = lane >> 4;           // edge slot within quad
    const int li = lane & 15;          // 16-lane column group
    const int cs = li * 8;             // 8 bf16 columns per lane
    const int wid = (blockIdx.x * blockDim.x + tid) >> 6;
    const int nw = (gridDim.x * blockDim.x) >> 6;

    float bv[8];
#pragma unroll
    for (int k = 0; k < 8; ++k) bv[k] = bias[cs + k];

    float s8[8], q8[8];
#pragma unroll
    for (int k = 0; k < 8; ++k) { s8[k] = 0.f; q8[k] = 0.f; }

    for (int p = wid; p < half; p += nw) {
        const int vA = p;
        const int vB = p + half;
        const bool hasB = (vB < N);
        int begA = roff[vA];
        const int qA = (roff[vA + 1] - begA) >> 2;
        int begB = begA, qB = 0;
        if (hasB) { begB = roff[vB]; qB = (roff[vB + 1] - begB) >> 2; }
        int eA = begA, eB = begB;

        float accA[8], accB[8];
#pragma unroll
        for (int k = 0; k < 8; ++k) { accA[k] = 0.f; accB[k] = 0.f; }

        const int mq = (qA > qB) ? qA : qB;
        for (int i = 0; i < mq; ++i) {
            const int4 a4 = *(const int4*)(csr + eA);
            const int4 b4 = *(const int4*)(csr + eB);
            int ua = (g == 0) ? a4.x : (g == 1) ? a4.y : (g == 2) ? a4.z : a4.w;
            int ub = (g == 0) ? b4.x : (g == 1) ? b4.y : (g == 2) ? b4.z : b4.w;
            ua = (i < qA) ? ua : N;
            ub = (i < qB) ? ub : N;
            const uint4 ga = *(const uint4*)(hb + (size_t)ua * D + cs);
            const uint4 gb = *(const uint4*)(hb + (size_t)ub * D + cs);
            accA[0] += bf_lo(ga.x); accA[1] += bf_hi(ga.x);
            accA[2] += bf_lo(ga.y); accA[3] += bf_hi(ga.y);
            accA[4] += bf_lo(ga.z); accA[5] += bf_hi(ga.z);
            accA[6] += bf_lo(ga.w); accA[7] += bf_hi(ga.w);
            accB[0] += bf_lo(gb.x); accB[1] += bf_hi(gb.x);
            accB[2] += bf_lo(gb.y); accB[3] += bf_hi(gb.y);
            accB[4] += bf_lo(gb.z); accB[5] += bf_hi(gb.z);
            accB[6] += bf_lo(gb.w); accB[7] += bf_hi(gb.w);
            if (i + 1 < qA) eA += 4;
            if (i + 1 < qB) eB += 4;
        }

        // fold the 4 edge-group partials
#pragma unroll
        for (int k = 0; k < 8; ++k) {
            accA[k] += __shfl_xor(accA[k], 16);
            accA[k] += __shfl_xor(accA[k], 32);
            accB[k] += __shfl_xor(accB[k], 16);
            accB[k] += __shfl_xor(accB[k], 32);
        }

        // ---- epilogue node A ----
        {
            const float dv = dinv[vA];
            const uint4 hs = *(const uint4*)(hb + (size_t)vA * D + cs);
            const uint4 rr = *(const uint4*)(resb + (size_t)vA * D + cs);
            float ox[8];
            ox[0] = (accA[0] + bf_lo(hs.x)) * dv + bv[0] + bf_lo(rr.x);
            ox[1] = (accA[1] + bf_hi(hs.x)) * dv + bv[1] + bf_hi(rr.x);
            ox[2] = (accA[2] + bf_lo(hs.y)) * dv + bv[2] + bf_lo(rr.y);
            ox[3] = (accA[3] + bf_hi(hs.y)) * dv + bv[3] + bf_hi(rr.y);
            ox[4] = (accA[4] + bf_lo(hs.z)) * dv + bv[4] + bf_lo(rr.z);
            ox[5] = (accA[5] + bf_hi(hs.z)) * dv + bv[5] + bf_hi(rr.z);
            ox[6] = (accA[6] + bf_lo(hs.w)) * dv + bv[6] + bf_lo(rr.w);
            ox[7] = (accA[7] + bf_hi(hs.w)) * dv + bv[7] + bf_hi(rr.w);
            if (g == 0) {
                uint4 pk;
                pk.x = (unsigned int)f2bf(ox[0]) | ((unsigned int)f2bf(ox[1]) << 16);
                pk.y = (unsigned int)f2bf(ox[2]) | ((unsigned int)f2bf(ox[3]) << 16);
                pk.z = (unsigned int)f2bf(ox[4]) | ((unsigned int)f2bf(ox[5]) << 16);
                pk.w = (unsigned int)f2bf(ox[6]) | ((unsigned int)f2bf(ox[7]) << 16);
                *(uint4*)(fbout + (size_t)vA * D + cs) = pk;
#pragma unroll
                for (int k = 0; k < 8; ++k) { s8[k] += ox[k]; q8[k] += ox[k] * ox[k]; }
            }
        }
        // ---- epilogue node B ----
        if (hasB) {
            const float dv = dinv[vB];
            const uint4 hs = *(const uint4*)(hb + (size_t)vB * D + cs);
            const uint4 rr = *(const uint4*)(resb + (size_t)vB * D + cs);
            float ox[8];
            ox[0] = (accB[0] + bf_lo(hs.x)) * dv + bv[0] + bf_lo(rr.x);
            ox[1] = (accB[1] + bf_hi(hs.x)) * dv + bv[1] + bf_hi(rr.x);
            ox[2] = (accB[2] + bf_lo(hs.y)) * dv + bv[2] + bf_lo(rr.y);
            ox[3] = (accB[3] + bf_hi(hs.y)) * dv + bv[3] + bf_hi(rr.y);
            ox[4] = (accB[4] + bf_lo(hs.z)) * dv + bv[4] + bf_lo(rr.z);
            ox[5] = (accB[5] + bf_hi(hs.z)) * dv + bv[5] + bf_hi(rr.z);
            ox[6] = (accB[6] + bf_lo(hs.w)) * dv + bv[6] + bf_lo(rr.w);
            ox[7] = (accB[7] + bf_hi(hs.w)) * dv + bv[7] + bf_hi(rr.w);
            if (g == 0) {
                uint4 pk;
                pk.x = (unsigned int)f2bf(ox[0]) | ((unsigned int)f2bf(ox[1]) << 16);
                pk.y = (unsigned int)f2bf(ox[2]) | ((unsigned int)f2bf(ox[3]) << 16);
                pk.z = (unsigned int)f2bf(ox[4]) | ((unsigned int)f2bf(ox[5]) << 16);
                pk.w = (unsigned int)f2bf(ox[6]) | ((unsigned int)f2bf(ox[7]) << 16);
                *(uint4*)(fbout + (size_t)vB * D + cs) = pk;
#pragma unroll
                for (int k = 0; k < 8; ++k) { s8[k] += ox[k]; q8[k] += ox[k] * ox[k]; }
            }
        }
    }

    // block-level BN-stats reduction: lanes g==0 hold valid partials
    __shared__ float sred[4][16][8];
    __shared__ float qred[4][16][8];
    const int w = tid >> 6;
    if (g == 0) {
#pragma unroll
        for (int k = 0; k < 8; ++k) { sred[w][li][k] = s8[k]; qred[w][li][k] = q8[k]; }
    }
    __syncthreads();
    if (tid < D) {
        const int col = tid;
        float ts = 0.f, tq = 0.f;
#pragma unroll
        for (int ww = 0; ww < 4; ++ww) {
            ts += sred[ww][col >> 3][col & 7];
            tq += qred[ww][col >> 3][col & 7];
        }
        atomicAdd(&stats[col], ts);
        atomicAdd(&stats[D + col], tq);
    }
}

__global__ void k_bnfin(const float* __restrict__ stats, const float* __restrict__ gamma,
                        const float* __restrict__ beta,
                        float* __restrict__ a_next, float* __restrict__ c_next, float invN) {
    int t = threadIdx.x;  // 128
    float mean = stats[t] * invN;
    float var = stats[D + t] * invN - mean * mean;
    float rs = rsqrtf(var + BN_EPS);
    float a = gamma[t] * rs;
    a_next[t] = a;
    c_next[t] = beta[t] - mean * a;
}

// out[g] = (sum_{v in g} fb[v]) * a + cnt_g * c   (fb is bf16)
__global__ void k_pool(const unsigned short* __restrict__ fb, const int* __restrict__ goff,
                       const float* __restrict__ a, const float* __restrict__ c,
                       float* __restrict__ out) {
    int g = blockIdx.x, t = threadIdx.x;  // 128 threads
    int beg = goff[g], end = goff[g + 1];
    float acc = 0.f;
    for (int v = beg; v < end; ++v) acc += bf2f(fb[(size_t)v * D + t]);
    out[(size_t)g * D + t] = acc * a[t] + (float)(end - beg) * c[t];
}

// ---------------- launcher ----------------

extern "C" void kernel_launch(void* const* d_in, const int* in_sizes, int n_in,
                              void* d_out, int out_size, void* d_ws, size_t ws_size,
                              hipStream_t stream) {
    const float* x      = (const float*)d_in[0];
    const int*   ei     = (const int*)d_in[1];
    const int*   batch  = (const int*)d_in[2];
    const float* Ws     = (const float*)d_in[3];
    const float* bs     = (const float*)d_in[4];
    const float* rWs    = (const float*)d_in[5];
    const float* rbs    = (const float*)d_in[6];
    const float* gammas = (const float*)d_in[7];
    const float* betas  = (const float*)d_in[8];
    float* out = (float*)d_out;

    const int N = in_sizes[2];
    const int E = in_sizes[1] / 2;
    const int G = out_size / D;
    const int* src = ei;
    const int* dst = ei + E;
    const int EP = E + 4 * N + 4;   // padded-CSR upper bound (+4 guard)
    const int half = (N + 1) >> 1;

    char* ws = (char*)d_ws;
    size_t off = 0;
    auto alloc = [&](size_t bytes) -> char* {
        char* p = ws + off;
        off += (bytes + 255) & ~(size_t)255;
        return p;
    };
    unsigned short* hb = (unsigned short*)alloc((size_t)(N + 1) * D * 2);
    unsigned short* fb = (unsigned short*)alloc((size_t)N * D * 2);
    unsigned short* rbuf = (unsigned short*)alloc((size_t)N * D * 2);
    int*   csr  = (int*)alloc((size_t)EP * 4);
    int*   roff = (int*)alloc((size_t)(N + 1) * 4);
    int*   cur  = (int*)alloc((size_t)N * 4);
    int*   cnt  = (int*)alloc((size_t)N * 4);
    float* dinv = (float*)alloc((size_t)N * 4);
    int*   gcnt = (int*)alloc((size_t)G * 4);
    int*   goff = (int*)alloc((size_t)(G + 1) * 4);
    int*   bsum = (int*)alloc(256 * 4);
    int*   bbase= (int*)alloc(256 * 4);
    float* stats= (float*)alloc((size_t)NLAYERS * 2 * D * 4);
    float* aarr = (float*)alloc((size_t)(NLAYERS + 1) * D * 4);
    float* carr = (float*)alloc((size_t)(NLAYERS + 1) * D * 4);
    unsigned short* Wp = (unsigned short*)alloc((size_t)2 * D * D * 2);
    float* cwA  = (float*)alloc(D * 4);
    float* crb  = (float*)alloc(D * 4);
    (void)ws_size;

    hipMemsetAsync(cnt, 0, (size_t)N * 4, stream);
    hipMemsetAsync(gcnt, 0, (size_t)G * 4, stream);
    hipMemsetAsync(stats, 0, (size_t)NLAYERS * 2 * D * 4, stream);

    k_hist_edges<<<(E + 255) / 256, 256, 0, stream>>>(dst, cnt, E);
    k_hist_batch<<<(N + 255) / 256, 256, 0, stream>>>(batch, gcnt, N);
    k_dinv<<<(N + 255) / 256, 256, 0, stream>>>(cnt, dinv, N);
    k_csr_init<<<(EP + 255) / 256, 256, 0, stream>>>(csr, EP, N);
    k_zrow<<<1, D, 0, stream>>>(hb, N);
    k_xb<<<(N * (D / 8) + 255) / 256, 256, 0, stream>>>(x, fb, N * (D / 8));

    int nb = (N + 1023) / 1024;
    k_scan_partial<<<nb, 256, 0, stream>>>(cnt, bsum, N);
    k_scan_small<<<1, 256, 0, stream>>>(bsum, bbase, nb);
    k_scan_apply<<<nb, 256, 0, stream>>>(cnt, bbase, roff, cur, N);
    k_gscan<<<1, 256, 0, stream>>>(gcnt, goff, G, N);
    k_fill<<<(E + 255) / 256, 256, 0, stream>>>(src, dst, cur, csr, E);
    k_init_ac<<<1, D, 0, stream>>>(aarr, carr);

    for (int l = 0; l < NLAYERS; ++l) {
        const float* W  = Ws + (size_t)l * D * D;
        const float* rW = rWs + (size_t)l * D * D;
        const float* aP = aarr + (size_t)l * D;
        const float* cP = carr + (size_t)l * D;

        k_packfold<<<129, 256, 0, stream>>>(W, rW, aP, cP, rbs + (size_t)l * D,
                                            Wp, cwA, crb);

        k_gemm_mfma<<<(N + 127) / 128, 256, 0, stream>>>(fb, Wp, cwA, crb, dinv,
                                                         hb, rbuf, N);
        k_agg<<<4096, 256, 0, stream>>>(hb, rbuf, fb, roff, csr, dinv,
                                        bs + (size_t)l * D,
                                        stats + (size_t)l * 2 * D, N, half);
        k_bnfin<<<1, D, 0, stream>>>(stats + (size_t)l * 2 * D, gammas + (size_t)l * D,
                                     betas + (size_t)l * D,
                                     aarr + (size_t)(l + 1) * D, carr + (size_t)(l + 1) * D,
                                     1.0f / (float)N);
    }

    k_pool<<<G, D, 0, stream>>>(fb, goff, aarr + (size_t)NLAYERS * D,
                                carr + (size_t)NLAYERS * D, out);
}

// Round 11
// 782.424 us; speedup vs baseline: 1.9127x; 1.0591x over previous
//
#include <hip/hip_runtime.h>

#define D 128
#define NLAYERS 3
#define BN_EPS 1e-5f

typedef short bf16x8 __attribute__((ext_vector_type(8)));
typedef float f32x4 __attribute__((ext_vector_type(4)));

__device__ __forceinline__ unsigned short f2bf(float f) {
    unsigned int u = __float_as_uint(f);
    u += 0x7FFFu + ((u >> 16) & 1u);   // round-to-nearest-even
    return (unsigned short)(u >> 16);
}
__device__ __forceinline__ float bf2f(unsigned short b) {
    return __uint_as_float(((unsigned int)b) << 16);
}
__device__ __forceinline__ float bf_lo(unsigned int u) {
    return __uint_as_float(u << 16);
}
__device__ __forceinline__ float bf_hi(unsigned int u) {
    return __uint_as_float(u & 0xFFFF0000u);
}

// ---------------- setup kernels ----------------

// merged: edge histogram + batch histogram
__global__ void k_hist(const int* __restrict__ dst, const int* __restrict__ batch,
                       int* __restrict__ cnt, int* __restrict__ gcnt, int E, int N) {
    int i = blockIdx.x * blockDim.x + threadIdx.x;
    if (i < E) {
        atomicAdd(&cnt[dst[i]], 1);
    } else {
        int j = i - E;
        if (j < N) atomicAdd(&gcnt[batch[j]], 1);
    }
}

// merged: dinv + zero dummy row of hb
__global__ void k_dinv_zrow(const int* __restrict__ cnt, float* __restrict__ dinv,
                            unsigned short* __restrict__ hb, int N) {
    int i = blockIdx.x * blockDim.x + threadIdx.x;
    if (i < N) dinv[i] = rsqrtf((float)(cnt[i] + 1));   // +1 self loop
    if (blockIdx.x == 0 && threadIdx.x < D) hb[(size_t)N * D + threadIdx.x] = 0;
}

// x (f32) -> fb (bf16), 8 elems/thread
__global__ void k_xb(const float* __restrict__ x, unsigned short* __restrict__ fb, int n8) {
    int i = blockIdx.x * blockDim.x + threadIdx.x;
    if (i < n8) {
        const float4 a = ((const float4*)x)[i * 2];
        const float4 b = ((const float4*)x)[i * 2 + 1];
        uint4 p;
        p.x = (unsigned int)f2bf(a.x) | ((unsigned int)f2bf(a.y) << 16);
        p.y = (unsigned int)f2bf(a.z) | ((unsigned int)f2bf(a.w) << 16);
        p.z = (unsigned int)f2bf(b.x) | ((unsigned int)f2bf(b.y) << 16);
        p.w = (unsigned int)f2bf(b.z) | ((unsigned int)f2bf(b.w) << 16);
        ((uint4*)fb)[i] = p;
    }
}

// partial sums of blocks of 1024 PADDED counts (padded to multiple of 4)
__global__ void k_scan_partial(const int* __restrict__ cnt, int* __restrict__ bsum, int N) {
    __shared__ int sh[256];
    int b = blockIdx.x, t = threadIdx.x;
    int base = b * 1024 + t * 4;
    int s = 0;
#pragma unroll
    for (int i = 0; i < 4; ++i) {
        int idx = base + i;
        int cv = (idx < N) ? cnt[idx] : 0;
        s += (cv + 3) & ~3;
    }
    sh[t] = s;
    for (int ofs = 128; ofs > 0; ofs >>= 1) {
        __syncthreads();
        if (t < ofs) sh[t] += sh[t + ofs];
    }
    __syncthreads();
    if (t == 0) bsum[b] = sh[0];
}

// merged: block 0 = exclusive scan of block sums; block 1 = graph-count scan
__global__ void k_scan_small_g(const int* __restrict__ bsum, int* __restrict__ bbase, int nb,
                               const int* __restrict__ gcnt, int* __restrict__ goff,
                               int G, int N) {
    __shared__ int sh[256];
    int t = threadIdx.x;
    if (blockIdx.x == 0) {
        int v = (t < nb) ? bsum[t] : 0;
        sh[t] = v;
        __syncthreads();
        for (int ofs = 1; ofs < 256; ofs <<= 1) {
            int vv = (t >= ofs) ? sh[t - ofs] : 0;
            __syncthreads();
            sh[t] += vv;
            __syncthreads();
        }
        bbase[t] = sh[t] - v;   // exclusive
    } else {
        int base = t * 4;
        int v[4]; int s = 0;
#pragma unroll
        for (int i = 0; i < 4; ++i) { v[i] = (base + i < G) ? gcnt[base + i] : 0; s += v[i]; }
        sh[t] = s;
        __syncthreads();
        for (int ofs = 1; ofs < 256; ofs <<= 1) {
            int vv = (t >= ofs) ? sh[t - ofs] : 0;
            __syncthreads();
            sh[t] += vv;
            __syncthreads();
        }
        int o = sh[t] - s;
#pragma unroll
        for (int i = 0; i < 4; ++i) {
            int idx = base + i;
            if (idx < G) { goff[idx] = o; o += v[i]; }
        }
        if (t == 255) goff[G] = N;
    }
}

// scan apply; ALSO writes the per-node CSR pad slots (dummy index N) so no
// separate csr_init pass over the whole array is needed.
__global__ void k_scan_apply(const int* __restrict__ cnt, const int* __restrict__ bbase,
                             int* __restrict__ roff, int* __restrict__ cur,
                             int* __restrict__ csr, int N) {
    __shared__ int sh[256];
    int b = blockIdx.x, t = threadIdx.x;
    int base = b * 1024 + t * 4;
    int vr[4], v[4]; int s = 0;
#pragma unroll
    for (int i = 0; i < 4; ++i) {
        int cv = (base + i < N) ? cnt[base + i] : 0;
        vr[i] = cv;
        v[i] = (cv + 3) & ~3;
        s += v[i];
    }
    sh[t] = s;
    __syncthreads();
    for (int ofs = 1; ofs < 256; ofs <<= 1) {
        int vv = (t >= ofs) ? sh[t - ofs] : 0;
        __syncthreads();
        sh[t] += vv;
        __syncthreads();
    }
    int o = bbase[b] + sh[t] - s;
#pragma unroll
    for (int i = 0; i < 4; ++i) {
        int idx = base + i;
        if (idx < N) {
            roff[idx] = o; cur[idx] = o;
            for (int p = vr[i]; p < v[i]; ++p) csr[o + p] = N;   // pads
            o += v[i];
            if (idx == N - 1) roff[N] = o;
        }
    }
}

__global__ void k_fill(const int* __restrict__ src, const int* __restrict__ dst,
                       int* __restrict__ cur, int* __restrict__ csr, int E) {
    int i = blockIdx.x * blockDim.x + threadIdx.x;
    if (i < E) {
        int p = atomicAdd(&cur[dst[i]], 1);
        csr[p] = src[i];
    }
}

// Merged pack + fold + BN-finalize. For layer l: a/c are derived IN-KERNEL
// from the previous layer's stats (first=1 -> a=1, c=0).
// Blocks 0..127: pack a[k]*W / a[k]*rW into MFMA fragment layout.
// Block 128: cwA[j] = sum_k c[k]W[k][j]; crb[j] = rb[j] + sum_k c[k]rW[k][j].
__global__ void k_packfold(const float* __restrict__ W, const float* __restrict__ rW,
                           const float* __restrict__ gam, const float* __restrict__ bet,
                           const float* __restrict__ stats, const float* __restrict__ rb,
                           unsigned short* __restrict__ Wp,
                           float* __restrict__ cwA, float* __restrict__ crb,
                           int first, float invN) {
    if (blockIdx.x < 128) {
        int idx = blockIdx.x * 256 + threadIdx.x;       // 0..32767
        int m = idx >> 14;
        int i = idx & 16383;
        int k = i >> 7, col = i & 127;
        float a = 1.f;
        if (!first) {
            float mean = stats[k] * invN;
            float var = stats[D + k] * invN - mean * mean;
            a = gam[k] * rsqrtf(var + BN_EPS);
        }
        const float* src = m ? rW : W;
        float v = a * src[i];
        int frag = ((k >> 5) << 3) + (col >> 4);
        int lane = (((k & 31) >> 3) << 4) + (col & 15);
        int j = k & 7;
        Wp[(m << 14) + frag * 512 + lane * 8 + j] = f2bf(v);
    } else {
        __shared__ float csh[128];
        int t = threadIdx.x;  // 256
        if (t < D) {
            float c = 0.f;
            if (!first) {
                float mean = stats[t] * invN;
                float var = stats[D + t] * invN - mean * mean;
                float a = gam[t] * rsqrtf(var + BN_EPS);
                c = bet[t] - mean * a;
            }
            csh[t] = c;
        }
        __syncthreads();
        if (t < D) {
            float s = 0.f;
            for (int k = 0; k < D; ++k) s += csh[k] * W[k * D + t];
            cwA[t] = s;
        } else {
            int j = t - D;
            float s = rb[j];
            for (int k = 0; k < D; ++k) s += csh[k] * rW[k * D + j];
            crb[j] = s;
        }
    }
}

// ---------------- MFMA dual GEMM (LDS-transposed coalesced epilogue) --------
// hb (bf16) = (fb @ W0 + add0) * dinv[row] ; rbuf (bf16) = relu(fb @ W1 + add1)
// After each m's MFMAs, acc is packed (bias/dinv/relu applied) into the Wb
// LDS buffer in swizzled (node,feat) layout, then stored as 128 complete
// 256B rows with fully-coalesced uint4 stores (4 rows / instruction).
__global__ __launch_bounds__(256) void k_gemm_mfma(
    const unsigned short* __restrict__ fb,
    const unsigned short* __restrict__ Wp,    // [2][16384] packed frags
    const float* __restrict__ add0, const float* __restrict__ add1,
    const float* __restrict__ dinv,
    unsigned short* __restrict__ hb, unsigned short* __restrict__ rbuf, int N) {
    __shared__ unsigned short As[128 * 128];   // 32 KB, XOR-swizzled
    __shared__ unsigned short Wb[128 * 128];   // 32 KB: W frags, then epilogue
    const int t = threadIdx.x;
    const int rowbase = blockIdx.x * 128;

#pragma unroll
    for (int i = 0; i < 8; ++i) {
        int ch = t + i * 256;            // 16B chunk id, 0..2047
        int row = ch >> 4, slot = ch & 15;
        uint4 v = make_uint4(0, 0, 0, 0);
        int gr = rowbase + row;
        if (gr < N) v = *(const uint4*)(fb + (size_t)gr * D + slot * 8);
        *(uint4*)((char*)As + row * 256 + ((slot ^ (row & 7)) << 4)) = v;
    }

    const int wave = t >> 6, l = t & 63;
    const int wrow = wave * 32;
    const int lg = l >> 4, lc = l & 15;

    const int n0 = wrow + lc;                  // local node rows
    const int n1 = wrow + 16 + lc;
    const int g0 = rowbase + n0;               // global nodes
    const int g1 = rowbase + n1;
    const int f0 = lg * 4;                     // feature base within col-frag
    const int half = lg & 1;

#pragma unroll 1
    for (int m = 0; m < 2; ++m) {
        const unsigned short* wp = Wp + (m << 14);
        __syncthreads();   // As stores done (m=0) / Wb epilogue reads done (m=1)
#pragma unroll
        for (int i = 0; i < 8; ++i) {
            int ch = t + i * 256;        // 16B chunk id, 0..2047
            *(uint4*)((char*)Wb + ch * 16) = *(const uint4*)((const char*)wp + ch * 16);
        }
        __syncthreads();

        f32x4 acc[2][8];
#pragma unroll
        for (int nf = 0; nf < 2; ++nf)
#pragma unroll
            for (int cf = 0; cf < 8; ++cf) acc[nf][cf] = (f32x4){0.f, 0.f, 0.f, 0.f};

#pragma unroll
        for (int ks = 0; ks < 4; ++ks) {
            const int s = ks * 4 + lg;
            bf16x8 a0 = *(const bf16x8*)((const char*)As + n0 * 256 + ((s ^ (n0 & 7)) << 4));
            bf16x8 a1 = *(const bf16x8*)((const char*)As + n1 * 256 + ((s ^ (n1 & 7)) << 4));
#pragma unroll
            for (int cf = 0; cf < 8; ++cf) {
                bf16x8 b = *(const bf16x8*)((const char*)Wb + ((ks * 8 + cf) * 64 + l) * 16);
                // W frag as A (row=feature), activation frag as B (col=node)
                acc[0][cf] = __builtin_amdgcn_mfma_f32_16x16x32_bf16(b, a0, acc[0][cf], 0, 0, 0);
                acc[1][cf] = __builtin_amdgcn_mfma_f32_16x16x32_bf16(b, a1, acc[1][cf], 0, 0, 0);
            }
        }

        __syncthreads();   // all waves done reading Wb frags -> reuse as epilogue buf

        if (m == 0) {
            const float dv0 = (g0 < N) ? dinv[g0] : 0.f;
            const float dv1 = (g1 < N) ? dinv[g1] : 0.f;
#pragma unroll
            for (int cf = 0; cf < 8; ++cf) {
                const int fx = cf * 16 + f0;
                const float4 va = *(const float4*)(add0 + fx);
                const int slot = cf * 2 + (lg >> 1);
                uint2 p0, p1;
                p0.x = (unsigned int)f2bf((acc[0][cf][0] + va.x) * dv0) |
                       ((unsigned int)f2bf((acc[0][cf][1] + va.y) * dv0) << 16);
                p0.y = (unsigned int)f2bf((acc[0][cf][2] + va.z) * dv0) |
                       ((unsigned int)f2bf((acc[0][cf][3] + va.w) * dv0) << 16);
                p1.x = (unsigned int)f2bf((acc[1][cf][0] + va.x) * dv1) |
                       ((unsigned int)f2bf((acc[1][cf][1] + va.y) * dv1) << 16);
                p1.y = (unsigned int)f2bf((acc[1][cf][2] + va.z) * dv1) |
                       ((unsigned int)f2bf((acc[1][cf][3] + va.w) * dv1) << 16);
                *(uint2*)((char*)Wb + n0 * 256 + ((slot ^ (n0 & 7)) << 4) + half * 8) = p0;
                *(uint2*)((char*)Wb + n1 * 256 + ((slot ^ (n1 & 7)) << 4) + half * 8) = p1;
            }
        } else {
#pragma unroll
            for (int cf = 0; cf < 8; ++cf) {
                const int fx = cf * 16 + f0;
                const float4 va = *(const float4*)(add1 + fx);
                const int slot = cf * 2 + (lg >> 1);
                uint2 p0, p1;
                p0.x = (unsigned int)f2bf(fmaxf(acc[0][cf][0] + va.x, 0.f)) |
                       ((unsigned int)f2bf(fmaxf(acc[0][cf][1] + va.y, 0.f)) << 16);
                p0.y = (unsigned int)f2bf(fmaxf(acc[0][cf][2] + va.z, 0.f)) |
                       ((unsigned int)f2bf(fmaxf(acc[0][cf][3] + va.w, 0.f)) << 16);
                p1.x = (unsigned int)f2bf(fmaxf(acc[1][cf][0] + va.x, 0.f)) |
                       ((unsigned int)f2bf(fmaxf(acc[1][cf][1] + va.y, 0.f)) << 16);
                p1.y = (unsigned int)f2bf(fmaxf(acc[1][cf][2] + va.z, 0.f)) |
                       ((unsigned int)f2bf(fmaxf(acc[1][cf][3] + va.w, 0.f)) << 16);
                *(uint2*)((char*)Wb + n0 * 256 + ((slot ^ (n0 & 7)) << 4) + half * 8) = p0;
                *(uint2*)((char*)Wb + n1 * 256 + ((slot ^ (n1 & 7)) << 4) + half * 8) = p1;
            }
        }

        __syncthreads();   // epilogue tile complete

        unsigned short* __restrict__ dstp = (m == 0) ? hb : rbuf;
#pragma unroll
        for (int i = 0; i < 8; ++i) {
            int ch = t + i * 256;
            int row = ch >> 4, sl = ch & 15;
            int gr = rowbase + row;
            if (gr < N) {
                uint4 v = *(const uint4*)((const char*)Wb + row * 256 + ((sl ^ (row & 7)) << 4));
                *(uint4*)(dstp + (size_t)gr * D + sl * 8) = v;
            }
        }
    }
}

// ---------------- aggregation + residual + BN stats ----------------
// DUAL-NODE per wave; 4 edges per gather instruction; CSR padded to x4 with
// dummy index N -> zero row. Reads bf16 residual; writes bf16 fbout + stats.
__global__ __launch_bounds__(256) void k_agg(
    const unsigned short* __restrict__ hb, const unsigned short* __restrict__ resb,
    unsigned short* __restrict__ fbout,
    const int* __restrict__ roff, const int* __restrict__ csr,
    const float* __restrict__ dinv, const float* __restrict__ bias,
    float* __restrict__ stats, int N, int half) {
    const int tid = threadIdx.x;
    const int lane = tid & 63;
    const int g = lane >> 4;           // edge slot within quad
    const int li = lane & 15;          // 16-lane column group
    const int cs = li * 8;             // 8 bf16 columns per lane
    const int wid = (blockIdx.x * blockDim.x + tid) >> 6;
    const int nw = (gridDim.x * blockDim.x) >> 6;

    float bv[8];
#pragma unroll
    for (int k = 0; k < 8; ++k) bv[k] = bias[cs + k];

    float s8[8], q8[8];
#pragma unroll
    for (int k = 0; k < 8; ++k) { s8[k] = 0.f; q8[k] = 0.f; }

    for (int p = wid; p < half; p += nw) {
        const int vA = p;
        const int vB = p + half;
        const bool hasB = (vB < N);
        int begA = roff[vA];
        const int qA = (roff[vA + 1] - begA) >> 2;
        int begB = begA, qB = 0;
        if (hasB) { begB = roff[vB]; qB = (roff[vB + 1] - begB) >> 2; }
        int eA = begA, eB = begB;

        float accA[8], accB[8];
#pragma unroll
        for (int k = 0; k < 8; ++k) { accA[k] = 0.f; accB[k] = 0.f; }

        const int mq = (qA > qB) ? qA : qB;
        for (int i = 0; i < mq; ++i) {
            const int4 a4 = *(const int4*)(csr + eA);
            const int4 b4 = *(const int4*)(csr + eB);
            int ua = (g == 0) ? a4.x : (g == 1) ? a4.y : (g == 2) ? a4.z : a4.w;
            int ub = (g == 0) ? b4.x : (g == 1) ? b4.y : (g == 2) ? b4.z : b4.w;
            ua = (i < qA) ? ua : N;
            ub = (i < qB) ? ub : N;
            const uint4 ga = *(const uint4*)(hb + (size_t)ua * D + cs);
            const uint4 gb = *(const uint4*)(hb + (size_t)ub * D + cs);
            accA[0] += bf_lo(ga.x); accA[1] += bf_hi(ga.x);
            accA[2] += bf_lo(ga.y); accA[3] += bf_hi(ga.y);
            accA[4] += bf_lo(ga.z); accA[5] += bf_hi(ga.z);
            accA[6] += bf_lo(ga.w); accA[7] += bf_hi(ga.w);
            accB[0] += bf_lo(gb.x); accB[1] += bf_hi(gb.x);
            accB[2] += bf_lo(gb.y); accB[3] += bf_hi(gb.y);
            accB[4] += bf_lo(gb.z); accB[5] += bf_hi(gb.z);
            accB[6] += bf_lo(gb.w); accB[7] += bf_hi(gb.w);
            if (i + 1 < qA) eA += 4;
            if (i + 1 < qB) eB += 4;
        }

        // fold the 4 edge-group partials
#pragma unroll
        for (int k = 0; k < 8; ++k) {
            accA[k] += __shfl_xor(accA[k], 16);
            accA[k] += __shfl_xor(accA[k], 32);
            accB[k] += __shfl_xor(accB[k], 16);
            accB[k] += __shfl_xor(accB[k], 32);
        }

        // ---- epilogue node A ----
        {
            const float dv = dinv[vA];
            const uint4 hs = *(const uint4*)(hb + (size_t)vA * D + cs);
            const uint4 rr = *(const uint4*)(resb + (size_t)vA * D + cs);
            float ox[8];
            ox[0] = (accA[0] + bf_lo(hs.x)) * dv + bv[0] + bf_lo(rr.x);
            ox[1] = (accA[1] + bf_hi(hs.x)) * dv + bv[1] + bf_hi(rr.x);
            ox[2] = (accA[2] + bf_lo(hs.y)) * dv + bv[2] + bf_lo(rr.y);
            ox[3] = (accA[3] + bf_hi(hs.y)) * dv + bv[3] + bf_hi(rr.y);
            ox[4] = (accA[4] + bf_lo(hs.z)) * dv + bv[4] + bf_lo(rr.z);
            ox[5] = (accA[5] + bf_hi(hs.z)) * dv + bv[5] + bf_hi(rr.z);
            ox[6] = (accA[6] + bf_lo(hs.w)) * dv + bv[6] + bf_lo(rr.w);
            ox[7] = (accA[7] + bf_hi(hs.w)) * dv + bv[7] + bf_hi(rr.w);
            if (g == 0) {
                uint4 pk;
                pk.x = (unsigned int)f2bf(ox[0]) | ((unsigned int)f2bf(ox[1]) << 16);
                pk.y = (unsigned int)f2bf(ox[2]) | ((unsigned int)f2bf(ox[3]) << 16);
                pk.z = (unsigned int)f2bf(ox[4]) | ((unsigned int)f2bf(ox[5]) << 16);
                pk.w = (unsigned int)f2bf(ox[6]) | ((unsigned int)f2bf(ox[7]) << 16);
                *(uint4*)(fbout + (size_t)vA * D + cs) = pk;
#pragma unroll
                for (int k = 0; k < 8; ++k) { s8[k] += ox[k]; q8[k] += ox[k] * ox[k]; }
            }
        }
        // ---- epilogue node B ----
        if (hasB) {
            const float dv = dinv[vB];
            const uint4 hs = *(const uint4*)(hb + (size_t)vB * D + cs);
            const uint4 rr = *(const uint4*)(resb + (size_t)vB * D + cs);
            float ox[8];
            ox[0] = (accB[0] + bf_lo(hs.x)) * dv + bv[0] + bf_lo(rr.x);
            ox[1] = (accB[1] + bf_hi(hs.x)) * dv + bv[1] + bf_hi(rr.x);
            ox[2] = (accB[2] + bf_lo(hs.y)) * dv + bv[2] + bf_lo(rr.y);
            ox[3] = (accB[3] + bf_hi(hs.y)) * dv + bv[3] + bf_hi(rr.y);
            ox[4] = (accB[4] + bf_lo(hs.z)) * dv + bv[4] + bf_lo(rr.z);
            ox[5] = (accB[5] + bf_hi(hs.z)) * dv + bv[5] + bf_hi(rr.z);
            ox[6] = (accB[6] + bf_lo(hs.w)) * dv + bv[6] + bf_lo(rr.w);
            ox[7] = (accB[7] + bf_hi(hs.w)) * dv + bv[7] + bf_hi(rr.w);
            if (g == 0) {
                uint4 pk;
                pk.x = (unsigned int)f2bf(ox[0]) | ((unsigned int)f2bf(ox[1]) << 16);
                pk.y = (unsigned int)f2bf(ox[2]) | ((unsigned int)f2bf(ox[3]) << 16);
                pk.z = (unsigned int)f2bf(ox[4]) | ((unsigned int)f2bf(ox[5]) << 16);
                pk.w = (unsigned int)f2bf(ox[6]) | ((unsigned int)f2bf(ox[7]) << 16);
                *(uint4*)(fbout + (size_t)vB * D + cs) = pk;
#pragma unroll
                for (int k = 0; k < 8; ++k) { s8[k] += ox[k]; q8[k] += ox[k] * ox[k]; }
            }
        }
    }

    // block-level BN-stats reduction: lanes g==0 hold valid partials
    __shared__ float sred[4][16][8];
    __shared__ float qred[4][16][8];
    const int w = tid >> 6;
    if (g == 0) {
#pragma unroll
        for (int k = 0; k < 8; ++k) { sred[w][li][k] = s8[k]; qred[w][li][k] = q8[k]; }
    }
    __syncthreads();
    if (tid < D) {
        const int col = tid;
        float ts = 0.f, tq = 0.f;
#pragma unroll
        for (int ww = 0; ww < 4; ++ww) {
            ts += sred[ww][col >> 3][col & 7];
            tq += qred[ww][col >> 3][col & 7];
        }
        atomicAdd(&stats[col], ts);
        atomicAdd(&stats[D + col], tq);
    }
}

// pool with embedded final BN: a,c computed per-block from last stats
__global__ void k_pool(const unsigned short* __restrict__ fb, const int* __restrict__ goff,
                       const float* __restrict__ gam, const float* __restrict__ bet,
                       const float* __restrict__ stats, float invN,
                       float* __restrict__ out) {
    int g = blockIdx.x, t = threadIdx.x;  // 128 threads
    float mean = stats[t] * invN;
    float var = stats[D + t] * invN - mean * mean;
    float a = gam[t] * rsqrtf(var + BN_EPS);
    float c = bet[t] - mean * a;
    int beg = goff[g], end = goff[g + 1];
    float acc = 0.f;
    for (int v = beg; v < end; ++v) acc += bf2f(fb[(size_t)v * D + t]);
    out[(size_t)g * D + t] = acc * a + (float)(end - beg) * c;
}

// ---------------- launcher ----------------

extern "C" void kernel_launch(void* const* d_in, const int* in_sizes, int n_in,
                              void* d_out, int out_size, void* d_ws, size_t ws_size,
                              hipStream_t stream) {
    const float* x      = (const float*)d_in[0];
    const int*   ei     = (const int*)d_in[1];
    const int*   batch  = (const int*)d_in[2];
    const float* Ws     = (const float*)d_in[3];
    const float* bs     = (const float*)d_in[4];
    const float* rWs    = (const float*)d_in[5];
    const float* rbs    = (const float*)d_in[6];
    const float* gammas = (const float*)d_in[7];
    const float* betas  = (const float*)d_in[8];
    float* out = (float*)d_out;

    const int N = in_sizes[2];
    const int E = in_sizes[1] / 2;
    const int G = out_size / D;
    const int* src = ei;
    const int* dst = ei + E;
    const int EP = E + 4 * N + 4;   // padded-CSR upper bound (+4 guard)
    const int half = (N + 1) >> 1;
    const float invN = 1.0f / (float)N;

    char* ws = (char*)d_ws;
    size_t off = 0;
    auto alloc = [&](size_t bytes) -> char* {
        char* p = ws + off;
        off += (bytes + 255) & ~(size_t)255;
        return p;
    };
    unsigned short* hb = (unsigned short*)alloc((size_t)(N + 1) * D * 2);
    unsigned short* fb = (unsigned short*)alloc((size_t)N * D * 2);
    unsigned short* rbuf = (unsigned short*)alloc((size_t)N * D * 2);
    int*   csr  = (int*)alloc((size_t)EP * 4);
    int*   roff = (int*)alloc((size_t)(N + 1) * 4);
    int*   cur  = (int*)alloc((size_t)N * 4);
    int*   cnt  = (int*)alloc((size_t)N * 4);
    float* dinv = (float*)alloc((size_t)N * 4);
    int*   gcnt = (int*)alloc((size_t)G * 4);
    int*   goff = (int*)alloc((size_t)(G + 1) * 4);
    int*   bsum = (int*)alloc(256 * 4);
    int*   bbase= (int*)alloc(256 * 4);
    float* stats= (float*)alloc((size_t)NLAYERS * 2 * D * 4);
    unsigned short* Wp = (unsigned short*)alloc((size_t)2 * D * D * 2);
    float* cwA  = (float*)alloc(D * 4);
    float* crb  = (float*)alloc(D * 4);
    (void)ws_size;

    hipMemsetAsync(cnt, 0, (size_t)N * 4, stream);
    hipMemsetAsync(gcnt, 0, (size_t)G * 4, stream);
    hipMemsetAsync(stats, 0, (size_t)NLAYERS * 2 * D * 4, stream);

    k_hist<<<(E + N + 255) / 256, 256, 0, stream>>>(dst, batch, cnt, gcnt, E, N);
    k_dinv_zrow<<<(N + 255) / 256, 256, 0, stream>>>(cnt, dinv, hb, N);
    k_xb<<<(N * (D / 8) + 255) / 256, 256, 0, stream>>>(x, fb, N * (D / 8));

    int nb = (N + 1023) / 1024;
    k_scan_partial<<<nb, 256, 0, stream>>>(cnt, bsum, N);
    k_scan_small_g<<<2, 256, 0, stream>>>(bsum, bbase, nb, gcnt, goff, G, N);
    k_scan_apply<<<nb, 256, 0, stream>>>(cnt, bbase, roff, cur, csr, N);
    k_fill<<<(E + 255) / 256, 256, 0, stream>>>(src, dst, cur, csr, E);

    for (int l = 0; l < NLAYERS; ++l) {
        const float* W  = Ws + (size_t)l * D * D;
        const float* rW = rWs + (size_t)l * D * D;
        const float* gamP = gammas + (size_t)(l > 0 ? l - 1 : 0) * D;
        const float* betP = betas + (size_t)(l > 0 ? l - 1 : 0) * D;
        const float* stP  = stats + (size_t)(l > 0 ? l - 1 : 0) * 2 * D;

        k_packfold<<<129, 256, 0, stream>>>(W, rW, gamP, betP, stP,
                                            rbs + (size_t)l * D,
                                            Wp, cwA, crb, (l == 0) ? 1 : 0, invN);

        k_gemm_mfma<<<(N + 127) / 128, 256, 0, stream>>>(fb, Wp, cwA, crb, dinv,
                                                         hb, rbuf, N);
        k_agg<<<4096, 256, 0, stream>>>(hb, rbuf, fb, roff, csr, dinv,
                                        bs + (size_t)l * D,
                                        stats + (size_t)l * 2 * D, N, half);
    }

    k_pool<<<G, 128, 0, stream>>>(fb, goff,
                                  gammas + (size_t)(NLAYERS - 1) * D,
                                  betas + (size_t)(NLAYERS - 1) * D,
                                  stats + (size_t)(NLAYERS - 1) * 2 * D,
                                  invN, out);
}

// Round 12
// 746.306 us; speedup vs baseline: 2.0053x; 1.0484x over previous
//
#include <hip/hip_runtime.h>

#define D 128
#define NLAYERS 3
#define BN_EPS 1e-5f

typedef short bf16x8 __attribute__((ext_vector_type(8)));
typedef float f32x4 __attribute__((ext_vector_type(4)));

__device__ __forceinline__ unsigned short f2bf(float f) {
    unsigned int u = __float_as_uint(f);
    u += 0x7FFFu + ((u >> 16) & 1u);   // round-to-nearest-even
    return (unsigned short)(u >> 16);
}
__device__ __forceinline__ float bf2f(unsigned short b) {
    return __uint_as_float(((unsigned int)b) << 16);
}
__device__ __forceinline__ float bf_lo(unsigned int u) {
    return __uint_as_float(u << 16);
}
__device__ __forceinline__ float bf_hi(unsigned int u) {
    return __uint_as_float(u & 0xFFFF0000u);
}

// ---------------- setup kernels ----------------

// zero cnt + gcnt + stats in one dispatch
__global__ void k_zero(int* __restrict__ cnt, int* __restrict__ gcnt,
                       int* __restrict__ stats, int N, int G, int S) {
    int i = blockIdx.x * blockDim.x + threadIdx.x;
    if (i < N) cnt[i] = 0;
    else if (i < N + G) gcnt[i - N] = 0;
    else if (i < N + G + S) stats[i - N - G] = 0;
}

// merged: edge histogram + batch histogram + x->bf16 convert
__global__ void k_hist_xb(const int* __restrict__ dst, const int* __restrict__ batch,
                          const float* __restrict__ x,
                          int* __restrict__ cnt, int* __restrict__ gcnt,
                          unsigned short* __restrict__ fb, int E, int N, int n8) {
    int i = blockIdx.x * blockDim.x + threadIdx.x;
    if (i < E) {
        atomicAdd(&cnt[dst[i]], 1);
    } else if (i < E + N) {
        atomicAdd(&gcnt[batch[i - E]], 1);
    } else {
        int j = i - E - N;
        if (j < n8) {
            const float4 a = ((const float4*)x)[j * 2];
            const float4 b = ((const float4*)x)[j * 2 + 1];
            uint4 p;
            p.x = (unsigned int)f2bf(a.x) | ((unsigned int)f2bf(a.y) << 16);
            p.y = (unsigned int)f2bf(a.z) | ((unsigned int)f2bf(a.w) << 16);
            p.z = (unsigned int)f2bf(b.x) | ((unsigned int)f2bf(b.y) << 16);
            p.w = (unsigned int)f2bf(b.z) | ((unsigned int)f2bf(b.w) << 16);
            ((uint4*)fb)[j] = p;
        }
    }
}

// partial sums of PADDED counts; also computes dinv and zeroes dummy hb row
__global__ void k_scan_partial(const int* __restrict__ cnt, int* __restrict__ bsum,
                               float* __restrict__ dinv, unsigned short* __restrict__ hb,
                               int N) {
    __shared__ int sh[256];
    int b = blockIdx.x, t = threadIdx.x;
    int base = b * 1024 + t * 4;
    int s = 0;
#pragma unroll
    for (int i = 0; i < 4; ++i) {
        int idx = base + i;
        int cv = (idx < N) ? cnt[idx] : 0;
        if (idx < N) dinv[idx] = rsqrtf((float)(cv + 1));   // +1 self loop
        s += (cv + 3) & ~3;
    }
    if (b == 0 && t < D) hb[(size_t)N * D + t] = 0;
    sh[t] = s;
    for (int ofs = 128; ofs > 0; ofs >>= 1) {
        __syncthreads();
        if (t < ofs) sh[t] += sh[t + ofs];
    }
    __syncthreads();
    if (t == 0) bsum[b] = sh[0];
}

// merged: block 0 = exclusive scan of block sums; block 1 = graph-count scan
__global__ void k_scan_small_g(const int* __restrict__ bsum, int* __restrict__ bbase, int nb,
                               const int* __restrict__ gcnt, int* __restrict__ goff,
                               int G, int N) {
    __shared__ int sh[256];
    int t = threadIdx.x;
    if (blockIdx.x == 0) {
        int v = (t < nb) ? bsum[t] : 0;
        sh[t] = v;
        __syncthreads();
        for (int ofs = 1; ofs < 256; ofs <<= 1) {
            int vv = (t >= ofs) ? sh[t - ofs] : 0;
            __syncthreads();
            sh[t] += vv;
            __syncthreads();
        }
        bbase[t] = sh[t] - v;   // exclusive
    } else {
        int base = t * 4;
        int v[4]; int s = 0;
#pragma unroll
        for (int i = 0; i < 4; ++i) { v[i] = (base + i < G) ? gcnt[base + i] : 0; s += v[i]; }
        sh[t] = s;
        __syncthreads();
        for (int ofs = 1; ofs < 256; ofs <<= 1) {
            int vv = (t >= ofs) ? sh[t - ofs] : 0;
            __syncthreads();
            sh[t] += vv;
            __syncthreads();
        }
        int o = sh[t] - s;
#pragma unroll
        for (int i = 0; i < 4; ++i) {
            int idx = base + i;
            if (idx < G) { goff[idx] = o; o += v[i]; }
        }
        if (t == 255) goff[G] = N;
    }
}

// scan apply; ALSO writes the per-node CSR pad slots (dummy index N)
__global__ void k_scan_apply(const int* __restrict__ cnt, const int* __restrict__ bbase,
                             int* __restrict__ roff, int* __restrict__ cur,
                             int* __restrict__ csr, int N) {
    __shared__ int sh[256];
    int b = blockIdx.x, t = threadIdx.x;
    int base = b * 1024 + t * 4;
    int vr[4], v[4]; int s = 0;
#pragma unroll
    for (int i = 0; i < 4; ++i) {
        int cv = (base + i < N) ? cnt[base + i] : 0;
        vr[i] = cv;
        v[i] = (cv + 3) & ~3;
        s += v[i];
    }
    sh[t] = s;
    __syncthreads();
    for (int ofs = 1; ofs < 256; ofs <<= 1) {
        int vv = (t >= ofs) ? sh[t - ofs] : 0;
        __syncthreads();
        sh[t] += vv;
        __syncthreads();
    }
    int o = bbase[b] + sh[t] - s;
#pragma unroll
    for (int i = 0; i < 4; ++i) {
        int idx = base + i;
        if (idx < N) {
            roff[idx] = o; cur[idx] = o;
            for (int p = vr[i]; p < v[i]; ++p) csr[o + p] = N;   // pads
            o += v[i];
            if (idx == N - 1) roff[N] = o;
        }
    }
}

__global__ void k_fill(const int* __restrict__ src, const int* __restrict__ dst,
                       int* __restrict__ cur, int* __restrict__ csr, int E) {
    int i = blockIdx.x * blockDim.x + threadIdx.x;
    if (i < E) {
        int p = atomicAdd(&cur[dst[i]], 1);
        csr[p] = src[i];
    }
}

// Merged pack + fold + BN-finalize. a/c derived in-kernel from prev stats.
__global__ void k_packfold(const float* __restrict__ W, const float* __restrict__ rW,
                           const float* __restrict__ gam, const float* __restrict__ bet,
                           const float* __restrict__ stats, const float* __restrict__ rb,
                           unsigned short* __restrict__ Wp,
                           float* __restrict__ cwA, float* __restrict__ crb,
                           int first, float invN) {
    if (blockIdx.x < 128) {
        int idx = blockIdx.x * 256 + threadIdx.x;       // 0..32767
        int m = idx >> 14;
        int i = idx & 16383;
        int k = i >> 7, col = i & 127;
        float a = 1.f;
        if (!first) {
            float mean = stats[k] * invN;
            float var = stats[D + k] * invN - mean * mean;
            a = gam[k] * rsqrtf(var + BN_EPS);
        }
        const float* src = m ? rW : W;
        float v = a * src[i];
        int frag = ((k >> 5) << 3) + (col >> 4);
        int lane = (((k & 31) >> 3) << 4) + (col & 15);
        int j = k & 7;
        Wp[(m << 14) + frag * 512 + lane * 8 + j] = f2bf(v);
    } else {
        __shared__ float csh[128];
        int t = threadIdx.x;  // 256
        if (t < D) {
            float c = 0.f;
            if (!first) {
                float mean = stats[t] * invN;
                float var = stats[D + t] * invN - mean * mean;
                float a = gam[t] * rsqrtf(var + BN_EPS);
                c = bet[t] - mean * a;
            }
            csh[t] = c;
        }
        __syncthreads();
        if (t < D) {
            float s = 0.f;
            for (int k = 0; k < D; ++k) s += csh[k] * W[k * D + t];
            cwA[t] = s;
        } else {
            int j = t - D;
            float s = rb[j];
            for (int k = 0; k < D; ++k) s += csh[k] * rW[k * D + j];
            crb[j] = s;
        }
    }
}

// ---------------- MFMA dual GEMM (LDS-transposed coalesced epilogue) --------
__global__ __launch_bounds__(256) void k_gemm_mfma(
    const unsigned short* __restrict__ fb,
    const unsigned short* __restrict__ Wp,    // [2][16384] packed frags
    const float* __restrict__ add0, const float* __restrict__ add1,
    const float* __restrict__ dinv,
    unsigned short* __restrict__ hb, unsigned short* __restrict__ rbuf, int N) {
    __shared__ unsigned short As[128 * 128];   // 32 KB, XOR-swizzled
    __shared__ unsigned short Wb[128 * 128];   // 32 KB: W frags, then epilogue
    const int t = threadIdx.x;
    const int rowbase = blockIdx.x * 128;

#pragma unroll
    for (int i = 0; i < 8; ++i) {
        int ch = t + i * 256;            // 16B chunk id, 0..2047
        int row = ch >> 4, slot = ch & 15;
        uint4 v = make_uint4(0, 0, 0, 0);
        int gr = rowbase + row;
        if (gr < N) v = *(const uint4*)(fb + (size_t)gr * D + slot * 8);
        *(uint4*)((char*)As + row * 256 + ((slot ^ (row & 7)) << 4)) = v;
    }

    const int wave = t >> 6, l = t & 63;
    const int wrow = wave * 32;
    const int lg = l >> 4, lc = l & 15;

    const int n0 = wrow + lc;                  // local node rows
    const int n1 = wrow + 16 + lc;
    const int g0 = rowbase + n0;               // global nodes
    const int g1 = rowbase + n1;
    const int f0 = lg * 4;                     // feature base within col-frag
    const int half = lg & 1;

#pragma unroll 1
    for (int m = 0; m < 2; ++m) {
        const unsigned short* wp = Wp + (m << 14);
        __syncthreads();
#pragma unroll
        for (int i = 0; i < 8; ++i) {
            int ch = t + i * 256;
            *(uint4*)((char*)Wb + ch * 16) = *(const uint4*)((const char*)wp + ch * 16);
        }
        __syncthreads();

        f32x4 acc[2][8];
#pragma unroll
        for (int nf = 0; nf < 2; ++nf)
#pragma unroll
            for (int cf = 0; cf < 8; ++cf) acc[nf][cf] = (f32x4){0.f, 0.f, 0.f, 0.f};

#pragma unroll
        for (int ks = 0; ks < 4; ++ks) {
            const int s = ks * 4 + lg;
            bf16x8 a0 = *(const bf16x8*)((const char*)As + n0 * 256 + ((s ^ (n0 & 7)) << 4));
            bf16x8 a1 = *(const bf16x8*)((const char*)As + n1 * 256 + ((s ^ (n1 & 7)) << 4));
#pragma unroll
            for (int cf = 0; cf < 8; ++cf) {
                bf16x8 b = *(const bf16x8*)((const char*)Wb + ((ks * 8 + cf) * 64 + l) * 16);
                acc[0][cf] = __builtin_amdgcn_mfma_f32_16x16x32_bf16(b, a0, acc[0][cf], 0, 0, 0);
                acc[1][cf] = __builtin_amdgcn_mfma_f32_16x16x32_bf16(b, a1, acc[1][cf], 0, 0, 0);
            }
        }

        __syncthreads();   // done reading Wb frags -> reuse as epilogue buf

        if (m == 0) {
            const float dv0 = (g0 < N) ? dinv[g0] : 0.f;
            const float dv1 = (g1 < N) ? dinv[g1] : 0.f;
#pragma unroll
            for (int cf = 0; cf < 8; ++cf) {
                const int fx = cf * 16 + f0;
                const float4 va = *(const float4*)(add0 + fx);
                const int slot = cf * 2 + (lg >> 1);
                uint2 p0, p1;
                p0.x = (unsigned int)f2bf((acc[0][cf][0] + va.x) * dv0) |
                       ((unsigned int)f2bf((acc[0][cf][1] + va.y) * dv0) << 16);
                p0.y = (unsigned int)f2bf((acc[0][cf][2] + va.z) * dv0) |
                       ((unsigned int)f2bf((acc[0][cf][3] + va.w) * dv0) << 16);
                p1.x = (unsigned int)f2bf((acc[1][cf][0] + va.x) * dv1) |
                       ((unsigned int)f2bf((acc[1][cf][1] + va.y) * dv1) << 16);
                p1.y = (unsigned int)f2bf((acc[1][cf][2] + va.z) * dv1) |
                       ((unsigned int)f2bf((acc[1][cf][3] + va.w) * dv1) << 16);
                *(uint2*)((char*)Wb + n0 * 256 + ((slot ^ (n0 & 7)) << 4) + half * 8) = p0;
                *(uint2*)((char*)Wb + n1 * 256 + ((slot ^ (n1 & 7)) << 4) + half * 8) = p1;
            }
        } else {
#pragma unroll
            for (int cf = 0; cf < 8; ++cf) {
                const int fx = cf * 16 + f0;
                const float4 va = *(const float4*)(add1 + fx);
                const int slot = cf * 2 + (lg >> 1);
                uint2 p0, p1;
                p0.x = (unsigned int)f2bf(fmaxf(acc[0][cf][0] + va.x, 0.f)) |
                       ((unsigned int)f2bf(fmaxf(acc[0][cf][1] + va.y, 0.f)) << 16);
                p0.y = (unsigned int)f2bf(fmaxf(acc[0][cf][2] + va.z, 0.f)) |
                       ((unsigned int)f2bf(fmaxf(acc[0][cf][3] + va.w, 0.f)) << 16);
                p1.x = (unsigned int)f2bf(fmaxf(acc[1][cf][0] + va.x, 0.f)) |
                       ((unsigned int)f2bf(fmaxf(acc[1][cf][1] + va.y, 0.f)) << 16);
                p1.y = (unsigned int)f2bf(fmaxf(acc[1][cf][2] + va.z, 0.f)) |
                       ((unsigned int)f2bf(fmaxf(acc[1][cf][3] + va.w, 0.f)) << 16);
                *(uint2*)((char*)Wb + n0 * 256 + ((slot ^ (n0 & 7)) << 4) + half * 8) = p0;
                *(uint2*)((char*)Wb + n1 * 256 + ((slot ^ (n1 & 7)) << 4) + half * 8) = p1;
            }
        }

        __syncthreads();   // epilogue tile complete

        unsigned short* __restrict__ dstp = (m == 0) ? hb : rbuf;
#pragma unroll
        for (int i = 0; i < 8; ++i) {
            int ch = t + i * 256;
            int row = ch >> 4, sl = ch & 15;
            int gr = rowbase + row;
            if (gr < N) {
                uint4 v = *(const uint4*)((const char*)Wb + row * 256 + ((sl ^ (row & 7)) << 4));
                *(uint4*)(dstp + (size_t)gr * D + sl * 8) = v;
            }
        }
    }
}

// ---------------- aggregation + residual + BN stats ----------------
// DUAL-NODE x DUAL-QUAD per wave: 4 independent gather-quads in flight per
// iteration. Clamped addresses + select-to-dummy-row guards keep the loop
// wave-uniform. CSR padded to x4 with dummy index N -> zero row.
__global__ __launch_bounds__(256) void k_agg(
    const unsigned short* __restrict__ hb, const unsigned short* __restrict__ resb,
    unsigned short* __restrict__ fbout,
    const int* __restrict__ roff, const int* __restrict__ csr,
    const float* __restrict__ dinv, const float* __restrict__ bias,
    float* __restrict__ stats, int N, int half) {
    const int tid = threadIdx.x;
    const int lane = tid & 63;
    const int g = lane >> 4;           // edge slot within quad
    const int li = lane & 15;          // 16-lane column group
    const int cs = li * 8;             // 8 bf16 columns per lane
    const int wid = (blockIdx.x * blockDim.x + tid) >> 6;
    const int nw = (gridDim.x * blockDim.x) >> 6;

    float bv[8];
#pragma unroll
    for (int k = 0; k < 8; ++k) bv[k] = bias[cs + k];

    float s8[8], q8[8];
#pragma unroll
    for (int k = 0; k < 8; ++k) { s8[k] = 0.f; q8[k] = 0.f; }

    for (int p = wid; p < half; p += nw) {
        const int vA = p;
        const int vB = p + half;
        const bool hasB = (vB < N);
        const int begA = roff[vA];
        const int qA = (roff[vA + 1] - begA) >> 2;
        int begB = begA, qB = 0;
        if (hasB) { begB = roff[vB]; qB = (roff[vB + 1] - begB) >> 2; }

        float accA[8], accB[8];
#pragma unroll
        for (int k = 0; k < 8; ++k) { accA[k] = 0.f; accB[k] = 0.f; }

        const int mq = (qA > qB) ? qA : qB;
        for (int i = 0; i < mq; i += 2) {
            // clamped quad addresses (reads past segment are discarded via select)
            int jA0 = i < qA ? i : (qA - 1); jA0 = jA0 < 0 ? 0 : jA0;
            int jA1 = (i + 1) < qA ? (i + 1) : (qA - 1); jA1 = jA1 < 0 ? 0 : jA1;
            int jB0 = i < qB ? i : (qB - 1); jB0 = jB0 < 0 ? 0 : jB0;
            int jB1 = (i + 1) < qB ? (i + 1) : (qB - 1); jB1 = jB1 < 0 ? 0 : jB1;
            const int4 a40 = *(const int4*)(csr + begA + jA0 * 4);
            const int4 a41 = *(const int4*)(csr + begA + jA1 * 4);
            const int4 b40 = *(const int4*)(csr + begB + jB0 * 4);
            const int4 b41 = *(const int4*)(csr + begB + jB1 * 4);
            int ua0 = (g == 0) ? a40.x : (g == 1) ? a40.y : (g == 2) ? a40.z : a40.w;
            int ua1 = (g == 0) ? a41.x : (g == 1) ? a41.y : (g == 2) ? a41.z : a41.w;
            int ub0 = (g == 0) ? b40.x : (g == 1) ? b40.y : (g == 2) ? b40.z : b40.w;
            int ub1 = (g == 0) ? b41.x : (g == 1) ? b41.y : (g == 2) ? b41.z : b41.w;
            ua0 = (i < qA) ? ua0 : N;
            ua1 = (i + 1 < qA) ? ua1 : N;
            ub0 = (i < qB) ? ub0 : N;
            ub1 = (i + 1 < qB) ? ub1 : N;
            const uint4 ga0 = *(const uint4*)(hb + (size_t)ua0 * D + cs);
            const uint4 ga1 = *(const uint4*)(hb + (size_t)ua1 * D + cs);
            const uint4 gb0 = *(const uint4*)(hb + (size_t)ub0 * D + cs);
            const uint4 gb1 = *(const uint4*)(hb + (size_t)ub1 * D + cs);
            accA[0] += bf_lo(ga0.x) + bf_lo(ga1.x); accA[1] += bf_hi(ga0.x) + bf_hi(ga1.x);
            accA[2] += bf_lo(ga0.y) + bf_lo(ga1.y); accA[3] += bf_hi(ga0.y) + bf_hi(ga1.y);
            accA[4] += bf_lo(ga0.z) + bf_lo(ga1.z); accA[5] += bf_hi(ga0.z) + bf_hi(ga1.z);
            accA[6] += bf_lo(ga0.w) + bf_lo(ga1.w); accA[7] += bf_hi(ga0.w) + bf_hi(ga1.w);
            accB[0] += bf_lo(gb0.x) + bf_lo(gb1.x); accB[1] += bf_hi(gb0.x) + bf_hi(gb1.x);
            accB[2] += bf_lo(gb0.y) + bf_lo(gb1.y); accB[3] += bf_hi(gb0.y) + bf_hi(gb1.y);
            accB[4] += bf_lo(gb0.z) + bf_lo(gb1.z); accB[5] += bf_hi(gb0.z) + bf_hi(gb1.z);
            accB[6] += bf_lo(gb0.w) + bf_lo(gb1.w); accB[7] += bf_hi(gb0.w) + bf_hi(gb1.w);
        }

        // fold the 4 edge-group partials
#pragma unroll
        for (int k = 0; k < 8; ++k) {
            accA[k] += __shfl_xor(accA[k], 16);
            accA[k] += __shfl_xor(accA[k], 32);
            accB[k] += __shfl_xor(accB[k], 16);
            accB[k] += __shfl_xor(accB[k], 32);
        }

        // ---- epilogue node A ----
        {
            const float dv = dinv[vA];
            const uint4 hs = *(const uint4*)(hb + (size_t)vA * D + cs);
            const uint4 rr = *(const uint4*)(resb + (size_t)vA * D + cs);
            float ox[8];
            ox[0] = (accA[0] + bf_lo(hs.x)) * dv + bv[0] + bf_lo(rr.x);
            ox[1] = (accA[1] + bf_hi(hs.x)) * dv + bv[1] + bf_hi(rr.x);
            ox[2] = (accA[2] + bf_lo(hs.y)) * dv + bv[2] + bf_lo(rr.y);
            ox[3] = (accA[3] + bf_hi(hs.y)) * dv + bv[3] + bf_hi(rr.y);
            ox[4] = (accA[4] + bf_lo(hs.z)) * dv + bv[4] + bf_lo(rr.z);
            ox[5] = (accA[5] + bf_hi(hs.z)) * dv + bv[5] + bf_hi(rr.z);
            ox[6] = (accA[6] + bf_lo(hs.w)) * dv + bv[6] + bf_lo(rr.w);
            ox[7] = (accA[7] + bf_hi(hs.w)) * dv + bv[7] + bf_hi(rr.w);
            if (g == 0) {
                uint4 pk;
                pk.x = (unsigned int)f2bf(ox[0]) | ((unsigned int)f2bf(ox[1]) << 16);
                pk.y = (unsigned int)f2bf(ox[2]) | ((unsigned int)f2bf(ox[3]) << 16);
                pk.z = (unsigned int)f2bf(ox[4]) | ((unsigned int)f2bf(ox[5]) << 16);
                pk.w = (unsigned int)f2bf(ox[6]) | ((unsigned int)f2bf(ox[7]) << 16);
                *(uint4*)(fbout + (size_t)vA * D + cs) = pk;
#pragma unroll
                for (int k = 0; k < 8; ++k) { s8[k] += ox[k]; q8[k] += ox[k] * ox[k]; }
            }
        }
        // ---- epilogue node B ----
        if (hasB) {
            const float dv = dinv[vB];
            const uint4 hs = *(const uint4*)(hb + (size_t)vB * D + cs);
            const uint4 rr = *(const uint4*)(resb + (size_t)vB * D + cs);
            float ox[8];
            ox[0] = (accB[0] + bf_lo(hs.x)) * dv + bv[0] + bf_lo(rr.x);
            ox[1] = (accB[1] + bf_hi(hs.x)) * dv + bv[1] + bf_hi(rr.x);
            ox[2] = (accB[2] + bf_lo(hs.y)) * dv + bv[2] + bf_lo(rr.y);
            ox[3] = (accB[3] + bf_hi(hs.y)) * dv + bv[3] + bf_hi(rr.y);
            ox[4] = (accB[4] + bf_lo(hs.z)) * dv + bv[4] + bf_lo(rr.z);
            ox[5] = (accB[5] + bf_hi(hs.z)) * dv + bv[5] + bf_hi(rr.z);
            ox[6] = (accB[6] + bf_lo(hs.w)) * dv + bv[6] + bf_lo(rr.w);
            ox[7] = (accB[7] + bf_hi(hs.w)) * dv + bv[7] + bf_hi(rr.w);
            if (g == 0) {
                uint4 pk;
                pk.x = (unsigned int)f2bf(ox[0]) | ((unsigned int)f2bf(ox[1]) << 16);
                pk.y = (unsigned int)f2bf(ox[2]) | ((unsigned int)f2bf(ox[3]) << 16);
                pk.z = (unsigned int)f2bf(ox[4]) | ((unsigned int)f2bf(ox[5]) << 16);
                pk.w = (unsigned int)f2bf(ox[6]) | ((unsigned int)f2bf(ox[7]) << 16);
                *(uint4*)(fbout + (size_t)vB * D + cs) = pk;
#pragma unroll
                for (int k = 0; k < 8; ++k) { s8[k] += ox[k]; q8[k] += ox[k] * ox[k]; }
            }
        }
    }

    // block-level BN-stats reduction: lanes g==0 hold valid partials
    __shared__ float sred[4][16][8];
    __shared__ float qred[4][16][8];
    const int w = tid >> 6;
    if (g == 0) {
#pragma unroll
        for (int k = 0; k < 8; ++k) { sred[w][li][k] = s8[k]; qred[w][li][k] = q8[k]; }
    }
    __syncthreads();
    if (tid < D) {
        const int col = tid;
        float ts = 0.f, tq = 0.f;
#pragma unroll
        for (int ww = 0; ww < 4; ++ww) {
            ts += sred[ww][col >> 3][col & 7];
            tq += qred[ww][col >> 3][col & 7];
        }
        atomicAdd(&stats[col], ts);
        atomicAdd(&stats[D + col], tq);
    }
}

// pool with embedded final BN: a,c computed per-block from last stats
__global__ void k_pool(const unsigned short* __restrict__ fb, const int* __restrict__ goff,
                       const float* __restrict__ gam, const float* __restrict__ bet,
                       const float* __restrict__ stats, float invN,
                       float* __restrict__ out) {
    int g = blockIdx.x, t = threadIdx.x;  // 128 threads
    float mean = stats[t] * invN;
    float var = stats[D + t] * invN - mean * mean;
    float a = gam[t] * rsqrtf(var + BN_EPS);
    float c = bet[t] - mean * a;
    int beg = goff[g], end = goff[g + 1];
    float acc = 0.f;
    for (int v = beg; v < end; ++v) acc += bf2f(fb[(size_t)v * D + t]);
    out[(size_t)g * D + t] = acc * a + (float)(end - beg) * c;
}

// ---------------- launcher ----------------

extern "C" void kernel_launch(void* const* d_in, const int* in_sizes, int n_in,
                              void* d_out, int out_size, void* d_ws, size_t ws_size,
                              hipStream_t stream) {
    const float* x      = (const float*)d_in[0];
    const int*   ei     = (const int*)d_in[1];
    const int*   batch  = (const int*)d_in[2];
    const float* Ws     = (const float*)d_in[3];
    const float* bs     = (const float*)d_in[4];
    const float* rWs    = (const float*)d_in[5];
    const float* rbs    = (const float*)d_in[6];
    const float* gammas = (const float*)d_in[7];
    const float* betas  = (const float*)d_in[8];
    float* out = (float*)d_out;

    const int N = in_sizes[2];
    const int E = in_sizes[1] / 2;
    const int G = out_size / D;
    const int* src = ei;
    const int* dst = ei + E;
    const int EP = E + 4 * N + 8;   // padded-CSR upper bound (+2 quad guard)
    const int half = (N + 1) >> 1;
    const float invN = 1.0f / (float)N;
    const int n8 = N * (D / 8);

    char* ws = (char*)d_ws;
    size_t off = 0;
    auto alloc = [&](size_t bytes) -> char* {
        char* p = ws + off;
        off += (bytes + 255) & ~(size_t)255;
        return p;
    };
    unsigned short* hb = (unsigned short*)alloc((size_t)(N + 1) * D * 2);
    unsigned short* fb = (unsigned short*)alloc((size_t)N * D * 2);
    unsigned short* rbuf = (unsigned short*)alloc((size_t)N * D * 2);
    int*   csr  = (int*)alloc((size_t)EP * 4);
    int*   roff = (int*)alloc((size_t)(N + 1) * 4);
    int*   cur  = (int*)alloc((size_t)N * 4);
    int*   cnt  = (int*)alloc((size_t)N * 4);
    float* dinv = (float*)alloc((size_t)N * 4);
    int*   gcnt = (int*)alloc((size_t)G * 4);
    int*   goff = (int*)alloc((size_t)(G + 1) * 4);
    int*   bsum = (int*)alloc(256 * 4);
    int*   bbase= (int*)alloc(256 * 4);
    float* stats= (float*)alloc((size_t)NLAYERS * 2 * D * 4);
    unsigned short* Wp = (unsigned short*)alloc((size_t)2 * D * D * 2);
    float* cwA  = (float*)alloc(D * 4);
    float* crb  = (float*)alloc(D * 4);
    (void)ws_size;

    const int S = NLAYERS * 2 * D;
    k_zero<<<(N + G + S + 255) / 256, 256, 0, stream>>>(cnt, gcnt, (int*)stats, N, G, S);
    k_hist_xb<<<(E + N + n8 + 255) / 256, 256, 0, stream>>>(dst, batch, x, cnt, gcnt,
                                                            fb, E, N, n8);

    int nb = (N + 1023) / 1024;
    k_scan_partial<<<nb, 256, 0, stream>>>(cnt, bsum, dinv, hb, N);
    k_scan_small_g<<<2, 256, 0, stream>>>(bsum, bbase, nb, gcnt, goff, G, N);
    k_scan_apply<<<nb, 256, 0, stream>>>(cnt, bbase, roff, cur, csr, N);
    k_fill<<<(E + 255) / 256, 256, 0, stream>>>(src, dst, cur, csr, E);

    for (int l = 0; l < NLAYERS; ++l) {
        const float* W  = Ws + (size_t)l * D * D;
        const float* rW = rWs + (size_t)l * D * D;
        const float* gamP = gammas + (size_t)(l > 0 ? l - 1 : 0) * D;
        const float* betP = betas + (size_t)(l > 0 ? l - 1 : 0) * D;
        const float* stP  = stats + (size_t)(l > 0 ? l - 1 : 0) * 2 * D;

        k_packfold<<<129, 256, 0, stream>>>(W, rW, gamP, betP, stP,
                                            rbs + (size_t)l * D,
                                            Wp, cwA, crb, (l == 0) ? 1 : 0, invN);

        k_gemm_mfma<<<(N + 127) / 128, 256, 0, stream>>>(fb, Wp, cwA, crb, dinv,
                                                         hb, rbuf, N);
        k_agg<<<4096, 256, 0, stream>>>(hb, rbuf, fb, roff, csr, dinv,
                                        bs + (size_t)l * D,
                                        stats + (size_t)l * 2 * D, N, half);
    }

    k_pool<<<G, 128, 0, stream>>>(fb, goff,
                                  gammas + (size_t)(NLAYERS - 1) * D,
                                  betas + (size_t)(NLAYERS - 1) * D,
                                  stats + (size_t)(NLAYERS - 1) * 2 * D,
                                  invN, out);
}

// Round 13
// 742.298 us; speedup vs baseline: 2.0161x; 1.0054x over previous
//
#include <hip/hip_runtime.h>

#define D 128
#define NLAYERS 3
#define BN_EPS 1e-5f

typedef short bf16x8 __attribute__((ext_vector_type(8)));
typedef float f32x4 __attribute__((ext_vector_type(4)));

__device__ __forceinline__ unsigned short f2bf(float f) {
    unsigned int u = __float_as_uint(f);
    u += 0x7FFFu + ((u >> 16) & 1u);   // round-to-nearest-even
    return (unsigned short)(u >> 16);
}
__device__ __forceinline__ float bf2f(unsigned short b) {
    return __uint_as_float(((unsigned int)b) << 16);
}
__device__ __forceinline__ float bf_lo(unsigned int u) {
    return __uint_as_float(u << 16);
}
__device__ __forceinline__ float bf_hi(unsigned int u) {
    return __uint_as_float(u & 0xFFFF0000u);
}

// ---------------- setup kernels ----------------

// zero cnt + gcnt + stats in one dispatch
__global__ void k_zero(int* __restrict__ cnt, int* __restrict__ gcnt,
                       int* __restrict__ stats, int N, int G, int S) {
    int i = blockIdx.x * blockDim.x + threadIdx.x;
    if (i < N) cnt[i] = 0;
    else if (i < N + G) gcnt[i - N] = 0;
    else if (i < N + G + S) stats[i - N - G] = 0;
}

// merged: edge histogram + batch histogram + x->bf16 convert
__global__ void k_hist_xb(const int* __restrict__ dst, const int* __restrict__ batch,
                          const float* __restrict__ x,
                          int* __restrict__ cnt, int* __restrict__ gcnt,
                          unsigned short* __restrict__ fb, int E, int N, int n8) {
    int i = blockIdx.x * blockDim.x + threadIdx.x;
    if (i < E) {
        atomicAdd(&cnt[dst[i]], 1);
    } else if (i < E + N) {
        atomicAdd(&gcnt[batch[i - E]], 1);
    } else {
        int j = i - E - N;
        if (j < n8) {
            const float4 a = ((const float4*)x)[j * 2];
            const float4 b = ((const float4*)x)[j * 2 + 1];
            uint4 p;
            p.x = (unsigned int)f2bf(a.x) | ((unsigned int)f2bf(a.y) << 16);
            p.y = (unsigned int)f2bf(a.z) | ((unsigned int)f2bf(a.w) << 16);
            p.z = (unsigned int)f2bf(b.x) | ((unsigned int)f2bf(b.y) << 16);
            p.w = (unsigned int)f2bf(b.z) | ((unsigned int)f2bf(b.w) << 16);
            ((uint4*)fb)[j] = p;
        }
    }
}

// partial sums of PADDED counts; also computes dinv and zeroes dummy hb row
__global__ void k_scan_partial(const int* __restrict__ cnt, int* __restrict__ bsum,
                               float* __restrict__ dinv, unsigned short* __restrict__ hb,
                               int N) {
    __shared__ int sh[256];
    int b = blockIdx.x, t = threadIdx.x;
    int base = b * 1024 + t * 4;
    int s = 0;
#pragma unroll
    for (int i = 0; i < 4; ++i) {
        int idx = base + i;
        int cv = (idx < N) ? cnt[idx] : 0;
        if (idx < N) dinv[idx] = rsqrtf((float)(cv + 1));   // +1 self loop
        s += (cv + 3) & ~3;
    }
    if (b == 0 && t < D) hb[(size_t)N * D + t] = 0;
    sh[t] = s;
    for (int ofs = 128; ofs > 0; ofs >>= 1) {
        __syncthreads();
        if (t < ofs) sh[t] += sh[t + ofs];
    }
    __syncthreads();
    if (t == 0) bsum[b] = sh[0];
}

// merged: block 0 = exclusive scan of block sums; block 1 = graph-count scan
__global__ void k_scan_small_g(const int* __restrict__ bsum, int* __restrict__ bbase, int nb,
                               const int* __restrict__ gcnt, int* __restrict__ goff,
                               int G, int N) {
    __shared__ int sh[256];
    int t = threadIdx.x;
    if (blockIdx.x == 0) {
        int v = (t < nb) ? bsum[t] : 0;
        sh[t] = v;
        __syncthreads();
        for (int ofs = 1; ofs < 256; ofs <<= 1) {
            int vv = (t >= ofs) ? sh[t - ofs] : 0;
            __syncthreads();
            sh[t] += vv;
            __syncthreads();
        }
        bbase[t] = sh[t] - v;   // exclusive
    } else {
        int base = t * 4;
        int v[4]; int s = 0;
#pragma unroll
        for (int i = 0; i < 4; ++i) { v[i] = (base + i < G) ? gcnt[base + i] : 0; s += v[i]; }
        sh[t] = s;
        __syncthreads();
        for (int ofs = 1; ofs < 256; ofs <<= 1) {
            int vv = (t >= ofs) ? sh[t - ofs] : 0;
            __syncthreads();
            sh[t] += vv;
            __syncthreads();
        }
        int o = sh[t] - s;
#pragma unroll
        for (int i = 0; i < 4; ++i) {
            int idx = base + i;
            if (idx < G) { goff[idx] = o; o += v[i]; }
        }
        if (t == 255) goff[G] = N;
    }
}

// scan apply; ALSO writes the per-node CSR pad slots (dummy index N)
__global__ void k_scan_apply(const int* __restrict__ cnt, const int* __restrict__ bbase,
                             int* __restrict__ roff, int* __restrict__ cur,
                             int* __restrict__ csr, int N) {
    __shared__ int sh[256];
    int b = blockIdx.x, t = threadIdx.x;
    int base = b * 1024 + t * 4;
    int vr[4], v[4]; int s = 0;
#pragma unroll
    for (int i = 0; i < 4; ++i) {
        int cv = (base + i < N) ? cnt[base + i] : 0;
        vr[i] = cv;
        v[i] = (cv + 3) & ~3;
        s += v[i];
    }
    sh[t] = s;
    __syncthreads();
    for (int ofs = 1; ofs < 256; ofs <<= 1) {
        int vv = (t >= ofs) ? sh[t - ofs] : 0;
        __syncthreads();
        sh[t] += vv;
        __syncthreads();
    }
    int o = bbase[b] + sh[t] - s;
#pragma unroll
    for (int i = 0; i < 4; ++i) {
        int idx = base + i;
        if (idx < N) {
            roff[idx] = o; cur[idx] = o;
            for (int p = vr[i]; p < v[i]; ++p) csr[o + p] = N;   // pads
            o += v[i];
            if (idx == N - 1) roff[N] = o;
        }
    }
}

__global__ void k_fill(const int* __restrict__ src, const int* __restrict__ dst,
                       int* __restrict__ cur, int* __restrict__ csr, int E) {
    int i = blockIdx.x * blockDim.x + threadIdx.x;
    if (i < E) {
        int p = atomicAdd(&cur[dst[i]], 1);
        csr[p] = src[i];
    }
}

// Merged pack + fold + BN-finalize. a/c derived in-kernel from prev stats.
__global__ void k_packfold(const float* __restrict__ W, const float* __restrict__ rW,
                           const float* __restrict__ gam, const float* __restrict__ bet,
                           const float* __restrict__ stats, const float* __restrict__ rb,
                           unsigned short* __restrict__ Wp,
                           float* __restrict__ cwA, float* __restrict__ crb,
                           int first, float invN) {
    if (blockIdx.x < 128) {
        int idx = blockIdx.x * 256 + threadIdx.x;       // 0..32767
        int m = idx >> 14;
        int i = idx & 16383;
        int k = i >> 7, col = i & 127;
        float a = 1.f;
        if (!first) {
            float mean = stats[k] * invN;
            float var = stats[D + k] * invN - mean * mean;
            a = gam[k] * rsqrtf(var + BN_EPS);
        }
        const float* src = m ? rW : W;
        float v = a * src[i];
        int frag = ((k >> 5) << 3) + (col >> 4);
        int lane = (((k & 31) >> 3) << 4) + (col & 15);
        int j = k & 7;
        Wp[(m << 14) + frag * 512 + lane * 8 + j] = f2bf(v);
    } else {
        __shared__ float csh[128];
        int t = threadIdx.x;  // 256
        if (t < D) {
            float c = 0.f;
            if (!first) {
                float mean = stats[t] * invN;
                float var = stats[D + t] * invN - mean * mean;
                float a = gam[t] * rsqrtf(var + BN_EPS);
                c = bet[t] - mean * a;
            }
            csh[t] = c;
        }
        __syncthreads();
        if (t < D) {
            float s = 0.f;
            for (int k = 0; k < D; ++k) s += csh[k] * W[k * D + t];
            cwA[t] = s;
        } else {
            int j = t - D;
            float s = rb[j];
            for (int k = 0; k < D; ++k) s += csh[k] * rW[k * D + j];
            crb[j] = s;
        }
    }
}

// ---------------- MFMA GEMM, 64-row tiles, one GEMM per block ----------------
// blockIdx.y = m: m=0 -> hb = (fb@W0 + add0)*dinv ; m=1 -> rbuf = relu(fb@W1+add1)
// As 16 KB + Wb 32 KB = 48 KB -> 3 blocks/CU. All 12 global loads issued
// before ONE barrier; single MFMA pass; epilogue reuses As; coalesced stores.
__global__ __launch_bounds__(256) void k_gemm_mfma(
    const unsigned short* __restrict__ fb,
    const unsigned short* __restrict__ Wp,    // [2][16384] packed frags
    const float* __restrict__ add0, const float* __restrict__ add1,
    const float* __restrict__ dinv,
    unsigned short* __restrict__ hb, unsigned short* __restrict__ rbuf, int N) {
    __shared__ unsigned short As[64 * 128];    // 16 KB, XOR-swizzled
    __shared__ unsigned short Wb[128 * 128];   // 32 KB, linear frag layout
    const int t = threadIdx.x;
    const int m = blockIdx.y;
    const int rowbase = blockIdx.x * 64;
    const unsigned short* wp = Wp + (m << 14);

    // stage A tile (64 rows x 256B) — 1024 chunks of 16B
#pragma unroll
    for (int i = 0; i < 4; ++i) {
        int ch = t + i * 256;
        int row = ch >> 4, slot = ch & 15;
        uint4 v = make_uint4(0, 0, 0, 0);
        int gr = rowbase + row;
        if (gr < N) v = *(const uint4*)(fb + (size_t)gr * D + slot * 8);
        *(uint4*)((char*)As + row * 256 + ((slot ^ (row & 7)) << 4)) = v;
    }
    // stage this GEMM's W frags (32 KB) — 2048 chunks
#pragma unroll
    for (int i = 0; i < 8; ++i) {
        int ch = t + i * 256;
        *(uint4*)((char*)Wb + ch * 16) = *(const uint4*)((const char*)wp + ch * 16);
    }
    __syncthreads();

    const int wave = t >> 6, l = t & 63;
    const int wrow = wave * 16;
    const int lg = l >> 4, lc = l & 15;
    const int n0 = wrow + lc;                  // local node row
    const int g0 = rowbase + n0;               // global node
    const int f0 = lg * 4;                     // feature base within col-frag
    const int half = lg & 1;

    f32x4 acc[8];
#pragma unroll
    for (int cf = 0; cf < 8; ++cf) acc[cf] = (f32x4){0.f, 0.f, 0.f, 0.f};

#pragma unroll
    for (int ks = 0; ks < 4; ++ks) {
        const int s = ks * 4 + lg;
        bf16x8 a0 = *(const bf16x8*)((const char*)As + n0 * 256 + ((s ^ (n0 & 7)) << 4));
#pragma unroll
        for (int cf = 0; cf < 8; ++cf) {
            bf16x8 b = *(const bf16x8*)((const char*)Wb + ((ks * 8 + cf) * 64 + l) * 16);
            // W frag as A (row=feature), activation frag as B (col=node)
            acc[cf] = __builtin_amdgcn_mfma_f32_16x16x32_bf16(b, a0, acc[cf], 0, 0, 0);
        }
    }

    __syncthreads();   // As consumed -> reuse as epilogue buffer

    if (m == 0) {
        const float dv0 = (g0 < N) ? dinv[g0] : 0.f;
#pragma unroll
        for (int cf = 0; cf < 8; ++cf) {
            const int fx = cf * 16 + f0;
            const float4 va = *(const float4*)(add0 + fx);
            const int slot = cf * 2 + (lg >> 1);
            uint2 p0;
            p0.x = (unsigned int)f2bf((acc[cf][0] + va.x) * dv0) |
                   ((unsigned int)f2bf((acc[cf][1] + va.y) * dv0) << 16);
            p0.y = (unsigned int)f2bf((acc[cf][2] + va.z) * dv0) |
                   ((unsigned int)f2bf((acc[cf][3] + va.w) * dv0) << 16);
            *(uint2*)((char*)As + n0 * 256 + ((slot ^ (n0 & 7)) << 4) + half * 8) = p0;
        }
    } else {
#pragma unroll
        for (int cf = 0; cf < 8; ++cf) {
            const int fx = cf * 16 + f0;
            const float4 va = *(const float4*)(add1 + fx);
            const int slot = cf * 2 + (lg >> 1);
            uint2 p0;
            p0.x = (unsigned int)f2bf(fmaxf(acc[cf][0] + va.x, 0.f)) |
                   ((unsigned int)f2bf(fmaxf(acc[cf][1] + va.y, 0.f)) << 16);
            p0.y = (unsigned int)f2bf(fmaxf(acc[cf][2] + va.z, 0.f)) |
                   ((unsigned int)f2bf(fmaxf(acc[cf][3] + va.w, 0.f)) << 16);
            *(uint2*)((char*)As + n0 * 256 + ((slot ^ (n0 & 7)) << 4) + half * 8) = p0;
        }
    }

    __syncthreads();   // epilogue tile complete

    unsigned short* __restrict__ dstp = (m == 0) ? hb : rbuf;
#pragma unroll
    for (int i = 0; i < 4; ++i) {
        int ch = t + i * 256;
        int row = ch >> 4, sl = ch & 15;
        int gr = rowbase + row;
        if (gr < N) {
            uint4 v = *(const uint4*)((const char*)As + row * 256 + ((sl ^ (row & 7)) << 4));
            *(uint4*)(dstp + (size_t)gr * D + sl * 8) = v;
        }
    }
}

// ---------------- aggregation + residual + BN stats ----------------
// DUAL-NODE x DUAL-QUAD per wave: 4 independent gather-quads in flight per
// iteration. Clamped addresses + select-to-dummy-row guards keep the loop
// wave-uniform. CSR padded to x4 with dummy index N -> zero row.
__global__ __launch_bounds__(256) void k_agg(
    const unsigned short* __restrict__ hb, const unsigned short* __restrict__ resb,
    unsigned short* __restrict__ fbout,
    const int* __restrict__ roff, const int* __restrict__ csr,
    const float* __restrict__ dinv, const float* __restrict__ bias,
    float* __restrict__ stats, int N, int half) {
    const int tid = threadIdx.x;
    const int lane = tid & 63;
    const int g = lane >> 4;           // edge slot within quad
    const int li = lane & 15;          // 16-lane column group
    const int cs = li * 8;             // 8 bf16 columns per lane
    const int wid = (blockIdx.x * blockDim.x + tid) >> 6;
    const int nw = (gridDim.x * blockDim.x) >> 6;

    float bv[8];
#pragma unroll
    for (int k = 0; k < 8; ++k) bv[k] = bias[cs + k];

    float s8[8], q8[8];
#pragma unroll
    for (int k = 0; k < 8; ++k) { s8[k] = 0.f; q8[k] = 0.f; }

    for (int p = wid; p < half; p += nw) {
        const int vA = p;
        const int vB = p + half;
        const bool hasB = (vB < N);
        const int begA = roff[vA];
        const int qA = (roff[vA + 1] - begA) >> 2;
        int begB = begA, qB = 0;
        if (hasB) { begB = roff[vB]; qB = (roff[vB + 1] - begB) >> 2; }

        float accA[8], accB[8];
#pragma unroll
        for (int k = 0; k < 8; ++k) { accA[k] = 0.f; accB[k] = 0.f; }

        const int mq = (qA > qB) ? qA : qB;
        for (int i = 0; i < mq; i += 2) {
            int jA0 = i < qA ? i : (qA - 1); jA0 = jA0 < 0 ? 0 : jA0;
            int jA1 = (i + 1) < qA ? (i + 1) : (qA - 1); jA1 = jA1 < 0 ? 0 : jA1;
            int jB0 = i < qB ? i : (qB - 1); jB0 = jB0 < 0 ? 0 : jB0;
            int jB1 = (i + 1) < qB ? (i + 1) : (qB - 1); jB1 = jB1 < 0 ? 0 : jB1;
            const int4 a40 = *(const int4*)(csr + begA + jA0 * 4);
            const int4 a41 = *(const int4*)(csr + begA + jA1 * 4);
            const int4 b40 = *(const int4*)(csr + begB + jB0 * 4);
            const int4 b41 = *(const int4*)(csr + begB + jB1 * 4);
            int ua0 = (g == 0) ? a40.x : (g == 1) ? a40.y : (g == 2) ? a40.z : a40.w;
            int ua1 = (g == 0) ? a41.x : (g == 1) ? a41.y : (g == 2) ? a41.z : a41.w;
            int ub0 = (g == 0) ? b40.x : (g == 1) ? b40.y : (g == 2) ? b40.z : b40.w;
            int ub1 = (g == 0) ? b41.x : (g == 1) ? b41.y : (g == 2) ? b41.z : b41.w;
            ua0 = (i < qA) ? ua0 : N;
            ua1 = (i + 1 < qA) ? ua1 : N;
            ub0 = (i < qB) ? ub0 : N;
            ub1 = (i + 1 < qB) ? ub1 : N;
            const uint4 ga0 = *(const uint4*)(hb + (size_t)ua0 * D + cs);
            const uint4 ga1 = *(const uint4*)(hb + (size_t)ua1 * D + cs);
            const uint4 gb0 = *(const uint4*)(hb + (size_t)ub0 * D + cs);
            const uint4 gb1 = *(const uint4*)(hb + (size_t)ub1 * D + cs);
            accA[0] += bf_lo(ga0.x) + bf_lo(ga1.x); accA[1] += bf_hi(ga0.x) + bf_hi(ga1.x);
            accA[2] += bf_lo(ga0.y) + bf_lo(ga1.y); accA[3] += bf_hi(ga0.y) + bf_hi(ga1.y);
            accA[4] += bf_lo(ga0.z) + bf_lo(ga1.z); accA[5] += bf_hi(ga0.z) + bf_hi(ga1.z);
            accA[6] += bf_lo(ga0.w) + bf_lo(ga1.w); accA[7] += bf_hi(ga0.w) + bf_hi(ga1.w);
            accB[0] += bf_lo(gb0.x) + bf_lo(gb1.x); accB[1] += bf_hi(gb0.x) + bf_hi(gb1.x);
            accB[2] += bf_lo(gb0.y) + bf_lo(gb1.y); accB[3] += bf_hi(gb0.y) + bf_hi(gb1.y);
            accB[4] += bf_lo(gb0.z) + bf_lo(gb1.z); accB[5] += bf_hi(gb0.z) + bf_hi(gb1.z);
            accB[6] += bf_lo(gb0.w) + bf_lo(gb1.w); accB[7] += bf_hi(gb0.w) + bf_hi(gb1.w);
        }

        // fold the 4 edge-group partials
#pragma unroll
        for (int k = 0; k < 8; ++k) {
            accA[k] += __shfl_xor(accA[k], 16);
            accA[k] += __shfl_xor(accA[k], 32);
            accB[k] += __shfl_xor(accB[k], 16);
            accB[k] += __shfl_xor(accB[k], 32);
        }

        // ---- epilogue node A ----
        {
            const float dv = dinv[vA];
            const uint4 hs = *(const uint4*)(hb + (size_t)vA * D + cs);
            const uint4 rr = *(const uint4*)(resb + (size_t)vA * D + cs);
            float ox[8];
            ox[0] = (accA[0] + bf_lo(hs.x)) * dv + bv[0] + bf_lo(rr.x);
            ox[1] = (accA[1] + bf_hi(hs.x)) * dv + bv[1] + bf_hi(rr.x);
            ox[2] = (accA[2] + bf_lo(hs.y)) * dv + bv[2] + bf_lo(rr.y);
            ox[3] = (accA[3] + bf_hi(hs.y)) * dv + bv[3] + bf_hi(rr.y);
            ox[4] = (accA[4] + bf_lo(hs.z)) * dv + bv[4] + bf_lo(rr.z);
            ox[5] = (accA[5] + bf_hi(hs.z)) * dv + bv[5] + bf_hi(rr.z);
            ox[6] = (accA[6] + bf_lo(hs.w)) * dv + bv[6] + bf_lo(rr.w);
            ox[7] = (accA[7] + bf_hi(hs.w)) * dv + bv[7] + bf_hi(rr.w);
            if (g == 0) {
                uint4 pk;
                pk.x = (unsigned int)f2bf(ox[0]) | ((unsigned int)f2bf(ox[1]) << 16);
                pk.y = (unsigned int)f2bf(ox[2]) | ((unsigned int)f2bf(ox[3]) << 16);
                pk.z = (unsigned int)f2bf(ox[4]) | ((unsigned int)f2bf(ox[5]) << 16);
                pk.w = (unsigned int)f2bf(ox[6]) | ((unsigned int)f2bf(ox[7]) << 16);
                *(uint4*)(fbout + (size_t)vA * D + cs) = pk;
#pragma unroll
                for (int k = 0; k < 8; ++k) { s8[k] += ox[k]; q8[k] += ox[k] * ox[k]; }
            }
        }
        // ---- epilogue node B ----
        if (hasB) {
            const float dv = dinv[vB];
            const uint4 hs = *(const uint4*)(hb + (size_t)vB * D + cs);
            const uint4 rr = *(const uint4*)(resb + (size_t)vB * D + cs);
            float ox[8];
            ox[0] = (accB[0] + bf_lo(hs.x)) * dv + bv[0] + bf_lo(rr.x);
            ox[1] = (accB[1] + bf_hi(hs.x)) * dv + bv[1] + bf_hi(rr.x);
            ox[2] = (accB[2] + bf_lo(hs.y)) * dv + bv[2] + bf_lo(rr.y);
            ox[3] = (accB[3] + bf_hi(hs.y)) * dv + bv[3] + bf_hi(rr.y);
            ox[4] = (accB[4] + bf_lo(hs.z)) * dv + bv[4] + bf_lo(rr.z);
            ox[5] = (accB[5] + bf_hi(hs.z)) * dv + bv[5] + bf_hi(rr.z);
            ox[6] = (accB[6] + bf_lo(hs.w)) * dv + bv[6] + bf_lo(rr.w);
            ox[7] = (accB[7] + bf_hi(hs.w)) * dv + bv[7] + bf_hi(rr.w);
            if (g == 0) {
                uint4 pk;
                pk.x = (unsigned int)f2bf(ox[0]) | ((unsigned int)f2bf(ox[1]) << 16);
                pk.y = (unsigned int)f2bf(ox[2]) | ((unsigned int)f2bf(ox[3]) << 16);
                pk.z = (unsigned int)f2bf(ox[4]) | ((unsigned int)f2bf(ox[5]) << 16);
                pk.w = (unsigned int)f2bf(ox[6]) | ((unsigned int)f2bf(ox[7]) << 16);
                *(uint4*)(fbout + (size_t)vB * D + cs) = pk;
#pragma unroll
                for (int k = 0; k < 8; ++k) { s8[k] += ox[k]; q8[k] += ox[k] * ox[k]; }
            }
        }
    }

    // block-level BN-stats reduction: lanes g==0 hold valid partials
    __shared__ float sred[4][16][8];
    __shared__ float qred[4][16][8];
    const int w = tid >> 6;
    if (g == 0) {
#pragma unroll
        for (int k = 0; k < 8; ++k) { sred[w][li][k] = s8[k]; qred[w][li][k] = q8[k]; }
    }
    __syncthreads();
    if (tid < D) {
        const int col = tid;
        float ts = 0.f, tq = 0.f;
#pragma unroll
        for (int ww = 0; ww < 4; ++ww) {
            ts += sred[ww][col >> 3][col & 7];
            tq += qred[ww][col >> 3][col & 7];
        }
        atomicAdd(&stats[col], ts);
        atomicAdd(&stats[D + col], tq);
    }
}

// pool with embedded final BN: a,c computed per-block from last stats
__global__ void k_pool(const unsigned short* __restrict__ fb, const int* __restrict__ goff,
                       const float* __restrict__ gam, const float* __restrict__ bet,
                       const float* __restrict__ stats, float invN,
                       float* __restrict__ out) {
    int g = blockIdx.x, t = threadIdx.x;  // 128 threads
    float mean = stats[t] * invN;
    float var = stats[D + t] * invN - mean * mean;
    float a = gam[t] * rsqrtf(var + BN_EPS);
    float c = bet[t] - mean * a;
    int beg = goff[g], end = goff[g + 1];
    float acc = 0.f;
    for (int v = beg; v < end; ++v) acc += bf2f(fb[(size_t)v * D + t]);
    out[(size_t)g * D + t] = acc * a + (float)(end - beg) * c;
}

// ---------------- launcher ----------------

extern "C" void kernel_launch(void* const* d_in, const int* in_sizes, int n_in,
                              void* d_out, int out_size, void* d_ws, size_t ws_size,
                              hipStream_t stream) {
    const float* x      = (const float*)d_in[0];
    const int*   ei     = (const int*)d_in[1];
    const int*   batch  = (const int*)d_in[2];
    const float* Ws     = (const float*)d_in[3];
    const float* bs     = (const float*)d_in[4];
    const float* rWs    = (const float*)d_in[5];
    const float* rbs    = (const float*)d_in[6];
    const float* gammas = (const float*)d_in[7];
    const float* betas  = (const float*)d_in[8];
    float* out = (float*)d_out;

    const int N = in_sizes[2];
    const int E = in_sizes[1] / 2;
    const int G = out_size / D;
    const int* src = ei;
    const int* dst = ei + E;
    const int EP = E + 4 * N + 8;   // padded-CSR upper bound (+2 quad guard)
    const int half = (N + 1) >> 1;
    const float invN = 1.0f / (float)N;
    const int n8 = N * (D / 8);

    char* ws = (char*)d_ws;
    size_t off = 0;
    auto alloc = [&](size_t bytes) -> char* {
        char* p = ws + off;
        off += (bytes + 255) & ~(size_t)255;
        return p;
    };
    unsigned short* hb = (unsigned short*)alloc((size_t)(N + 1) * D * 2);
    unsigned short* fb = (unsigned short*)alloc((size_t)N * D * 2);
    unsigned short* rbuf = (unsigned short*)alloc((size_t)N * D * 2);
    int*   csr  = (int*)alloc((size_t)EP * 4);
    int*   roff = (int*)alloc((size_t)(N + 1) * 4);
    int*   cur  = (int*)alloc((size_t)N * 4);
    int*   cnt  = (int*)alloc((size_t)N * 4);
    float* dinv = (float*)alloc((size_t)N * 4);
    int*   gcnt = (int*)alloc((size_t)G * 4);
    int*   goff = (int*)alloc((size_t)(G + 1) * 4);
    int*   bsum = (int*)alloc(256 * 4);
    int*   bbase= (int*)alloc(256 * 4);
    float* stats= (float*)alloc((size_t)NLAYERS * 2 * D * 4);
    unsigned short* Wp = (unsigned short*)alloc((size_t)2 * D * D * 2);
    float* cwA  = (float*)alloc(D * 4);
    float* crb  = (float*)alloc(D * 4);
    (void)ws_size;

    const int S = NLAYERS * 2 * D;
    k_zero<<<(N + G + S + 255) / 256, 256, 0, stream>>>(cnt, gcnt, (int*)stats, N, G, S);
    k_hist_xb<<<(E + N + n8 + 255) / 256, 256, 0, stream>>>(dst, batch, x, cnt, gcnt,
                                                            fb, E, N, n8);

    int nb = (N + 1023) / 1024;
    k_scan_partial<<<nb, 256, 0, stream>>>(cnt, bsum, dinv, hb, N);
    k_scan_small_g<<<2, 256, 0, stream>>>(bsum, bbase, nb, gcnt, goff, G, N);
    k_scan_apply<<<nb, 256, 0, stream>>>(cnt, bbase, roff, cur, csr, N);
    k_fill<<<(E + 255) / 256, 256, 0, stream>>>(src, dst, cur, csr, E);

    dim3 ggrid((N + 63) / 64, 2);
    for (int l = 0; l < NLAYERS; ++l) {
        const float* W  = Ws + (size_t)l * D * D;
        const float* rW = rWs + (size_t)l * D * D;
        const float* gamP = gammas + (size_t)(l > 0 ? l - 1 : 0) * D;
        const float* betP = betas + (size_t)(l > 0 ? l - 1 : 0) * D;
        const float* stP  = stats + (size_t)(l > 0 ? l - 1 : 0) * 2 * D;

        k_packfold<<<129, 256, 0, stream>>>(W, rW, gamP, betP, stP,
                                            rbs + (size_t)l * D,
                                            Wp, cwA, crb, (l == 0) ? 1 : 0, invN);

        k_gemm_mfma<<<ggrid, 256, 0, stream>>>(fb, Wp, cwA, crb, dinv,
                                               hb, rbuf, N);
        k_agg<<<4096, 256, 0, stream>>>(hb, rbuf, fb, roff, csr, dinv,
                                        bs + (size_t)l * D,
                                        stats + (size_t)l * 2 * D, N, half);
    }

    k_pool<<<G, 128, 0, stream>>>(fb, goff,
                                  gammas + (size_t)(NLAYERS - 1) * D,
                                  betas + (size_t)(NLAYERS - 1) * D,
                                  stats + (size_t)(NLAYERS - 1) * 2 * D,
                                  invN, out);
}